// Round 1
// baseline (281.096 us; speedup 1.0000x reference)
//
#include <hip/hip_runtime.h>

// Problem constants
#define PB 2
#define PS 2048
#define PHID 1024
#define PH 16
#define PKV 8
#define PD 64
#define PM (PB*PS)  // 4096

typedef __bf16 bf16_t;
typedef __bf16 bf16x8 __attribute__((ext_vector_type(8)));
typedef float f32x4 __attribute__((ext_vector_type(4)));

#define MFMA16(a,b,c) __builtin_amdgcn_mfma_f32_16x16x32_bf16((a),(b),(c),0,0,0)

// ---------------------------------------------------------------------------
// Kernel 1: fused QKV projection + RMSNorm + multidim RoPE, split-bf16 GEMM.
// grid: (64 row-tiles, 32 head-slots). slot 0-15: Q head, 16-23: K head, 24-31: V head.
// Outputs: q,k as hi+lo bf16 [B,H(KV),S,D]; v transposed bf16 [B,KV,D,S].
// ---------------------------------------------------------------------------
__global__ __launch_bounds__(256)
void qkv_kernel(const float* __restrict__ hs,
                const float* __restrict__ Wq, const float* __restrict__ Wk,
                const float* __restrict__ Wv,
                const float* __restrict__ cosp, const float* __restrict__ sinp,
                const float* __restrict__ qnw, const float* __restrict__ knw,
                bf16_t* __restrict__ qh_o, bf16_t* __restrict__ ql_o,
                bf16_t* __restrict__ kh_o, bf16_t* __restrict__ kl_o,
                bf16_t* __restrict__ vt_o)
{
  __shared__ __align__(16) bf16_t Ash[64][40], Asl[64][40];  // hs tile hi/lo [row][k]
  __shared__ __align__(16) bf16_t Bsh[64][40], Bsl[64][40];  // W tile hi/lo, transposed [n][k]

  const int tid = threadIdx.x;
  const int lane = tid & 63, wave = tid >> 6;
  const int lo16 = lane & 15, hi4 = lane >> 4;
  const int m0 = blockIdx.x * 64;
  const int slot = blockIdx.y;

  const float* W; int N, kind, hd;
  if (slot < 16)      { W = Wq; N = 1024; hd = slot;      kind = 0; }
  else if (slot < 24) { W = Wk; N = 512;  hd = slot - 16; kind = 1; }
  else                { W = Wv; N = 512;  hd = slot - 24; kind = 2; }
  const int col0 = hd * 64;

  f32x4 acc[4];
  #pragma unroll
  for (int j = 0; j < 4; ++j) acc[j] = f32x4{0.f, 0.f, 0.f, 0.f};

  const int arow = tid >> 2, akc = (tid & 3) * 8;   // A stage: 8 contiguous k per thread
  const int bn   = tid & 63, bkc = (tid >> 6) * 8;  // B stage: 8 strided k (coalesced in n)

  for (int k0 = 0; k0 < PHID; k0 += 32) {
    {   // stage A (hs fp32 -> hi/lo bf16)
      const float* ap = &hs[(size_t)(m0 + arow) * PHID + k0 + akc];
      float4 x0 = *(const float4*)ap;
      float4 x1 = *(const float4*)(ap + 4);
      float xs[8] = {x0.x, x0.y, x0.z, x0.w, x1.x, x1.y, x1.z, x1.w};
      bf16x8 hv, lv;
      #pragma unroll
      for (int i = 0; i < 8; ++i) {
        bf16_t hb = (bf16_t)xs[i];
        hv[i] = hb;
        lv[i] = (bf16_t)(xs[i] - (float)hb);
      }
      *(bf16x8*)&Ash[arow][akc] = hv;
      *(bf16x8*)&Asl[arow][akc] = lv;
    }
    {   // stage B transposed (W fp32 -> hi/lo bf16), coalesced across n
      const float* wp = &W[(size_t)(k0 + bkc) * N + col0 + bn];
      bf16x8 hv, lv;
      #pragma unroll
      for (int i = 0; i < 8; ++i) {
        float x = wp[(size_t)i * N];
        bf16_t hb = (bf16_t)x;
        hv[i] = hb;
        lv[i] = (bf16_t)(x - (float)hb);
      }
      *(bf16x8*)&Bsh[bn][bkc] = hv;
      *(bf16x8*)&Bsl[bn][bkc] = lv;
    }
    __syncthreads();
    {
      bf16x8 ah = *(const bf16x8*)&Ash[wave*16 + lo16][hi4*8];
      bf16x8 al = *(const bf16x8*)&Asl[wave*16 + lo16][hi4*8];
      #pragma unroll
      for (int j = 0; j < 4; ++j) {
        bf16x8 bh = *(const bf16x8*)&Bsh[j*16 + lo16][hi4*8];
        bf16x8 bl = *(const bf16x8*)&Bsl[j*16 + lo16][hi4*8];
        acc[j] = MFMA16(ah, bh, acc[j]);   // hi*hi
        acc[j] = MFMA16(al, bh, acc[j]);   // lo*hi
        acc[j] = MFMA16(ah, bl, acc[j]);   // hi*lo  (lo*lo dropped, ~2^-18 rel)
      }
    }
    __syncthreads();
  }

  // ---- epilogue: RMSNorm over D=64 (full row lives in this 16-lane group) ----
  float scale[4];
  #pragma unroll
  for (int r = 0; r < 4; ++r) {
    float s = 0.f;
    #pragma unroll
    for (int j = 0; j < 4; ++j) s += acc[j][r] * acc[j][r];
    #pragma unroll
    for (int m = 1; m < 16; m <<= 1) s += __shfl_xor(s, m);
    scale[r] = 1.0f / sqrtf(s * (1.0f/64.0f) + 1e-6f);
  }
  float nw[4];
  #pragma unroll
  for (int j = 0; j < 4; ++j)
    nw[j] = (kind == 0) ? qnw[lo16 + 16*j] : (kind == 1 ? knw[lo16 + 16*j] : 1.0f);

  float y[4][4];  // [j][r]
  #pragma unroll
  for (int j = 0; j < 4; ++j)
    #pragma unroll
    for (int r = 0; r < 4; ++r) y[j][r] = acc[j][r] * scale[r] * nw[j];

  if (kind == 2) {
    // V: no rope; store transposed [B,KV,D,S] for contiguous PV B-fragments
    #pragma unroll
    for (int r = 0; r < 4; ++r) {
      int mg = m0 + wave*16 + hi4*4 + r;
      int b = mg >> 11, sq = mg & 2047;
      #pragma unroll
      for (int j = 0; j < 4; ++j) {
        int d = lo16 + 16*j;
        vt_o[((size_t)((b*PKV + hd)*PD + d))*PS + sq] = (bf16_t)y[j][r];
      }
    }
  } else {
    // RoPE: ndim=2 -> cpd=32; rotate partner is col+-16 == same lane, j^1 register
    #pragma unroll
    for (int r = 0; r < 4; ++r) {
      int mg = m0 + wave*16 + hi4*4 + r;
      int b = mg >> 11, sq = mg & 2047;
      const float* cp = &cosp[(size_t)mg * PD];
      const float* sp = &sinp[(size_t)mg * PD];
      float z[4];
      #pragma unroll
      for (int j = 0; j < 4; ++j) {
        float c = cp[lo16 + 16*j], s = sp[lo16 + 16*j];
        float rot = (j & 1) ? y[j-1][r] : -y[j+1][r];
        z[j] = y[j][r] * c + rot * s;
      }
      #pragma unroll
      for (int j = 0; j < 4; ++j) {
        int d = lo16 + 16*j;
        bf16_t zh = (bf16_t)z[j];
        bf16_t zl = (bf16_t)(z[j] - (float)zh);
        if (kind == 0) {
          size_t idx = ((size_t)(b*PH + hd)*PS + sq)*PD + d;
          qh_o[idx] = zh; ql_o[idx] = zl;
        } else {
          size_t idx = ((size_t)(b*PKV + hd)*PS + sq)*PD + d;
          kh_o[idx] = zh; kl_o[idx] = zl;
        }
      }
    }
  }
}

// ---------------------------------------------------------------------------
// Kernel 2: flash attention. grid (32 q-tiles, B*H=32). 4 waves x 16 q-rows.
// QK^T in split-bf16 (fp32-grade scores), online softmax fp32, PV in bf16.
// ---------------------------------------------------------------------------
__global__ __launch_bounds__(256)
void attn_kernel(const bf16_t* __restrict__ qh_g, const bf16_t* __restrict__ ql_g,
                 const bf16_t* __restrict__ kh_g, const bf16_t* __restrict__ kl_g,
                 const bf16_t* __restrict__ vt_g, bf16_t* __restrict__ aout)
{
  __shared__ __align__(16) bf16_t Ksh[64][72], Ksl[64][72];  // K tile hi/lo [ki][d]
  __shared__ __align__(16) bf16_t Vss[64][72];               // V^T tile [d][ki]
  __shared__ __align__(16) bf16_t Pss[64][72];               // P tile [qi][ki]

  const int tid = threadIdx.x, lane = tid & 63, wave = tid >> 6;
  const int lo16 = lane & 15, hi4 = lane >> 4;
  const int qt = blockIdx.x;
  const int bh = blockIdx.y;
  const int b = bh >> 4, h = bh & 15, kvh = h >> 1;   // GQA: groups=2

  // Q fragments (A-operand rows = lane&15), held for the whole kernel
  const size_t qbase = ((size_t)(b*PH + h)*PS + qt*64 + wave*16 + lo16) * PD;
  bf16x8 qfh[2], qfl[2];
  #pragma unroll
  for (int t = 0; t < 2; ++t) {
    qfh[t] = *(const bf16x8*)&qh_g[qbase + t*32 + hi4*8];
    qfl[t] = *(const bf16x8*)&ql_g[qbase + t*32 + hi4*8];
  }

  f32x4 o[4];
  #pragma unroll
  for (int j = 0; j < 4; ++j) o[j] = f32x4{0.f, 0.f, 0.f, 0.f};
  float mrow[4] = {-1e30f, -1e30f, -1e30f, -1e30f};
  float lrow[4] = {0.f, 0.f, 0.f, 0.f};

  const int srow = tid >> 2, sc = (tid & 3) * 16;
  const size_t kbase = (size_t)(b*PKV + kvh) * PS * PD;
  const size_t vbase = (size_t)(b*PKV + kvh) * PD * PS;

  for (int kt = 0; kt < PS/64; ++kt) {
    { // stage K hi/lo + V^T tiles (16 bf16 = two 16B loads per array per thread)
      const bf16_t* kp  = &kh_g[kbase + (size_t)(kt*64 + srow)*PD + sc];
      const bf16_t* klp = &kl_g[kbase + (size_t)(kt*64 + srow)*PD + sc];
      const bf16_t* vp  = &vt_g[vbase + (size_t)srow*PS + kt*64 + sc];
      *(bf16x8*)&Ksh[srow][sc]     = *(const bf16x8*)kp;
      *(bf16x8*)&Ksh[srow][sc + 8] = *(const bf16x8*)(kp + 8);
      *(bf16x8*)&Ksl[srow][sc]     = *(const bf16x8*)klp;
      *(bf16x8*)&Ksl[srow][sc + 8] = *(const bf16x8*)(klp + 8);
      *(bf16x8*)&Vss[srow][sc]     = *(const bf16x8*)vp;
      *(bf16x8*)&Vss[srow][sc + 8] = *(const bf16x8*)(vp + 8);
    }
    __syncthreads();

    // QK^T: scores[qi = hi4*4+r][ki = lo16+16j]
    f32x4 sacc[4];
    #pragma unroll
    for (int j = 0; j < 4; ++j) sacc[j] = f32x4{0.f, 0.f, 0.f, 0.f};
    #pragma unroll
    for (int j = 0; j < 4; ++j) {
      #pragma unroll
      for (int t = 0; t < 2; ++t) {
        bf16x8 bh_ = *(const bf16x8*)&Ksh[j*16 + lo16][t*32 + hi4*8];
        bf16x8 bl_ = *(const bf16x8*)&Ksl[j*16 + lo16][t*32 + hi4*8];
        sacc[j] = MFMA16(qfh[t], bh_, sacc[j]);
        sacc[j] = MFMA16(qfl[t], bh_, sacc[j]);
        sacc[j] = MFMA16(qfh[t], bl_, sacc[j]);
      }
    }

    // online softmax (fp32); row stats replicated across the 16-lane group
    #pragma unroll
    for (int r = 0; r < 4; ++r) {
      float tm = fmaxf(fmaxf(sacc[0][r], sacc[1][r]), fmaxf(sacc[2][r], sacc[3][r]));
      #pragma unroll
      for (int m = 1; m < 16; m <<= 1) tm = fmaxf(tm, __shfl_xor(tm, m));
      float mnew = fmaxf(mrow[r], tm);
      float alpha = __expf(mrow[r] - mnew);
      float ls = 0.f;
      #pragma unroll
      for (int j = 0; j < 4; ++j) {
        float p = __expf(sacc[j][r] - mnew);
        sacc[j][r] = p;
        ls += p;
      }
      #pragma unroll
      for (int m = 1; m < 16; m <<= 1) ls += __shfl_xor(ls, m);
      lrow[r] = lrow[r] * alpha + ls;
      mrow[r] = mnew;
      #pragma unroll
      for (int jd = 0; jd < 4; ++jd) o[jd][r] *= alpha;
    }

    // P -> LDS (bf16). Each wave writes rows [wave*16, wave*16+16) and reads
    // only those rows below: same-wave DS ordering, no barrier needed here.
    #pragma unroll
    for (int r = 0; r < 4; ++r)
      #pragma unroll
      for (int j = 0; j < 4; ++j)
        Pss[wave*16 + hi4*4 + r][lo16 + 16*j] = (bf16_t)sacc[j][r];

    // PV: o[qi][d] += P[qi][ki] * V[ki][d]  (B-frag from V^T tile, contiguous)
    #pragma unroll
    for (int jd = 0; jd < 4; ++jd) {
      #pragma unroll
      for (int t = 0; t < 2; ++t) {
        bf16x8 pa = *(const bf16x8*)&Pss[wave*16 + lo16][t*32 + hi4*8];
        bf16x8 bv = *(const bf16x8*)&Vss[jd*16 + lo16][t*32 + hi4*8];
        o[jd] = MFMA16(pa, bv, o[jd]);
      }
    }
    __syncthreads();  // protect K/V/P tiles before next stage
  }

  // normalize and write attn-out in [B,S,H*D] bf16 for the final projection
  #pragma unroll
  for (int r = 0; r < 4; ++r) {
    float inv = 1.0f / lrow[r];
    int sq = qt*64 + wave*16 + hi4*4 + r;
    size_t obase = ((size_t)(b*PS + sq))*(PH*PD) + h*PD;
    #pragma unroll
    for (int jd = 0; jd < 4; ++jd)
      aout[obase + lo16 + 16*jd] = (bf16_t)(o[jd][r] * inv);
  }
}

// ---------------------------------------------------------------------------
// Kernel 3: out-projection, single bf16 GEMM -> fp32 out. grid (64, 16).
// ---------------------------------------------------------------------------
__global__ __launch_bounds__(256)
void oproj_kernel(const bf16_t* __restrict__ ao, const float* __restrict__ Wo,
                  float* __restrict__ out)
{
  __shared__ __align__(16) bf16_t As[64][40], Bs[64][40];
  const int tid = threadIdx.x;
  const int lane = tid & 63, wave = tid >> 6;
  const int lo16 = lane & 15, hi4 = lane >> 4;
  const int m0 = blockIdx.x * 64;
  const int col0 = blockIdx.y * 64;

  f32x4 acc[4];
  #pragma unroll
  for (int j = 0; j < 4; ++j) acc[j] = f32x4{0.f, 0.f, 0.f, 0.f};

  const int arow = tid >> 2, akc = (tid & 3) * 8;
  const int bn   = tid & 63, bkc = (tid >> 6) * 8;

  for (int k0 = 0; k0 < PHID; k0 += 32) {
    *(bf16x8*)&As[arow][akc] =
        *(const bf16x8*)&ao[(size_t)(m0 + arow)*PHID + k0 + akc];
    {
      const float* wp = &Wo[(size_t)(k0 + bkc) * PHID + col0 + bn];
      bf16x8 bv;
      #pragma unroll
      for (int i = 0; i < 8; ++i) bv[i] = (bf16_t)wp[(size_t)i * PHID];
      *(bf16x8*)&Bs[bn][bkc] = bv;
    }
    __syncthreads();
    {
      bf16x8 a = *(const bf16x8*)&As[wave*16 + lo16][hi4*8];
      #pragma unroll
      for (int j = 0; j < 4; ++j) {
        bf16x8 bb = *(const bf16x8*)&Bs[j*16 + lo16][hi4*8];
        acc[j] = MFMA16(a, bb, acc[j]);
      }
    }
    __syncthreads();
  }

  #pragma unroll
  for (int r = 0; r < 4; ++r) {
    int mg = m0 + wave*16 + hi4*4 + r;
    #pragma unroll
    for (int j = 0; j < 4; ++j)
      out[(size_t)mg*PHID + col0 + lo16 + 16*j] = acc[j][r];
  }
}

// ---------------------------------------------------------------------------
extern "C" void kernel_launch(void* const* d_in, const int* in_sizes, int n_in,
                              void* d_out, int out_size, void* d_ws, size_t ws_size,
                              hipStream_t stream) {
  (void)in_sizes; (void)n_in; (void)out_size; (void)ws_size;
  const float* hs   = (const float*)d_in[0];
  const float* cosp = (const float*)d_in[1];
  const float* sinp = (const float*)d_in[2];
  // d_in[3] position_ids: only shape[-1]=2 is used (hardcoded NDIM=2)
  const float* Wq   = (const float*)d_in[4];
  const float* Wk   = (const float*)d_in[5];
  const float* Wv   = (const float*)d_in[6];
  const float* Wo   = (const float*)d_in[7];
  const float* qnw  = (const float*)d_in[8];
  const float* knw  = (const float*)d_in[9];
  float* out = (float*)d_out;

  bf16_t* ws = (bf16_t*)d_ws;
  const size_t QN = (size_t)PB*PH*PS*PD;   // 4,194,304
  const size_t KN = (size_t)PB*PKV*PS*PD;  // 2,097,152
  bf16_t* qh = ws;
  bf16_t* ql = qh + QN;
  bf16_t* kh = ql + QN;
  bf16_t* kl = kh + KN;
  bf16_t* vt = kl + KN;
  bf16_t* ao = vt + KN;                    // total 37,748,736 bytes of d_ws

  qkv_kernel<<<dim3(64, 32), 256, 0, stream>>>(hs, Wq, Wk, Wv, cosp, sinp,
                                               qnw, knw, qh, ql, kh, kl, vt);
  attn_kernel<<<dim3(32, 32), 256, 0, stream>>>(qh, ql, kh, kl, vt, ao);
  oproj_kernel<<<dim3(64, 16), 256, 0, stream>>>(ao, Wo, out);
}

// Round 2
// 228.622 us; speedup vs baseline: 1.2295x; 1.2295x over previous
//
#include <hip/hip_runtime.h>

// Problem constants
#define PB 2
#define PS 2048
#define PHID 1024
#define PH 16
#define PKV 8
#define PD 64
#define PM (PB*PS)  // 4096

typedef __bf16 bf16_t;
typedef __bf16 bf16x8 __attribute__((ext_vector_type(8)));
typedef float f32x4 __attribute__((ext_vector_type(4)));

#define MFMA16(a,b,c) __builtin_amdgcn_mfma_f32_16x16x32_bf16((a),(b),(c),0,0,0)

// ---------------------------------------------------------------------------
// Kernel 1: fused QKV projection + RMSNorm + multidim RoPE, split-bf16 GEMM.
// 128-row M-tiles (2 row-blocks per wave), reg-prefetch staging, V hi-only.
// grid: (32 row-tiles, 32 head-slots). slot 0-15: Q, 16-23: K, 24-31: V.
// ---------------------------------------------------------------------------
__global__ __launch_bounds__(256)
void qkv_kernel(const float* __restrict__ hs,
                const float* __restrict__ Wq, const float* __restrict__ Wk,
                const float* __restrict__ Wv,
                const float* __restrict__ cosp, const float* __restrict__ sinp,
                const float* __restrict__ qnw, const float* __restrict__ knw,
                bf16_t* __restrict__ qh_o, bf16_t* __restrict__ ql_o,
                bf16_t* __restrict__ kh_o, bf16_t* __restrict__ kl_o,
                bf16_t* __restrict__ vt_o)
{
  __shared__ __align__(16) bf16_t Ash[128][40], Asl[128][40];
  __shared__ __align__(16) bf16_t Bsh[64][40],  Bsl[64][40];

  const int tid = threadIdx.x;
  const int lane = tid & 63, wave = tid >> 6;
  const int lo16 = lane & 15, hi4 = lane >> 4;
  const int m0 = blockIdx.x * 128;
  const int slot = blockIdx.y;

  const float* W; int N, kind, hd;
  if (slot < 16)      { W = Wq; N = 1024; hd = slot;      kind = 0; }
  else if (slot < 24) { W = Wk; N = 512;  hd = slot - 16; kind = 1; }
  else                { W = Wv; N = 512;  hd = slot - 24; kind = 2; }
  const int col0 = hd * 64;

  f32x4 acc[2][4];
  #pragma unroll
  for (int qb = 0; qb < 2; ++qb)
    #pragma unroll
    for (int j = 0; j < 4; ++j) acc[qb][j] = f32x4{0.f, 0.f, 0.f, 0.f};

  // A stage: thread -> 4 float4 segments (rows tid/8 + 32i, cols (tid&7)*4)
  const int ar = tid >> 3, ac = (tid & 7) * 4;
  // B stage: 64 n x 32 k; thread n = tid&63, k-base (tid>>6)*8
  const int bn = tid & 63, bkc = (tid >> 6) * 8;

  float4 ga[4];
  float  gb[8];
  auto LOADA = [&](int k0) {
    #pragma unroll
    for (int i = 0; i < 4; ++i)
      ga[i] = *(const float4*)&hs[(size_t)(m0 + ar + 32*i) * PHID + k0 + ac];
  };
  auto LOADB = [&](int k0) {
    const float* wp = &W[(size_t)(k0 + bkc) * N + col0 + bn];
    #pragma unroll
    for (int i = 0; i < 8; ++i) gb[i] = wp[(size_t)i * N];
  };
  LOADA(0); LOADB(0);

  for (int k0 = 0; k0 < PHID; k0 += 32) {
    __syncthreads();   // previous MFMA phase done reading LDS
    // convert + write A (hi/lo)
    #pragma unroll
    for (int i = 0; i < 4; ++i) {
      float xs[4] = {ga[i].x, ga[i].y, ga[i].z, ga[i].w};
      bf16_t hv[4], lv[4];
      #pragma unroll
      for (int e = 0; e < 4; ++e) {
        hv[e] = (bf16_t)xs[e];
        lv[e] = (bf16_t)(xs[e] - (float)hv[e]);
      }
      *(ulong*)&Ash[ar + 32*i][ac] = *(ulong*)hv;
      *(ulong*)&Asl[ar + 32*i][ac] = *(ulong*)lv;
    }
    // convert + write B (hi always, lo only for Q/K)
    {
      bf16x8 hv, lv;
      #pragma unroll
      for (int i = 0; i < 8; ++i) {
        bf16_t hb = (bf16_t)gb[i];
        hv[i] = hb;
        lv[i] = (bf16_t)(gb[i] - (float)hb);
      }
      *(bf16x8*)&Bsh[bn][bkc] = hv;
      if (kind != 2) *(bf16x8*)&Bsl[bn][bkc] = lv;
    }
    if (k0 + 32 < PHID) { LOADA(k0 + 32); LOADB(k0 + 32); }
    __syncthreads();
    {
      bf16x8 ah[2], al[2];
      #pragma unroll
      for (int qb = 0; qb < 2; ++qb) {
        ah[qb] = *(const bf16x8*)&Ash[wave*32 + qb*16 + lo16][hi4*8];
        al[qb] = *(const bf16x8*)&Asl[wave*32 + qb*16 + lo16][hi4*8];
      }
      #pragma unroll
      for (int j = 0; j < 4; ++j) {
        bf16x8 bh = *(const bf16x8*)&Bsh[j*16 + lo16][hi4*8];
        if (kind != 2) {
          bf16x8 bl = *(const bf16x8*)&Bsl[j*16 + lo16][hi4*8];
          #pragma unroll
          for (int qb = 0; qb < 2; ++qb) {
            acc[qb][j] = MFMA16(ah[qb], bh, acc[qb][j]);
            acc[qb][j] = MFMA16(al[qb], bh, acc[qb][j]);
            acc[qb][j] = MFMA16(ah[qb], bl, acc[qb][j]);
          }
        } else {
          #pragma unroll
          for (int qb = 0; qb < 2; ++qb)
            acc[qb][j] = MFMA16(ah[qb], bh, acc[qb][j]);
        }
      }
    }
  }

  // ---- epilogue per row-block: RMSNorm + RoPE/transpose-store ----
  #pragma unroll
  for (int qb = 0; qb < 2; ++qb) {
    float scale[4];
    #pragma unroll
    for (int r = 0; r < 4; ++r) {
      float s = 0.f;
      #pragma unroll
      for (int j = 0; j < 4; ++j) s += acc[qb][j][r] * acc[qb][j][r];
      #pragma unroll
      for (int m = 1; m < 16; m <<= 1) s += __shfl_xor(s, m);
      scale[r] = 1.0f / sqrtf(s * (1.0f/64.0f) + 1e-6f);
    }
    float nw[4];
    #pragma unroll
    for (int j = 0; j < 4; ++j)
      nw[j] = (kind == 0) ? qnw[lo16 + 16*j] : (kind == 1 ? knw[lo16 + 16*j] : 1.0f);

    float y[4][4];
    #pragma unroll
    for (int j = 0; j < 4; ++j)
      #pragma unroll
      for (int r = 0; r < 4; ++r) y[j][r] = acc[qb][j][r] * scale[r] * nw[j];

    if (kind == 2) {
      #pragma unroll
      for (int r = 0; r < 4; ++r) {
        int mg = m0 + wave*32 + qb*16 + hi4*4 + r;
        int b = mg >> 11, sq = mg & 2047;
        #pragma unroll
        for (int j = 0; j < 4; ++j) {
          int d = lo16 + 16*j;
          vt_o[((size_t)((b*PKV + hd)*PD + d))*PS + sq] = (bf16_t)y[j][r];
        }
      }
    } else {
      #pragma unroll
      for (int r = 0; r < 4; ++r) {
        int mg = m0 + wave*32 + qb*16 + hi4*4 + r;
        int b = mg >> 11, sq = mg & 2047;
        const float* cp = &cosp[(size_t)mg * PD];
        const float* sp = &sinp[(size_t)mg * PD];
        float z[4];
        #pragma unroll
        for (int j = 0; j < 4; ++j) {
          float c = cp[lo16 + 16*j], s = sp[lo16 + 16*j];
          float rot = (j & 1) ? y[j-1][r] : -y[j+1][r];
          z[j] = y[j][r] * c + rot * s;
        }
        #pragma unroll
        for (int j = 0; j < 4; ++j) {
          int d = lo16 + 16*j;
          bf16_t zh = (bf16_t)z[j];
          bf16_t zl = (bf16_t)(z[j] - (float)zh);
          if (kind == 0) {
            size_t idx = ((size_t)(b*PH + hd)*PS + sq)*PD + d;
            qh_o[idx] = zh; ql_o[idx] = zl;
          } else {
            size_t idx = ((size_t)(b*PKV + hd)*PS + sq)*PD + d;
            kh_o[idx] = zh; kl_o[idx] = zl;
          }
        }
      }
    }
  }
}

// ---------------------------------------------------------------------------
// Kernel 2: flash attention. grid (16 q-tiles of 128, B*H=32). 4 waves,
// 32 q-rows per wave. Split-bf16 QK^T, fp32 online softmax, bf16 PV.
// Reg-prefetch of next K/V tile hides global latency under compute.
// ---------------------------------------------------------------------------
__global__ __launch_bounds__(256)
void attn_kernel(const bf16_t* __restrict__ qh_g, const bf16_t* __restrict__ ql_g,
                 const bf16_t* __restrict__ kh_g, const bf16_t* __restrict__ kl_g,
                 const bf16_t* __restrict__ vt_g, bf16_t* __restrict__ aout)
{
  __shared__ __align__(16) bf16_t Ksh[64][72], Ksl[64][72];  // K tile hi/lo [ki][d]
  __shared__ __align__(16) bf16_t Vss[64][72];               // V^T tile [d][ki]
  __shared__ __align__(16) bf16_t Pss[128][72];              // P tile [qi][ki]

  const int tid = threadIdx.x, lane = tid & 63, wave = tid >> 6;
  const int lo16 = lane & 15, hi4 = lane >> 4;
  const int qt = blockIdx.x;
  const int bh = blockIdx.y;
  const int b = bh >> 4, h = bh & 15, kvh = h >> 1;   // GQA groups=2

  // Q fragments: 2 row-blocks x 2 k-halves, hi+lo, held in registers
  bf16x8 qfh[2][2], qfl[2][2];
  #pragma unroll
  for (int qb = 0; qb < 2; ++qb) {
    const size_t qbase = ((size_t)(b*PH + h)*PS + qt*128 + wave*32 + qb*16 + lo16) * PD;
    #pragma unroll
    for (int t = 0; t < 2; ++t) {
      qfh[qb][t] = *(const bf16x8*)&qh_g[qbase + t*32 + hi4*8];
      qfl[qb][t] = *(const bf16x8*)&ql_g[qbase + t*32 + hi4*8];
    }
  }

  f32x4 o[2][4];
  float mrow[2][4], lrow[2][4];
  #pragma unroll
  for (int qb = 0; qb < 2; ++qb)
    #pragma unroll
    for (int j = 0; j < 4; ++j) {
      o[qb][j] = f32x4{0.f, 0.f, 0.f, 0.f};
      mrow[qb][j] = -1e30f; lrow[qb][j] = 0.f;
    }

  const int srow = tid >> 2, sc = (tid & 3) * 16;
  const size_t kbase = (size_t)(b*PKV + kvh) * PS * PD;
  const size_t vbase = (size_t)(b*PKV + kvh) * PD * PS;

  bf16x8 gk0, gk1, gl0, gl1, gv0, gv1;
  auto LOADT = [&](int kt) {
    const bf16_t* kp  = &kh_g[kbase + (size_t)(kt*64 + srow)*PD + sc];
    const bf16_t* klp = &kl_g[kbase + (size_t)(kt*64 + srow)*PD + sc];
    const bf16_t* vp  = &vt_g[vbase + (size_t)srow*PS + kt*64 + sc];
    gk0 = *(const bf16x8*)kp;        gk1 = *(const bf16x8*)(kp + 8);
    gl0 = *(const bf16x8*)klp;       gl1 = *(const bf16x8*)(klp + 8);
    gv0 = *(const bf16x8*)vp;        gv1 = *(const bf16x8*)(vp + 8);
  };
  LOADT(0);

  for (int kt = 0; kt < PS/64; ++kt) {
    __syncthreads();   // all waves done computing on previous tile
    *(bf16x8*)&Ksh[srow][sc]     = gk0;
    *(bf16x8*)&Ksh[srow][sc + 8] = gk1;
    *(bf16x8*)&Ksl[srow][sc]     = gl0;
    *(bf16x8*)&Ksl[srow][sc + 8] = gl1;
    *(bf16x8*)&Vss[srow][sc]     = gv0;
    *(bf16x8*)&Vss[srow][sc + 8] = gv1;
    if (kt + 1 < PS/64) LOADT(kt + 1);  // in flight during compute
    __syncthreads();

    // QK^T: K-fragments shared across both q row-blocks
    f32x4 sacc[2][4];
    #pragma unroll
    for (int qb = 0; qb < 2; ++qb)
      #pragma unroll
      for (int j = 0; j < 4; ++j) sacc[qb][j] = f32x4{0.f, 0.f, 0.f, 0.f};
    #pragma unroll
    for (int j = 0; j < 4; ++j) {
      #pragma unroll
      for (int t = 0; t < 2; ++t) {
        bf16x8 bh_ = *(const bf16x8*)&Ksh[j*16 + lo16][t*32 + hi4*8];
        bf16x8 bl_ = *(const bf16x8*)&Ksl[j*16 + lo16][t*32 + hi4*8];
        #pragma unroll
        for (int qb = 0; qb < 2; ++qb) {
          sacc[qb][j] = MFMA16(qfh[qb][t], bh_, sacc[qb][j]);
          sacc[qb][j] = MFMA16(qfl[qb][t], bh_, sacc[qb][j]);
          sacc[qb][j] = MFMA16(qfh[qb][t], bl_, sacc[qb][j]);
        }
      }
    }

    // online softmax (fp32), replicated across each 16-lane group
    #pragma unroll
    for (int qb = 0; qb < 2; ++qb) {
      #pragma unroll
      for (int r = 0; r < 4; ++r) {
        float tm = fmaxf(fmaxf(sacc[qb][0][r], sacc[qb][1][r]),
                         fmaxf(sacc[qb][2][r], sacc[qb][3][r]));
        #pragma unroll
        for (int m = 1; m < 16; m <<= 1) tm = fmaxf(tm, __shfl_xor(tm, m));
        float mnew = fmaxf(mrow[qb][r], tm);
        float alpha = __expf(mrow[qb][r] - mnew);
        float ls = 0.f;
        #pragma unroll
        for (int j = 0; j < 4; ++j) {
          float p = __expf(sacc[qb][j][r] - mnew);
          sacc[qb][j][r] = p;
          ls += p;
        }
        #pragma unroll
        for (int m = 1; m < 16; m <<= 1) ls += __shfl_xor(ls, m);
        lrow[qb][r] = lrow[qb][r] * alpha + ls;
        mrow[qb][r] = mnew;
        #pragma unroll
        for (int jd = 0; jd < 4; ++jd) o[qb][jd][r] *= alpha;
      }
    }

    // P -> LDS (same-wave rows only; in-wave DS ordering, no barrier)
    #pragma unroll
    for (int qb = 0; qb < 2; ++qb)
      #pragma unroll
      for (int r = 0; r < 4; ++r)
        #pragma unroll
        for (int j = 0; j < 4; ++j)
          Pss[wave*32 + qb*16 + hi4*4 + r][lo16 + 16*j] = (bf16_t)sacc[qb][j][r];

    bf16x8 pa[2][2];
    #pragma unroll
    for (int qb = 0; qb < 2; ++qb)
      #pragma unroll
      for (int t = 0; t < 2; ++t)
        pa[qb][t] = *(const bf16x8*)&Pss[wave*32 + qb*16 + lo16][t*32 + hi4*8];

    // PV: V-fragments shared across both q row-blocks
    #pragma unroll
    for (int jd = 0; jd < 4; ++jd) {
      #pragma unroll
      for (int t = 0; t < 2; ++t) {
        bf16x8 bv = *(const bf16x8*)&Vss[jd*16 + lo16][t*32 + hi4*8];
        #pragma unroll
        for (int qb = 0; qb < 2; ++qb)
          o[qb][jd] = MFMA16(pa[qb][t], bv, o[qb][jd]);
      }
    }
  }

  // normalize + write attn-out [B,S,H*D] bf16
  #pragma unroll
  for (int qb = 0; qb < 2; ++qb)
    #pragma unroll
    for (int r = 0; r < 4; ++r) {
      float inv = 1.0f / lrow[qb][r];
      int sq = qt*128 + wave*32 + qb*16 + hi4*4 + r;
      size_t obase = ((size_t)(b*PS + sq))*(PH*PD) + h*PD;
      #pragma unroll
      for (int jd = 0; jd < 4; ++jd)
        aout[obase + lo16 + 16*jd] = (bf16_t)(o[qb][jd][r] * inv);
    }
}

// ---------------------------------------------------------------------------
// Kernel 3: out-projection, bf16 GEMM -> fp32. 128-row tiles, reg-prefetch.
// grid (32, 16).
// ---------------------------------------------------------------------------
__global__ __launch_bounds__(256)
void oproj_kernel(const bf16_t* __restrict__ ao, const float* __restrict__ Wo,
                  float* __restrict__ out)
{
  __shared__ __align__(16) bf16_t As[128][40], Bs[64][40];
  const int tid = threadIdx.x;
  const int lane = tid & 63, wave = tid >> 6;
  const int lo16 = lane & 15, hi4 = lane >> 4;
  const int m0 = blockIdx.x * 128;
  const int col0 = blockIdx.y * 64;

  f32x4 acc[2][4];
  #pragma unroll
  for (int qb = 0; qb < 2; ++qb)
    #pragma unroll
    for (int j = 0; j < 4; ++j) acc[qb][j] = f32x4{0.f, 0.f, 0.f, 0.f};

  const int ar = tid >> 1, akc = (tid & 1) * 16;   // A: 16 bf16 per thread
  const int bn = tid & 63, bkc = (tid >> 6) * 8;

  bf16x8 gA0, gA1;
  float  gb[8];
  auto LOADA = [&](int k0) {
    const bf16_t* ap = &ao[(size_t)(m0 + ar) * PHID + k0 + akc];
    gA0 = *(const bf16x8*)ap;
    gA1 = *(const bf16x8*)(ap + 8);
  };
  auto LOADB = [&](int k0) {
    const float* wp = &Wo[(size_t)(k0 + bkc) * PHID + col0 + bn];
    #pragma unroll
    for (int i = 0; i < 8; ++i) gb[i] = wp[(size_t)i * PHID];
  };
  LOADA(0); LOADB(0);

  for (int k0 = 0; k0 < PHID; k0 += 32) {
    __syncthreads();
    *(bf16x8*)&As[ar][akc]     = gA0;
    *(bf16x8*)&As[ar][akc + 8] = gA1;
    {
      bf16x8 bv;
      #pragma unroll
      for (int i = 0; i < 8; ++i) bv[i] = (bf16_t)gb[i];
      *(bf16x8*)&Bs[bn][bkc] = bv;
    }
    if (k0 + 32 < PHID) { LOADA(k0 + 32); LOADB(k0 + 32); }
    __syncthreads();
    {
      bf16x8 a[2];
      #pragma unroll
      for (int qb = 0; qb < 2; ++qb)
        a[qb] = *(const bf16x8*)&As[wave*32 + qb*16 + lo16][hi4*8];
      #pragma unroll
      for (int j = 0; j < 4; ++j) {
        bf16x8 bb = *(const bf16x8*)&Bs[j*16 + lo16][hi4*8];
        #pragma unroll
        for (int qb = 0; qb < 2; ++qb)
          acc[qb][j] = MFMA16(a[qb], bb, acc[qb][j]);
      }
    }
  }

  #pragma unroll
  for (int qb = 0; qb < 2; ++qb)
    #pragma unroll
    for (int r = 0; r < 4; ++r) {
      int mg = m0 + wave*32 + qb*16 + hi4*4 + r;
      #pragma unroll
      for (int j = 0; j < 4; ++j)
        out[(size_t)mg*PHID + col0 + lo16 + 16*j] = acc[qb][j][r];
    }
}

// ---------------------------------------------------------------------------
extern "C" void kernel_launch(void* const* d_in, const int* in_sizes, int n_in,
                              void* d_out, int out_size, void* d_ws, size_t ws_size,
                              hipStream_t stream) {
  (void)in_sizes; (void)n_in; (void)out_size; (void)ws_size;
  const float* hs   = (const float*)d_in[0];
  const float* cosp = (const float*)d_in[1];
  const float* sinp = (const float*)d_in[2];
  // d_in[3] position_ids: only shape[-1]=2 is used (hardcoded NDIM=2)
  const float* Wq   = (const float*)d_in[4];
  const float* Wk   = (const float*)d_in[5];
  const float* Wv   = (const float*)d_in[6];
  const float* Wo   = (const float*)d_in[7];
  const float* qnw  = (const float*)d_in[8];
  const float* knw  = (const float*)d_in[9];
  float* out = (float*)d_out;

  bf16_t* ws = (bf16_t*)d_ws;
  const size_t QN = (size_t)PB*PH*PS*PD;   // 4,194,304
  const size_t KN = (size_t)PB*PKV*PS*PD;  // 2,097,152
  bf16_t* qh = ws;
  bf16_t* ql = qh + QN;
  bf16_t* kh = ql + QN;
  bf16_t* kl = kh + KN;
  bf16_t* vt = kl + KN;
  bf16_t* ao = vt + KN;                    // total 37,748,736 bytes of d_ws

  qkv_kernel<<<dim3(32, 32), 256, 0, stream>>>(hs, Wq, Wk, Wv, cosp, sinp,
                                               qnw, knw, qh, ql, kh, kl, vt);
  attn_kernel<<<dim3(16, 32), 256, 0, stream>>>(qh, ql, kh, kl, vt, ao);
  oproj_kernel<<<dim3(32, 16), 256, 0, stream>>>(ao, Wo, out);
}

// Round 4
// 198.740 us; speedup vs baseline: 1.4144x; 1.1504x over previous
//
#include <hip/hip_runtime.h>

// Problem constants
#define PB 2
#define PS 2048
#define PHID 1024
#define PH 16
#define PKV 8
#define PD 64
#define PM (PB*PS)   // 4096
#define PR (PB*PH*PS) // 65536 q-rows total

typedef __bf16 bf16_t;
typedef __bf16 bf16x8 __attribute__((ext_vector_type(8)));
typedef __bf16 bf16x2 __attribute__((ext_vector_type(2)));
typedef float f32x4 __attribute__((ext_vector_type(4)));

#define MFMA16(a,b,c) __builtin_amdgcn_mfma_f32_16x16x32_bf16((a),(b),(c),0,0,0)

// ---------------------------------------------------------------------------
// Kernel 1: fused QKV projection + RMSNorm + multidim RoPE, split-bf16 GEMM.
// 128-row M-tiles, reg-prefetch staging. Q and K both store hi+lo (numerics:
// the 3-term split product needs lo on both sides of QK^T).
// grid: 1024 1D, XCD-swizzled; decode rt = swz>>5 (row-tile), slot = swz&31.
// ---------------------------------------------------------------------------
__global__ __launch_bounds__(256)
void qkv_kernel(const float* __restrict__ hs,
                const float* __restrict__ Wq, const float* __restrict__ Wk,
                const float* __restrict__ Wv,
                const float* __restrict__ cosp, const float* __restrict__ sinp,
                const float* __restrict__ qnw, const float* __restrict__ knw,
                bf16_t* __restrict__ qh_o, bf16_t* __restrict__ ql_o,
                bf16_t* __restrict__ kh_o, bf16_t* __restrict__ kl_o,
                bf16_t* __restrict__ vt_o)
{
  __shared__ __align__(16) bf16_t Ash[128][40], Asl[128][40];
  __shared__ __align__(16) bf16_t Bsh[64][40],  Bsl[64][40];

  const int tid = threadIdx.x;
  const int lane = tid & 63, wave = tid >> 6;
  const int lo16 = lane & 15, hi4 = lane >> 4;
  const int lin = blockIdx.x;
  const int swz = (lin & 7) * 128 + (lin >> 3);  // XCD-cluster row-tiles
  const int m0 = (swz >> 5) * 128;
  const int slot = swz & 31;

  const float* W; int N, kind, hd;
  if (slot < 16)      { W = Wq; N = 1024; hd = slot;      kind = 0; }
  else if (slot < 24) { W = Wk; N = 512;  hd = slot - 16; kind = 1; }
  else                { W = Wv; N = 512;  hd = slot - 24; kind = 2; }
  const int col0 = hd * 64;

  f32x4 acc[2][4];
  #pragma unroll
  for (int qb = 0; qb < 2; ++qb)
    #pragma unroll
    for (int j = 0; j < 4; ++j) acc[qb][j] = f32x4{0.f, 0.f, 0.f, 0.f};

  const int ar = tid >> 3, ac = (tid & 7) * 4;
  const int bn = tid & 63, bkc = (tid >> 6) * 8;

  float4 ga[4];
  float  gb[8];
  auto LOADA = [&](int k0) {
    #pragma unroll
    for (int i = 0; i < 4; ++i)
      ga[i] = *(const float4*)&hs[(size_t)(m0 + ar + 32*i) * PHID + k0 + ac];
  };
  auto LOADB = [&](int k0) {
    const float* wp = &W[(size_t)(k0 + bkc) * N + col0 + bn];
    #pragma unroll
    for (int i = 0; i < 8; ++i) gb[i] = wp[(size_t)i * N];
  };
  LOADA(0); LOADB(0);

  for (int k0 = 0; k0 < PHID; k0 += 32) {
    __syncthreads();
    #pragma unroll
    for (int i = 0; i < 4; ++i) {
      float xs[4] = {ga[i].x, ga[i].y, ga[i].z, ga[i].w};
      bf16_t hv[4], lv[4];
      #pragma unroll
      for (int e = 0; e < 4; ++e) {
        hv[e] = (bf16_t)xs[e];
        lv[e] = (bf16_t)(xs[e] - (float)hv[e]);
      }
      *(ulong*)&Ash[ar + 32*i][ac] = *(ulong*)hv;
      *(ulong*)&Asl[ar + 32*i][ac] = *(ulong*)lv;
    }
    {
      bf16x8 hv, lv;
      #pragma unroll
      for (int i = 0; i < 8; ++i) {
        bf16_t hb = (bf16_t)gb[i];
        hv[i] = hb;
        lv[i] = (bf16_t)(gb[i] - (float)hb);
      }
      *(bf16x8*)&Bsh[bn][bkc] = hv;
      if (kind != 2) *(bf16x8*)&Bsl[bn][bkc] = lv;
    }
    if (k0 + 32 < PHID) { LOADA(k0 + 32); LOADB(k0 + 32); }
    __syncthreads();
    {
      bf16x8 ah[2], al[2];
      #pragma unroll
      for (int qb = 0; qb < 2; ++qb) {
        ah[qb] = *(const bf16x8*)&Ash[wave*32 + qb*16 + lo16][hi4*8];
        al[qb] = *(const bf16x8*)&Asl[wave*32 + qb*16 + lo16][hi4*8];
      }
      #pragma unroll
      for (int j = 0; j < 4; ++j) {
        bf16x8 bh = *(const bf16x8*)&Bsh[j*16 + lo16][hi4*8];
        if (kind != 2) {
          bf16x8 bl = *(const bf16x8*)&Bsl[j*16 + lo16][hi4*8];
          #pragma unroll
          for (int qb = 0; qb < 2; ++qb) {
            acc[qb][j] = MFMA16(ah[qb], bh, acc[qb][j]);
            acc[qb][j] = MFMA16(al[qb], bh, acc[qb][j]);
            acc[qb][j] = MFMA16(ah[qb], bl, acc[qb][j]);
          }
        } else {
          #pragma unroll
          for (int qb = 0; qb < 2; ++qb)
            acc[qb][j] = MFMA16(ah[qb], bh, acc[qb][j]);
        }
      }
    }
  }

  #pragma unroll
  for (int qb = 0; qb < 2; ++qb) {
    float scale[4];
    #pragma unroll
    for (int r = 0; r < 4; ++r) {
      float s = 0.f;
      #pragma unroll
      for (int j = 0; j < 4; ++j) s += acc[qb][j][r] * acc[qb][j][r];
      #pragma unroll
      for (int m = 1; m < 16; m <<= 1) s += __shfl_xor(s, m);
      scale[r] = 1.0f / sqrtf(s * (1.0f/64.0f) + 1e-6f);
    }
    float nw[4];
    #pragma unroll
    for (int j = 0; j < 4; ++j)
      nw[j] = (kind == 0) ? qnw[lo16 + 16*j] : (kind == 1 ? knw[lo16 + 16*j] : 1.0f);

    float y[4][4];
    #pragma unroll
    for (int j = 0; j < 4; ++j)
      #pragma unroll
      for (int r = 0; r < 4; ++r) y[j][r] = acc[qb][j][r] * scale[r] * nw[j];

    if (kind == 2) {
      #pragma unroll
      for (int r = 0; r < 4; ++r) {
        int mg = m0 + wave*32 + qb*16 + hi4*4 + r;
        int b = mg >> 11, sq = mg & 2047;
        #pragma unroll
        for (int j = 0; j < 4; ++j) {
          int d = lo16 + 16*j;
          vt_o[((size_t)((b*PKV + hd)*PD + d))*PS + sq] = (bf16_t)y[j][r];
        }
      }
    } else {
      #pragma unroll
      for (int r = 0; r < 4; ++r) {
        int mg = m0 + wave*32 + qb*16 + hi4*4 + r;
        int b = mg >> 11, sq = mg & 2047;
        const float* cp = &cosp[(size_t)mg * PD];
        const float* sp = &sinp[(size_t)mg * PD];
        float z[4];
        #pragma unroll
        for (int j = 0; j < 4; ++j) {
          float c = cp[lo16 + 16*j], s = sp[lo16 + 16*j];
          float rot = (j & 1) ? y[j-1][r] : -y[j+1][r];
          z[j] = y[j][r] * c + rot * s;
        }
        #pragma unroll
        for (int j = 0; j < 4; ++j) {
          int d = lo16 + 16*j;
          bf16_t zh = (bf16_t)z[j];
          bf16_t zl = (bf16_t)(z[j] - (float)zh);
          if (kind == 0) {
            size_t idx = ((size_t)(b*PH + hd)*PS + sq)*PD + d;
            qh_o[idx] = zh; ql_o[idx] = zl;
          } else {
            size_t idx = ((size_t)(b*PKV + hd)*PS + sq)*PD + d;
            kh_o[idx] = zh; kl_o[idx] = zl;
          }
        }
      }
    }
  }
}

// ---------------------------------------------------------------------------
// Kernel 2: flash attention, swapped QK^T (3-term split product), kv-split x2.
// grid 1024 1D XCD-swizzled -> (qt 16, bh 32, ks 2). 4 waves x 32 q-rows.
// S^T = Kh·Qh + Kh·Ql + Kl·Qh. Softmax lane-local + 2 shuffles.
// Partial out: unnormalized O (bf16) + (m,l) float2 per row per split.
// ---------------------------------------------------------------------------
__global__ __launch_bounds__(256, 3)
void attn_kernel(const bf16_t* __restrict__ qh_g, const bf16_t* __restrict__ ql_g,
                 const bf16_t* __restrict__ kh_g, const bf16_t* __restrict__ kl_g,
                 const bf16_t* __restrict__ vt_g,
                 bf16_t* __restrict__ op, float2* __restrict__ ml)
{
  __shared__ __align__(16) bf16_t Ksh[64][72];   // K hi tile [kv][d]
  __shared__ __align__(16) bf16_t Ksl[64][72];   // K lo tile [kv][d]
  __shared__ __align__(16) bf16_t Vss[64][72];   // V^T tile [d][kv]
  __shared__ __align__(16) bf16_t Pss[128][72];  // P tile [q][kv]; epilogue O-bounce

  const int tid = threadIdx.x, lane = tid & 63, wave = tid >> 6;
  const int lo16 = lane & 15, hi4 = lane >> 4;
  const int lin = blockIdx.x;
  const int swz = (lin & 7) * 128 + (lin >> 3);  // XCD-cluster same-head blocks
  const int qt = swz & 15;
  const int bh = (swz >> 4) & 31;
  const int ks = swz >> 9;
  const int b = bh >> 4, h = bh & 15, kvh = h >> 1;  // GQA groups=2

  // Q fragments (B-operand): lane holds Q[q = base+lo16][d = t*32+hi4*8+e]
  bf16x8 qfh[2][2], qfl[2][2];
  #pragma unroll
  for (int qb = 0; qb < 2; ++qb) {
    const size_t qbase = ((size_t)(b*PH + h)*PS + qt*128 + wave*32 + qb*16 + lo16) * PD;
    #pragma unroll
    for (int t = 0; t < 2; ++t) {
      qfh[qb][t] = *(const bf16x8*)&qh_g[qbase + t*32 + hi4*8];
      qfl[qb][t] = *(const bf16x8*)&ql_g[qbase + t*32 + hi4*8];
    }
  }

  // o[qb][jd] = O^T[d = 16jd + hi4*4 + r][q = qb*16 + lo16], unnormalized
  f32x4 o[2][4];
  float mq[2] = {-1e30f, -1e30f}, lq[2] = {0.f, 0.f};
  #pragma unroll
  for (int qb = 0; qb < 2; ++qb)
    #pragma unroll
    for (int j = 0; j < 4; ++j) o[qb][j] = f32x4{0.f, 0.f, 0.f, 0.f};

  const int srow = tid >> 2, sc = (tid & 3) * 16;
  const size_t kbase = (size_t)(b*PKV + kvh) * PS * PD + (size_t)ks * 1024 * PD;
  const size_t vbase = (size_t)(b*PKV + kvh) * PD * PS + (size_t)ks * 1024;

  bf16x8 gk0, gk1, gl0, gl1, gv0, gv1;
  auto LOADT = [&](int kt) {
    const bf16_t* kp  = &kh_g[kbase + (size_t)(kt*64 + srow)*PD + sc];
    const bf16_t* klp = &kl_g[kbase + (size_t)(kt*64 + srow)*PD + sc];
    const bf16_t* vp  = &vt_g[vbase + (size_t)srow*PS + kt*64 + sc];
    gk0 = *(const bf16x8*)kp;   gk1 = *(const bf16x8*)(kp + 8);
    gl0 = *(const bf16x8*)klp;  gl1 = *(const bf16x8*)(klp + 8);
    gv0 = *(const bf16x8*)vp;   gv1 = *(const bf16x8*)(vp + 8);
  };
  LOADT(0);

  for (int kt = 0; kt < 16; ++kt) {
    __syncthreads();
    *(bf16x8*)&Ksh[srow][sc]     = gk0;
    *(bf16x8*)&Ksh[srow][sc + 8] = gk1;
    *(bf16x8*)&Ksl[srow][sc]     = gl0;
    *(bf16x8*)&Ksl[srow][sc + 8] = gl1;
    *(bf16x8*)&Vss[srow][sc]     = gv0;
    *(bf16x8*)&Vss[srow][sc + 8] = gv1;
    if (kt + 1 < 16) LOADT(kt + 1);
    __syncthreads();

    // QK^T swapped: sacc[qb][j][r] = S[kv = 16j + hi4*4 + r][q = qb*16 + lo16]
    f32x4 sacc[2][4];
    #pragma unroll
    for (int qb = 0; qb < 2; ++qb)
      #pragma unroll
      for (int j = 0; j < 4; ++j) sacc[qb][j] = f32x4{0.f, 0.f, 0.f, 0.f};
    #pragma unroll
    for (int j = 0; j < 4; ++j) {
      #pragma unroll
      for (int t = 0; t < 2; ++t) {
        bf16x8 kfh = *(const bf16x8*)&Ksh[j*16 + lo16][t*32 + hi4*8];
        bf16x8 kfl = *(const bf16x8*)&Ksl[j*16 + lo16][t*32 + hi4*8];
        #pragma unroll
        for (int qb = 0; qb < 2; ++qb) {
          sacc[qb][j] = MFMA16(kfh, qfh[qb][t], sacc[qb][j]);
          sacc[qb][j] = MFMA16(kfh, qfl[qb][t], sacc[qb][j]);
          sacc[qb][j] = MFMA16(kfl, qfh[qb][t], sacc[qb][j]);
        }
      }
    }

    // online softmax: lane-local over 16 kv + 2 shuffles across hi4 groups
    #pragma unroll
    for (int qb = 0; qb < 2; ++qb) {
      float tm = sacc[qb][0][0];
      #pragma unroll
      for (int j = 0; j < 4; ++j)
        #pragma unroll
        for (int r = 0; r < 4; ++r) tm = fmaxf(tm, sacc[qb][j][r]);
      tm = fmaxf(tm, __shfl_xor(tm, 16));
      tm = fmaxf(tm, __shfl_xor(tm, 32));
      float mnew = fmaxf(mq[qb], tm);
      float alpha = __expf(mq[qb] - mnew);
      float ls = 0.f;
      #pragma unroll
      for (int j = 0; j < 4; ++j)
        #pragma unroll
        for (int r = 0; r < 4; ++r) {
          float p = __expf(sacc[qb][j][r] - mnew);
          sacc[qb][j][r] = p;
          ls += p;
        }
      ls += __shfl_xor(ls, 16);
      ls += __shfl_xor(ls, 32);
      lq[qb] = lq[qb] * alpha + ls;
      mq[qb] = mnew;
      #pragma unroll
      for (int jd = 0; jd < 4; ++jd) o[qb][jd] *= alpha;
    }

    // P -> LDS as packed b32 (same-wave rows; in-wave DS ordering, no barrier)
    #pragma unroll
    for (int qb = 0; qb < 2; ++qb)
      #pragma unroll
      for (int j = 0; j < 4; ++j)
        #pragma unroll
        for (int rp = 0; rp < 2; ++rp)
          *(bf16x2*)&Pss[wave*32 + qb*16 + lo16][j*16 + hi4*4 + 2*rp] =
              bf16x2{(bf16_t)sacc[qb][j][2*rp], (bf16_t)sacc[qb][j][2*rp+1]};

    bf16x8 pa[2][2];
    #pragma unroll
    for (int qb = 0; qb < 2; ++qb)
      #pragma unroll
      for (int t = 0; t < 2; ++t)
        pa[qb][t] = *(const bf16x8*)&Pss[wave*32 + qb*16 + lo16][t*32 + hi4*8];

    // PV: O^T = V^T * P; A = V^T frag, B = P frag
    #pragma unroll
    for (int jd = 0; jd < 4; ++jd) {
      #pragma unroll
      for (int t = 0; t < 2; ++t) {
        bf16x8 vf = *(const bf16x8*)&Vss[jd*16 + lo16][t*32 + hi4*8];
        #pragma unroll
        for (int qb = 0; qb < 2; ++qb)
          o[qb][jd] = MFMA16(vf, pa[qb][t], o[qb][jd]);
      }
    }
  }

  // ---- epilogue: write (m,l) and unnormalized O (bf16) via LDS transpose ----
  const int rbase = bh*PS + qt*128 + wave*32;
  if (hi4 == 0) {
    #pragma unroll
    for (int qb = 0; qb < 2; ++qb)
      ml[(size_t)ks*PR + rbase + qb*16 + lo16] = float2{mq[qb], lq[qb]};
  }
  #pragma unroll
  for (int qb = 0; qb < 2; ++qb)
    #pragma unroll
    for (int jd = 0; jd < 4; ++jd)
      #pragma unroll
      for (int rp = 0; rp < 2; ++rp)
        *(bf16x2*)&Pss[wave*32 + qb*16 + lo16][jd*16 + hi4*4 + 2*rp] =
            bf16x2{(bf16_t)o[qb][jd][2*rp], (bf16_t)o[qb][jd][2*rp+1]};
  {
    const int row = lane >> 1, half = lane & 1;
    const size_t gb_ = ((size_t)ks*PR + rbase + row) * PD + half*32;
    #pragma unroll
    for (int c = 0; c < 4; ++c)
      *(bf16x8*)&op[gb_ + c*8] = *(const bf16x8*)&Pss[wave*32 + row][half*32 + c*8];
  }
}

// ---------------------------------------------------------------------------
// Kernel 3: merge the two kv-split partials -> ao [B,S,H*D] bf16.
// ---------------------------------------------------------------------------
__global__ __launch_bounds__(256)
void merge_kernel(const bf16_t* __restrict__ op, const float2* __restrict__ ml,
                  bf16_t* __restrict__ ao)
{
  const int gid = blockIdx.x * 256 + threadIdx.x;
  const int row = gid >> 3, oct = gid & 7;
  float2 e0 = ml[row], e1 = ml[PR + row];
  float M = fmaxf(e0.x, e1.x);
  float w0 = __expf(e0.x - M), w1 = __expf(e1.x - M);
  float inv = 1.0f / (w0 * e0.y + w1 * e1.y);
  bf16x8 a = *(const bf16x8*)&op[(size_t)row*PD + oct*8];
  bf16x8 bq = *(const bf16x8*)&op[(size_t)(PR + row)*PD + oct*8];
  bf16x8 r;
  #pragma unroll
  for (int i = 0; i < 8; ++i)
    r[i] = (bf16_t)((w0 * (float)a[i] + w1 * (float)bq[i]) * inv);
  const int bh = row >> 11, sq = row & 2047;
  const int b = bh >> 4, h = bh & 15;
  *(bf16x8*)&ao[((size_t)(b*PS + sq))*PHID + h*PD + oct*8] = r;
}

// ---------------------------------------------------------------------------
// Kernel 4: out-projection, bf16 GEMM -> fp32. grid 512 1D swizzled.
// ---------------------------------------------------------------------------
__global__ __launch_bounds__(256)
void oproj_kernel(const bf16_t* __restrict__ ao, const float* __restrict__ Wo,
                  float* __restrict__ out)
{
  __shared__ __align__(16) bf16_t As[128][40], Bs[64][40];
  const int tid = threadIdx.x;
  const int lane = tid & 63, wave = tid >> 6;
  const int lo16 = lane & 15, hi4 = lane >> 4;
  const int lin = blockIdx.x;
  const int swz = (lin & 7) * 64 + (lin >> 3);   // cluster row-tiles per XCD
  const int m0 = (swz >> 4) * 128;
  const int col0 = (swz & 15) * 64;

  f32x4 acc[2][4];
  #pragma unroll
  for (int qb = 0; qb < 2; ++qb)
    #pragma unroll
    for (int j = 0; j < 4; ++j) acc[qb][j] = f32x4{0.f, 0.f, 0.f, 0.f};

  const int ar = tid >> 1, akc = (tid & 1) * 16;
  const int bn = tid & 63, bkc = (tid >> 6) * 8;

  bf16x8 gA0, gA1;
  float  gb[8];
  auto LOADA = [&](int k0) {
    const bf16_t* ap = &ao[(size_t)(m0 + ar) * PHID + k0 + akc];
    gA0 = *(const bf16x8*)ap;
    gA1 = *(const bf16x8*)(ap + 8);
  };
  auto LOADB = [&](int k0) {
    const float* wp = &Wo[(size_t)(k0 + bkc) * PHID + col0 + bn];
    #pragma unroll
    for (int i = 0; i < 8; ++i) gb[i] = wp[(size_t)i * PHID];
  };
  LOADA(0); LOADB(0);

  for (int k0 = 0; k0 < PHID; k0 += 32) {
    __syncthreads();
    *(bf16x8*)&As[ar][akc]     = gA0;
    *(bf16x8*)&As[ar][akc + 8] = gA1;
    {
      bf16x8 bv;
      #pragma unroll
      for (int i = 0; i < 8; ++i) bv[i] = (bf16_t)gb[i];
      *(bf16x8*)&Bs[bn][bkc] = bv;
    }
    if (k0 + 32 < PHID) { LOADA(k0 + 32); LOADB(k0 + 32); }
    __syncthreads();
    {
      bf16x8 a[2];
      #pragma unroll
      for (int qb = 0; qb < 2; ++qb)
        a[qb] = *(const bf16x8*)&As[wave*32 + qb*16 + lo16][hi4*8];
      #pragma unroll
      for (int j = 0; j < 4; ++j) {
        bf16x8 bb = *(const bf16x8*)&Bs[j*16 + lo16][hi4*8];
        #pragma unroll
        for (int qb = 0; qb < 2; ++qb)
          acc[qb][j] = MFMA16(a[qb], bb, acc[qb][j]);
      }
    }
  }

  #pragma unroll
  for (int qb = 0; qb < 2; ++qb)
    #pragma unroll
    for (int r = 0; r < 4; ++r) {
      int mg = m0 + wave*32 + qb*16 + hi4*4 + r;
      #pragma unroll
      for (int j = 0; j < 4; ++j)
        out[(size_t)mg*PHID + col0 + lo16 + 16*j] = acc[qb][j][r];
    }
}

// ---------------------------------------------------------------------------
extern "C" void kernel_launch(void* const* d_in, const int* in_sizes, int n_in,
                              void* d_out, int out_size, void* d_ws, size_t ws_size,
                              hipStream_t stream) {
  (void)in_sizes; (void)n_in; (void)out_size; (void)ws_size;
  const float* hs   = (const float*)d_in[0];
  const float* cosp = (const float*)d_in[1];
  const float* sinp = (const float*)d_in[2];
  // d_in[3] position_ids: only shape[-1]=2 used (NDIM=2 hardcoded)
  const float* Wq   = (const float*)d_in[4];
  const float* Wk   = (const float*)d_in[5];
  const float* Wv   = (const float*)d_in[6];
  const float* Wo   = (const float*)d_in[7];
  const float* qnw  = (const float*)d_in[8];
  const float* knw  = (const float*)d_in[9];
  float* out = (float*)d_out;

  bf16_t* ws = (bf16_t*)d_ws;
  const size_t QN = (size_t)PB*PH*PS*PD;   // 4,194,304 (== PR*PD)
  const size_t KN = (size_t)PB*PKV*PS*PD;  // 2,097,152
  bf16_t* qh = ws;
  bf16_t* ql = qh + QN;
  bf16_t* kh = ql + QN;
  bf16_t* kl = kh + KN;
  bf16_t* vt = kl + KN;
  bf16_t* op = vt + KN;                    // 2 * QN bf16 (kv-split partials)
  float2* ml = (float2*)(op + 2*QN);       // 2 * PR float2
  bf16_t* ao = qh;  // alias: attn no longer needs Q once merge runs (stream-ordered)

  qkv_kernel<<<dim3(1024), 256, 0, stream>>>(hs, Wq, Wk, Wv, cosp, sinp,
                                             qnw, knw, qh, ql, kh, kl, vt);
  attn_kernel<<<dim3(1024), 256, 0, stream>>>(qh, ql, kh, kl, vt, op, ml);
  merge_kernel<<<dim3(PR*8/256), 256, 0, stream>>>(op, ml, ao);
  oproj_kernel<<<dim3(512), 256, 0, stream>>>(ao, Wo, out);
}

// Round 5
// 187.648 us; speedup vs baseline: 1.4980x; 1.0591x over previous
//
#include <hip/hip_runtime.h>

// Problem constants
#define PB 2
#define PS 2048
#define PHID 1024
#define PH 16
#define PKV 8
#define PD 64
#define PM (PB*PS)   // 4096
#define PR (PB*PH*PS) // 65536 q-rows total

typedef __bf16 bf16_t;
typedef __bf16 bf16x8 __attribute__((ext_vector_type(8)));
typedef __bf16 bf16x2 __attribute__((ext_vector_type(2)));
typedef float f32x4 __attribute__((ext_vector_type(4)));

#define MFMA16(a,b,c) __builtin_amdgcn_mfma_f32_16x16x32_bf16((a),(b),(c),0,0,0)

// global -> LDS direct copy, 16B per lane. LDS dest = wave-uniform base +
// lane*16 (HW rule); global src is per-lane (pre-swizzled there).
__device__ __forceinline__ void gl16(const bf16_t* g, bf16_t* l) {
  __builtin_amdgcn_global_load_lds(
      (const __attribute__((address_space(1))) void*)g,
      (__attribute__((address_space(3))) void*)l, 16, 0, 0);
}

// ---------------------------------------------------------------------------
// Kernel 0a: hs fp32 -> hi/lo bf16 (once, instead of 32x inside qkv).
// ---------------------------------------------------------------------------
__global__ __launch_bounds__(256)
void convert_hs(const float* __restrict__ hs,
                bf16_t* __restrict__ hh, bf16_t* __restrict__ hl)
{
  const size_t i = ((size_t)blockIdx.x * 256 + threadIdx.x) * 8;
  float4 a = *(const float4*)&hs[i];
  float4 b = *(const float4*)&hs[i + 4];
  float xs[8] = {a.x, a.y, a.z, a.w, b.x, b.y, b.z, b.w};
  bf16x8 hv, lv;
  #pragma unroll
  for (int j = 0; j < 8; ++j) {
    hv[j] = (bf16_t)xs[j];
    lv[j] = (bf16_t)(xs[j] - (float)hv[j]);
  }
  *(bf16x8*)&hh[i] = hv;
  *(bf16x8*)&hl[i] = lv;
}

// ---------------------------------------------------------------------------
// Kernel 0b: weights -> transposed [n][k] bf16. Rows: 0-1023 Wq^T (hi+lo),
// 1024-1535 Wk^T (hi+lo), 1536-2047 Wv^T (hi), 2048-3071 Wo^T (hi).
// grid 768 = 48 slots x 16 k-tiles; 64k x 64n tile via LDS transpose.
// ---------------------------------------------------------------------------
__global__ __launch_bounds__(256)
void convert_w(const float* __restrict__ Wq, const float* __restrict__ Wk,
               const float* __restrict__ Wv, const float* __restrict__ Wo,
               bf16_t* __restrict__ wt_h, bf16_t* __restrict__ wt_l)
{
  __shared__ float Tt[64][68];
  const int tid = threadIdx.x;
  const int slot = blockIdx.x >> 4, k0 = (blockIdx.x & 15) * 64;

  const float* src; int N, ncol0, orow0; bool wlo = true;
  if (slot < 16)      { src = Wq; N = 1024; ncol0 = slot*64;       orow0 = slot*64; }
  else if (slot < 24) { src = Wk; N = 512;  ncol0 = (slot-16)*64;  orow0 = 1024 + (slot-16)*64; }
  else if (slot < 32) { src = Wv; N = 512;  ncol0 = (slot-24)*64;  orow0 = 1536 + (slot-24)*64; wlo = false; }
  else                { src = Wo; N = 1024; ncol0 = (slot-32)*64;  orow0 = 2048 + (slot-32)*64; wlo = false; }

  const int tk = tid >> 6, tn = tid & 63;
  #pragma unroll
  for (int i = 0; i < 16; ++i)
    Tt[tn][tk*16 + i] = src[(size_t)(k0 + tk*16 + i) * N + ncol0 + tn];
  __syncthreads();

  const int n = tid >> 2, kc = (tid & 3) * 16;
  float vv[16];
  #pragma unroll
  for (int i = 0; i < 16; ++i) vv[i] = Tt[n][kc + i];
  bf16x8 h0, h1, l0, l1;
  #pragma unroll
  for (int i = 0; i < 8; ++i) {
    h0[i] = (bf16_t)vv[i];       l0[i] = (bf16_t)(vv[i]   - (float)h0[i]);
    h1[i] = (bf16_t)vv[i+8];     l1[i] = (bf16_t)(vv[i+8] - (float)h1[i]);
  }
  const size_t ob = (size_t)(orow0 + n) * 1024 + k0 + kc;
  *(bf16x8*)&wt_h[ob]     = h0;
  *(bf16x8*)&wt_h[ob + 8] = h1;
  if (wlo) {
    *(bf16x8*)&wt_l[ob]     = l0;
    *(bf16x8*)&wt_l[ob + 8] = l1;
  }
}

// ---------------------------------------------------------------------------
// Kernel 1: QKV projection GEMM (all-bf16 inputs) + RMSNorm + RoPE epilogue.
// BK=64, global_load_lds staging with XOR swizzle (chunk ^= row&7 at 16B
// granularity; pre-swizzled global source + swizzled ds_read, linear dest).
// grid: 1024 1D XCD-swizzled = 32 row-tiles x 32 slots.
// ---------------------------------------------------------------------------
__global__ __launch_bounds__(256)
void qkv_kernel(const bf16_t* __restrict__ hsh, const bf16_t* __restrict__ hsl,
                const bf16_t* __restrict__ wth, const bf16_t* __restrict__ wtl,
                const float* __restrict__ cosp, const float* __restrict__ sinp,
                const float* __restrict__ qnw, const float* __restrict__ knw,
                bf16_t* __restrict__ qh_o, bf16_t* __restrict__ ql_o,
                bf16_t* __restrict__ kh_o, bf16_t* __restrict__ kl_o,
                bf16_t* __restrict__ vt_o)
{
  __shared__ __align__(16) bf16_t Ah[128][64], Al[128][64];  // 16 KB each
  __shared__ __align__(16) bf16_t Bh[64][64],  Bl[64][64];   // 8 KB each

  const int tid = threadIdx.x;
  const int lane = tid & 63, wave = tid >> 6;
  const int lo16 = lane & 15, hi4 = lane >> 4;
  const int lin = blockIdx.x;
  const int swz = (lin & 7) * 128 + (lin >> 3);
  const int m0 = (swz >> 5) * 128;
  const int slot = swz & 31;

  int kind, hd, orow;
  if (slot < 16)      { kind = 0; hd = slot;      orow = slot*64; }
  else if (slot < 24) { kind = 1; hd = slot - 16; orow = 1024 + hd*64; }
  else                { kind = 2; hd = slot - 24; orow = 1536 + hd*64; }
  const bool isV = (kind == 2);

  f32x4 acc[2][4];
  #pragma unroll
  for (int qb = 0; qb < 2; ++qb)
    #pragma unroll
    for (int j = 0; j < 4; ++j) acc[qb][j] = f32x4{0.f, 0.f, 0.f, 0.f};

  // staging geometry: each wave-issue covers 8 rows x 128B; lane -> (row ri,
  // phys chunk pc). logical chunk = pc ^ ri (row&7 == ri since bases %8==0).
  const int ri = lane >> 3, pc = lane & 7;
  const int lcs = ((pc ^ ri) * 8);   // element offset of logical chunk
  size_t aoff[4]; bf16_t* aldst[4];
  #pragma unroll
  for (int q = 0; q < 4; ++q) {
    aoff[q] = (size_t)(m0 + wave*32 + q*8 + ri) * PHID + lcs;
    aldst[q] = &Ah[wave*32 + q*8][0];
  }
  size_t boff[2]; int brow[2];
  #pragma unroll
  for (int q = 0; q < 2; ++q) {
    brow[q] = wave*16 + q*8;
    boff[q] = (size_t)(orow + brow[q] + ri) * 1024 + lcs;
  }

  const int rsw = lo16 & 7;  // read-side swizzle key (row & 7)

  for (int k0 = 0; k0 < PHID; k0 += 64) {
    __syncthreads();   // previous compute done reading LDS
    #pragma unroll
    for (int q = 0; q < 4; ++q) gl16(hsh + aoff[q] + k0, aldst[q]);
    #pragma unroll
    for (int q = 0; q < 2; ++q) gl16(wth + boff[q] + k0, &Bh[brow[q]][0]);
    if (!isV) {
      #pragma unroll
      for (int q = 0; q < 4; ++q) gl16(hsl + aoff[q] + k0, &Al[wave*32 + q*8][0]);
      #pragma unroll
      for (int q = 0; q < 2; ++q) gl16(wtl + boff[q] + k0, &Bl[brow[q]][0]);
    }
    __syncthreads();   // drains vmcnt before any wave reads

    #pragma unroll
    for (int t = 0; t < 2; ++t) {
      const int ccol = ((t*4 + hi4) ^ rsw) * 8;
      bf16x8 ah[2], al2[2];
      #pragma unroll
      for (int qb = 0; qb < 2; ++qb) {
        ah[qb] = *(const bf16x8*)&Ah[wave*32 + qb*16 + lo16][ccol];
        if (!isV) al2[qb] = *(const bf16x8*)&Al[wave*32 + qb*16 + lo16][ccol];
      }
      #pragma unroll
      for (int j = 0; j < 4; ++j) {
        bf16x8 bh = *(const bf16x8*)&Bh[j*16 + lo16][ccol];
        if (!isV) {
          bf16x8 bl = *(const bf16x8*)&Bl[j*16 + lo16][ccol];
          #pragma unroll
          for (int qb = 0; qb < 2; ++qb) {
            acc[qb][j] = MFMA16(ah[qb],  bh, acc[qb][j]);
            acc[qb][j] = MFMA16(al2[qb], bh, acc[qb][j]);
            acc[qb][j] = MFMA16(ah[qb],  bl, acc[qb][j]);
          }
        } else {
          #pragma unroll
          for (int qb = 0; qb < 2; ++qb)
            acc[qb][j] = MFMA16(ah[qb], bh, acc[qb][j]);
        }
      }
    }
  }

  // ---- epilogue: RMSNorm + RoPE / V-transpose stores (unchanged) ----
  #pragma unroll
  for (int qb = 0; qb < 2; ++qb) {
    float scale[4];
    #pragma unroll
    for (int r = 0; r < 4; ++r) {
      float s = 0.f;
      #pragma unroll
      for (int j = 0; j < 4; ++j) s += acc[qb][j][r] * acc[qb][j][r];
      #pragma unroll
      for (int m = 1; m < 16; m <<= 1) s += __shfl_xor(s, m);
      scale[r] = 1.0f / sqrtf(s * (1.0f/64.0f) + 1e-6f);
    }
    float nw[4];
    #pragma unroll
    for (int j = 0; j < 4; ++j)
      nw[j] = (kind == 0) ? qnw[lo16 + 16*j] : (kind == 1 ? knw[lo16 + 16*j] : 1.0f);

    float y[4][4];
    #pragma unroll
    for (int j = 0; j < 4; ++j)
      #pragma unroll
      for (int r = 0; r < 4; ++r) y[j][r] = acc[qb][j][r] * scale[r] * nw[j];

    if (kind == 2) {
      #pragma unroll
      for (int r = 0; r < 4; ++r) {
        int mg = m0 + wave*32 + qb*16 + hi4*4 + r;
        int b = mg >> 11, sq = mg & 2047;
        #pragma unroll
        for (int j = 0; j < 4; ++j) {
          int d = lo16 + 16*j;
          vt_o[((size_t)((b*PKV + hd)*PD + d))*PS + sq] = (bf16_t)y[j][r];
        }
      }
    } else {
      #pragma unroll
      for (int r = 0; r < 4; ++r) {
        int mg = m0 + wave*32 + qb*16 + hi4*4 + r;
        int b = mg >> 11, sq = mg & 2047;
        const float* cp = &cosp[(size_t)mg * PD];
        const float* sp = &sinp[(size_t)mg * PD];
        float z[4];
        #pragma unroll
        for (int j = 0; j < 4; ++j) {
          float c = cp[lo16 + 16*j], s = sp[lo16 + 16*j];
          float rot = (j & 1) ? y[j-1][r] : -y[j+1][r];
          z[j] = y[j][r] * c + rot * s;
        }
        #pragma unroll
        for (int j = 0; j < 4; ++j) {
          int d = lo16 + 16*j;
          bf16_t zh = (bf16_t)z[j];
          bf16_t zl = (bf16_t)(z[j] - (float)zh);
          if (kind == 0) {
            size_t idx = ((size_t)(b*PH + hd)*PS + sq)*PD + d;
            qh_o[idx] = zh; ql_o[idx] = zl;
          } else {
            size_t idx = ((size_t)(b*PKV + hd)*PS + sq)*PD + d;
            kh_o[idx] = zh; kl_o[idx] = zl;
          }
        }
      }
    }
  }
}

// ---------------------------------------------------------------------------
// Kernel 2: flash attention, swapped QK^T (3-term split product), kv-split x2.
// (unchanged from round 4 — passed at absmax 0.0156)
// ---------------------------------------------------------------------------
__global__ __launch_bounds__(256, 3)
void attn_kernel(const bf16_t* __restrict__ qh_g, const bf16_t* __restrict__ ql_g,
                 const bf16_t* __restrict__ kh_g, const bf16_t* __restrict__ kl_g,
                 const bf16_t* __restrict__ vt_g,
                 bf16_t* __restrict__ op, float2* __restrict__ ml)
{
  __shared__ __align__(16) bf16_t Ksh[64][72];
  __shared__ __align__(16) bf16_t Ksl[64][72];
  __shared__ __align__(16) bf16_t Vss[64][72];
  __shared__ __align__(16) bf16_t Pss[128][72];

  const int tid = threadIdx.x, lane = tid & 63, wave = tid >> 6;
  const int lo16 = lane & 15, hi4 = lane >> 4;
  const int lin = blockIdx.x;
  const int swz = (lin & 7) * 128 + (lin >> 3);
  const int qt = swz & 15;
  const int bh = (swz >> 4) & 31;
  const int ks = swz >> 9;
  const int b = bh >> 4, h = bh & 15, kvh = h >> 1;

  bf16x8 qfh[2][2], qfl[2][2];
  #pragma unroll
  for (int qb = 0; qb < 2; ++qb) {
    const size_t qbase = ((size_t)(b*PH + h)*PS + qt*128 + wave*32 + qb*16 + lo16) * PD;
    #pragma unroll
    for (int t = 0; t < 2; ++t) {
      qfh[qb][t] = *(const bf16x8*)&qh_g[qbase + t*32 + hi4*8];
      qfl[qb][t] = *(const bf16x8*)&ql_g[qbase + t*32 + hi4*8];
    }
  }

  f32x4 o[2][4];
  float mq[2] = {-1e30f, -1e30f}, lq[2] = {0.f, 0.f};
  #pragma unroll
  for (int qb = 0; qb < 2; ++qb)
    #pragma unroll
    for (int j = 0; j < 4; ++j) o[qb][j] = f32x4{0.f, 0.f, 0.f, 0.f};

  const int srow = tid >> 2, sc = (tid & 3) * 16;
  const size_t kbase = (size_t)(b*PKV + kvh) * PS * PD + (size_t)ks * 1024 * PD;
  const size_t vbase = (size_t)(b*PKV + kvh) * PD * PS + (size_t)ks * 1024;

  bf16x8 gk0, gk1, gl0, gl1, gv0, gv1;
  auto LOADT = [&](int kt) {
    const bf16_t* kp  = &kh_g[kbase + (size_t)(kt*64 + srow)*PD + sc];
    const bf16_t* klp = &kl_g[kbase + (size_t)(kt*64 + srow)*PD + sc];
    const bf16_t* vp  = &vt_g[vbase + (size_t)srow*PS + kt*64 + sc];
    gk0 = *(const bf16x8*)kp;   gk1 = *(const bf16x8*)(kp + 8);
    gl0 = *(const bf16x8*)klp;  gl1 = *(const bf16x8*)(klp + 8);
    gv0 = *(const bf16x8*)vp;   gv1 = *(const bf16x8*)(vp + 8);
  };
  LOADT(0);

  for (int kt = 0; kt < 16; ++kt) {
    __syncthreads();
    *(bf16x8*)&Ksh[srow][sc]     = gk0;
    *(bf16x8*)&Ksh[srow][sc + 8] = gk1;
    *(bf16x8*)&Ksl[srow][sc]     = gl0;
    *(bf16x8*)&Ksl[srow][sc + 8] = gl1;
    *(bf16x8*)&Vss[srow][sc]     = gv0;
    *(bf16x8*)&Vss[srow][sc + 8] = gv1;
    if (kt + 1 < 16) LOADT(kt + 1);
    __syncthreads();

    f32x4 sacc[2][4];
    #pragma unroll
    for (int qb = 0; qb < 2; ++qb)
      #pragma unroll
      for (int j = 0; j < 4; ++j) sacc[qb][j] = f32x4{0.f, 0.f, 0.f, 0.f};
    #pragma unroll
    for (int j = 0; j < 4; ++j) {
      #pragma unroll
      for (int t = 0; t < 2; ++t) {
        bf16x8 kfh = *(const bf16x8*)&Ksh[j*16 + lo16][t*32 + hi4*8];
        bf16x8 kfl = *(const bf16x8*)&Ksl[j*16 + lo16][t*32 + hi4*8];
        #pragma unroll
        for (int qb = 0; qb < 2; ++qb) {
          sacc[qb][j] = MFMA16(kfh, qfh[qb][t], sacc[qb][j]);
          sacc[qb][j] = MFMA16(kfh, qfl[qb][t], sacc[qb][j]);
          sacc[qb][j] = MFMA16(kfl, qfh[qb][t], sacc[qb][j]);
        }
      }
    }

    #pragma unroll
    for (int qb = 0; qb < 2; ++qb) {
      float tm = sacc[qb][0][0];
      #pragma unroll
      for (int j = 0; j < 4; ++j)
        #pragma unroll
        for (int r = 0; r < 4; ++r) tm = fmaxf(tm, sacc[qb][j][r]);
      tm = fmaxf(tm, __shfl_xor(tm, 16));
      tm = fmaxf(tm, __shfl_xor(tm, 32));
      float mnew = fmaxf(mq[qb], tm);
      float alpha = __expf(mq[qb] - mnew);
      float ls = 0.f;
      #pragma unroll
      for (int j = 0; j < 4; ++j)
        #pragma unroll
        for (int r = 0; r < 4; ++r) {
          float p = __expf(sacc[qb][j][r] - mnew);
          sacc[qb][j][r] = p;
          ls += p;
        }
      ls += __shfl_xor(ls, 16);
      ls += __shfl_xor(ls, 32);
      lq[qb] = lq[qb] * alpha + ls;
      mq[qb] = mnew;
      #pragma unroll
      for (int jd = 0; jd < 4; ++jd) o[qb][jd] *= alpha;
    }

    #pragma unroll
    for (int qb = 0; qb < 2; ++qb)
      #pragma unroll
      for (int j = 0; j < 4; ++j)
        #pragma unroll
        for (int rp = 0; rp < 2; ++rp)
          *(bf16x2*)&Pss[wave*32 + qb*16 + lo16][j*16 + hi4*4 + 2*rp] =
              bf16x2{(bf16_t)sacc[qb][j][2*rp], (bf16_t)sacc[qb][j][2*rp+1]};

    bf16x8 pa[2][2];
    #pragma unroll
    for (int qb = 0; qb < 2; ++qb)
      #pragma unroll
      for (int t = 0; t < 2; ++t)
        pa[qb][t] = *(const bf16x8*)&Pss[wave*32 + qb*16 + lo16][t*32 + hi4*8];

    #pragma unroll
    for (int jd = 0; jd < 4; ++jd) {
      #pragma unroll
      for (int t = 0; t < 2; ++t) {
        bf16x8 vf = *(const bf16x8*)&Vss[jd*16 + lo16][t*32 + hi4*8];
        #pragma unroll
        for (int qb = 0; qb < 2; ++qb)
          o[qb][jd] = MFMA16(vf, pa[qb][t], o[qb][jd]);
      }
    }
  }

  const int rbase = bh*PS + qt*128 + wave*32;
  if (hi4 == 0) {
    #pragma unroll
    for (int qb = 0; qb < 2; ++qb)
      ml[(size_t)ks*PR + rbase + qb*16 + lo16] = float2{mq[qb], lq[qb]};
  }
  #pragma unroll
  for (int qb = 0; qb < 2; ++qb)
    #pragma unroll
    for (int jd = 0; jd < 4; ++jd)
      #pragma unroll
      for (int rp = 0; rp < 2; ++rp)
        *(bf16x2*)&Pss[wave*32 + qb*16 + lo16][jd*16 + hi4*4 + 2*rp] =
            bf16x2{(bf16_t)o[qb][jd][2*rp], (bf16_t)o[qb][jd][2*rp+1]};
  {
    const int row = lane >> 1, half = lane & 1;
    const size_t gb_ = ((size_t)ks*PR + rbase + row) * PD + half*32;
    #pragma unroll
    for (int c = 0; c < 4; ++c)
      *(bf16x8*)&op[gb_ + c*8] = *(const bf16x8*)&Pss[wave*32 + row][half*32 + c*8];
  }
}

// ---------------------------------------------------------------------------
// Kernel 3: merge kv-split partials -> ao [B,S,H*D] bf16. (unchanged)
// ---------------------------------------------------------------------------
__global__ __launch_bounds__(256)
void merge_kernel(const bf16_t* __restrict__ op, const float2* __restrict__ ml,
                  bf16_t* __restrict__ ao)
{
  const int gid = blockIdx.x * 256 + threadIdx.x;
  const int row = gid >> 3, oct = gid & 7;
  float2 e0 = ml[row], e1 = ml[PR + row];
  float M = fmaxf(e0.x, e1.x);
  float w0 = __expf(e0.x - M), w1 = __expf(e1.x - M);
  float inv = 1.0f / (w0 * e0.y + w1 * e1.y);
  bf16x8 a = *(const bf16x8*)&op[(size_t)row*PD + oct*8];
  bf16x8 bq = *(const bf16x8*)&op[(size_t)(PR + row)*PD + oct*8];
  bf16x8 r;
  #pragma unroll
  for (int i = 0; i < 8; ++i)
    r[i] = (bf16_t)((w0 * (float)a[i] + w1 * (float)bq[i]) * inv);
  const int bh = row >> 11, sq = row & 2047;
  const int b = bh >> 4, h = bh & 15;
  *(bf16x8*)&ao[((size_t)(b*PS + sq))*PHID + h*PD + oct*8] = r;
}

// ---------------------------------------------------------------------------
// Kernel 4: out-projection, bf16 GEMM (pre-converted WoT) -> fp32.
// ---------------------------------------------------------------------------
__global__ __launch_bounds__(256)
void oproj_kernel(const bf16_t* __restrict__ ao, const bf16_t* __restrict__ woT,
                  float* __restrict__ out)
{
  __shared__ __align__(16) bf16_t As[128][40], Bs[64][40];
  const int tid = threadIdx.x;
  const int lane = tid & 63, wave = tid >> 6;
  const int lo16 = lane & 15, hi4 = lane >> 4;
  const int lin = blockIdx.x;
  const int swz = (lin & 7) * 64 + (lin >> 3);
  const int m0 = (swz >> 4) * 128;
  const int col0 = (swz & 15) * 64;

  f32x4 acc[2][4];
  #pragma unroll
  for (int qb = 0; qb < 2; ++qb)
    #pragma unroll
    for (int j = 0; j < 4; ++j) acc[qb][j] = f32x4{0.f, 0.f, 0.f, 0.f};

  const int ar = tid >> 1, akc = (tid & 1) * 16;
  const int bn = tid & 63, bkc = (tid >> 6) * 8;

  bf16x8 gA0, gA1, gB;
  auto LOADA = [&](int k0) {
    const bf16_t* ap = &ao[(size_t)(m0 + ar) * PHID + k0 + akc];
    gA0 = *(const bf16x8*)ap;
    gA1 = *(const bf16x8*)(ap + 8);
  };
  auto LOADB = [&](int k0) {
    gB = *(const bf16x8*)&woT[(size_t)(col0 + bn) * 1024 + k0 + bkc];
  };
  LOADA(0); LOADB(0);

  for (int k0 = 0; k0 < PHID; k0 += 32) {
    __syncthreads();
    *(bf16x8*)&As[ar][akc]     = gA0;
    *(bf16x8*)&As[ar][akc + 8] = gA1;
    *(bf16x8*)&Bs[bn][bkc]     = gB;
    if (k0 + 32 < PHID) { LOADA(k0 + 32); LOADB(k0 + 32); }
    __syncthreads();
    {
      bf16x8 a[2];
      #pragma unroll
      for (int qb = 0; qb < 2; ++qb)
        a[qb] = *(const bf16x8*)&As[wave*32 + qb*16 + lo16][hi4*8];
      #pragma unroll
      for (int j = 0; j < 4; ++j) {
        bf16x8 bb = *(const bf16x8*)&Bs[j*16 + lo16][hi4*8];
        #pragma unroll
        for (int qb = 0; qb < 2; ++qb)
          acc[qb][j] = MFMA16(a[qb], bb, acc[qb][j]);
      }
    }
  }

  #pragma unroll
  for (int qb = 0; qb < 2; ++qb)
    #pragma unroll
    for (int r = 0; r < 4; ++r) {
      int mg = m0 + wave*32 + qb*16 + hi4*4 + r;
      #pragma unroll
      for (int j = 0; j < 4; ++j)
        out[(size_t)mg*PHID + col0 + lo16 + 16*j] = acc[qb][j][r];
    }
}

// ---------------------------------------------------------------------------
extern "C" void kernel_launch(void* const* d_in, const int* in_sizes, int n_in,
                              void* d_out, int out_size, void* d_ws, size_t ws_size,
                              hipStream_t stream) {
  (void)in_sizes; (void)n_in; (void)out_size; (void)ws_size;
  const float* hs   = (const float*)d_in[0];
  const float* cosp = (const float*)d_in[1];
  const float* sinp = (const float*)d_in[2];
  // d_in[3] position_ids: only shape[-1]=2 used (NDIM=2 hardcoded)
  const float* Wq   = (const float*)d_in[4];
  const float* Wk   = (const float*)d_in[5];
  const float* Wv   = (const float*)d_in[6];
  const float* Wo   = (const float*)d_in[7];
  const float* qnw  = (const float*)d_in[8];
  const float* knw  = (const float*)d_in[9];
  float* out = (float*)d_out;

  bf16_t* ws = (bf16_t*)d_ws;
  const size_t QN = (size_t)PB*PH*PS*PD;    // 4,194,304 (== PR*PD)
  const size_t KN = (size_t)PB*PKV*PS*PD;   // 2,097,152
  const size_t HN = (size_t)PM*PHID;        // 4,194,304
  bf16_t* qh  = ws;                 // 8 MB
  bf16_t* ql  = qh + QN;            // 8 MB
  bf16_t* kh  = ql + QN;            // 4 MB
  bf16_t* kl  = kh + KN;            // 4 MB
  bf16_t* vt  = kl + KN;            // 4 MB
  bf16_t* hsh = vt + KN;            // 8 MB   (dead after qkv)
  bf16_t* hsl = hsh + HN;           // 8 MB   (dead after qkv)
  bf16_t* wth = hsl + HN;           // 6 MB   (rows 2048+ = WoT, live to oproj)
  bf16_t* wtl = wth + (size_t)3072*1024;  // 4 MB (dead after qkv)
  // aliases (stream-ordered reuse):
  bf16_t* op  = hsh;                          // 16 MB (== hsh+hsl exactly)
  float2* ml  = (float2*)wtl;                 // 1 MB into wtl
  bf16_t* ao  = qh;                           // attn done with Q before merge
  const bf16_t* woT = wth + (size_t)2048*1024;

  convert_hs<<<dim3(2048), 256, 0, stream>>>(hs, hsh, hsl);
  convert_w <<<dim3(768),  256, 0, stream>>>(Wq, Wk, Wv, Wo, wth, wtl);
  qkv_kernel<<<dim3(1024), 256, 0, stream>>>(hsh, hsl, wth, wtl, cosp, sinp,
                                             qnw, knw, qh, ql, kh, kl, vt);
  attn_kernel<<<dim3(1024), 256, 0, stream>>>(qh, ql, kh, kl, vt, op, ml);
  merge_kernel<<<dim3(PR*8/256), 256, 0, stream>>>(op, ml, ao);
  oproj_kernel<<<dim3(512), 256, 0, stream>>>(ao, woT, out);
}

// Round 6
// 157.309 us; speedup vs baseline: 1.7869x; 1.1929x over previous
//
#include <hip/hip_runtime.h>

// Problem constants
#define PB 2
#define PS 2048
#define PHID 1024
#define PH 16
#define PKV 8
#define PD 64
#define PM (PB*PS)    // 4096
#define PR (PB*PH*PS) // 65536 q-rows total

typedef __bf16 bf16_t;
typedef __bf16 bf16x8 __attribute__((ext_vector_type(8)));
typedef _Float16 f16_t;
typedef _Float16 f16x8 __attribute__((ext_vector_type(8)));
typedef _Float16 f16x2 __attribute__((ext_vector_type(2)));
typedef float f32x4 __attribute__((ext_vector_type(4)));

#define MFMA16(a,b,c) __builtin_amdgcn_mfma_f32_16x16x32_bf16((a),(b),(c),0,0,0)
#define MFMAH(a,b,c)  __builtin_amdgcn_mfma_f32_16x16x32_f16((a),(b),(c),0,0,0)
#define LOG2E 1.44269504f

// global -> LDS direct copy, 16B per lane.
__device__ __forceinline__ void gl16(const bf16_t* g, bf16_t* l) {
  __builtin_amdgcn_global_load_lds(
      (const __attribute__((address_space(1))) void*)g,
      (__attribute__((address_space(3))) void*)l, 16, 0, 0);
}

// ---------------------------------------------------------------------------
// Kernel 0a: hs fp32 -> hi/lo bf16 (once).
// ---------------------------------------------------------------------------
__global__ __launch_bounds__(256)
void convert_hs(const float* __restrict__ hs,
                bf16_t* __restrict__ hh, bf16_t* __restrict__ hl)
{
  const size_t i = ((size_t)blockIdx.x * 256 + threadIdx.x) * 8;
  float4 a = *(const float4*)&hs[i];
  float4 b = *(const float4*)&hs[i + 4];
  float xs[8] = {a.x, a.y, a.z, a.w, b.x, b.y, b.z, b.w};
  bf16x8 hv, lv;
  #pragma unroll
  for (int j = 0; j < 8; ++j) {
    hv[j] = (bf16_t)xs[j];
    lv[j] = (bf16_t)(xs[j] - (float)hv[j]);
  }
  *(bf16x8*)&hh[i] = hv;
  *(bf16x8*)&hl[i] = lv;
}

// ---------------------------------------------------------------------------
// Kernel 0b: weights -> transposed [n][k]. wt_h bf16: rows 0-1023 Wq^T hi,
// 1024-1535 Wk^T hi, 1536-2047 Wv^T hi. wt_l bf16: Wq^T/Wk^T lo (1536 rows).
// woT fp16: Wo^T (1024 rows). grid 768 = 48 slots x 16 k-tiles.
// ---------------------------------------------------------------------------
__global__ __launch_bounds__(256)
void convert_w(const float* __restrict__ Wq, const float* __restrict__ Wk,
               const float* __restrict__ Wv, const float* __restrict__ Wo,
               bf16_t* __restrict__ wt_h, bf16_t* __restrict__ wt_l,
               f16_t* __restrict__ woT)
{
  __shared__ float Tt[64][68];
  const int tid = threadIdx.x;
  const int slot = blockIdx.x >> 4, k0 = (blockIdx.x & 15) * 64;

  const float* src; int N, ncol0;
  if (slot < 16)      { src = Wq; N = 1024; ncol0 = slot*64; }
  else if (slot < 24) { src = Wk; N = 512;  ncol0 = (slot-16)*64; }
  else if (slot < 32) { src = Wv; N = 512;  ncol0 = (slot-24)*64; }
  else                { src = Wo; N = 1024; ncol0 = (slot-32)*64; }

  const int tk = tid >> 6, tn = tid & 63;
  #pragma unroll
  for (int i = 0; i < 16; ++i)
    Tt[tn][tk*16 + i] = src[(size_t)(k0 + tk*16 + i) * N + ncol0 + tn];
  __syncthreads();

  const int n = tid >> 2, kc = (tid & 3) * 16;
  float vv[16];
  #pragma unroll
  for (int i = 0; i < 16; ++i) vv[i] = Tt[n][kc + i];

  if (slot < 32) {
    const int orow0 = (slot < 16) ? slot*64
                    : (slot < 24) ? 1024 + (slot-16)*64
                                  : 1536 + (slot-24)*64;
    bf16x8 h0, h1, l0, l1;
    #pragma unroll
    for (int i = 0; i < 8; ++i) {
      h0[i] = (bf16_t)vv[i];    l0[i] = (bf16_t)(vv[i]   - (float)h0[i]);
      h1[i] = (bf16_t)vv[i+8];  l1[i] = (bf16_t)(vv[i+8] - (float)h1[i]);
    }
    const size_t ob = (size_t)(orow0 + n) * 1024 + k0 + kc;
    *(bf16x8*)&wt_h[ob]     = h0;
    *(bf16x8*)&wt_h[ob + 8] = h1;
    if (slot < 24) {
      *(bf16x8*)&wt_l[ob]     = l0;
      *(bf16x8*)&wt_l[ob + 8] = l1;
    }
  } else {
    f16x8 a0, a1;
    #pragma unroll
    for (int i = 0; i < 8; ++i) {
      a0[i] = (f16_t)vv[i];
      a1[i] = (f16_t)vv[i+8];
    }
    const size_t ob = (size_t)((slot-32)*64 + n) * 1024 + k0 + kc;
    *(f16x8*)&woT[ob]     = a0;
    *(f16x8*)&woT[ob + 8] = a1;
  }
}

// ---------------------------------------------------------------------------
// Kernel 1: QKV projection (split-bf16 3-term GEMM, 2^-16-grade) + RMSNorm +
// RoPE epilogue; outputs fp16 (Q pre-scaled by log2e for exp2-domain softmax).
// BK=64, global_load_lds + XOR-swizzled read. grid 1024 XCD-swizzled.
// ---------------------------------------------------------------------------
__global__ __launch_bounds__(256)
void qkv_kernel(const bf16_t* __restrict__ hsh, const bf16_t* __restrict__ hsl,
                const bf16_t* __restrict__ wth, const bf16_t* __restrict__ wtl,
                const float* __restrict__ cosp, const float* __restrict__ sinp,
                const float* __restrict__ qnw, const float* __restrict__ knw,
                f16_t* __restrict__ q_o, f16_t* __restrict__ k_o,
                f16_t* __restrict__ vt_o)
{
  __shared__ __align__(16) bf16_t Ah[128][64], Al[128][64];
  __shared__ __align__(16) bf16_t Bh[64][64],  Bl[64][64];

  const int tid = threadIdx.x;
  const int lane = tid & 63, wave = tid >> 6;
  const int lo16 = lane & 15, hi4 = lane >> 4;
  const int lin = blockIdx.x;
  const int swz = (lin & 7) * 128 + (lin >> 3);
  const int m0 = (swz >> 5) * 128;
  const int slot = swz & 31;

  int kind, hd, orow;
  if (slot < 16)      { kind = 0; hd = slot;      orow = slot*64; }
  else if (slot < 24) { kind = 1; hd = slot - 16; orow = 1024 + hd*64; }
  else                { kind = 2; hd = slot - 24; orow = 1536 + hd*64; }
  const bool isV = (kind == 2);

  f32x4 acc[2][4];
  #pragma unroll
  for (int qb = 0; qb < 2; ++qb)
    #pragma unroll
    for (int j = 0; j < 4; ++j) acc[qb][j] = f32x4{0.f, 0.f, 0.f, 0.f};

  const int ri = lane >> 3, pc = lane & 7;
  const int lcs = ((pc ^ ri) * 8);
  size_t aoff[4]; bf16_t* aldst[4];
  #pragma unroll
  for (int q = 0; q < 4; ++q) {
    aoff[q] = (size_t)(m0 + wave*32 + q*8 + ri) * PHID + lcs;
    aldst[q] = &Ah[wave*32 + q*8][0];
  }
  size_t boff[2]; int brow[2];
  #pragma unroll
  for (int q = 0; q < 2; ++q) {
    brow[q] = wave*16 + q*8;
    boff[q] = (size_t)(orow + brow[q] + ri) * 1024 + lcs;
  }

  const int rsw = lo16 & 7;

  for (int k0 = 0; k0 < PHID; k0 += 64) {
    __syncthreads();
    #pragma unroll
    for (int q = 0; q < 4; ++q) gl16(hsh + aoff[q] + k0, aldst[q]);
    #pragma unroll
    for (int q = 0; q < 2; ++q) gl16(wth + boff[q] + k0, &Bh[brow[q]][0]);
    if (!isV) {
      #pragma unroll
      for (int q = 0; q < 4; ++q) gl16(hsl + aoff[q] + k0, &Al[wave*32 + q*8][0]);
      #pragma unroll
      for (int q = 0; q < 2; ++q) gl16(wtl + boff[q] + k0, &Bl[brow[q]][0]);
    }
    __syncthreads();

    #pragma unroll
    for (int t = 0; t < 2; ++t) {
      const int ccol = ((t*4 + hi4) ^ rsw) * 8;
      bf16x8 ah[2], al2[2];
      #pragma unroll
      for (int qb = 0; qb < 2; ++qb) {
        ah[qb] = *(const bf16x8*)&Ah[wave*32 + qb*16 + lo16][ccol];
        if (!isV) al2[qb] = *(const bf16x8*)&Al[wave*32 + qb*16 + lo16][ccol];
      }
      #pragma unroll
      for (int j = 0; j < 4; ++j) {
        bf16x8 bh = *(const bf16x8*)&Bh[j*16 + lo16][ccol];
        if (!isV) {
          bf16x8 bl = *(const bf16x8*)&Bl[j*16 + lo16][ccol];
          #pragma unroll
          for (int qb = 0; qb < 2; ++qb) {
            acc[qb][j] = MFMA16(ah[qb],  bh, acc[qb][j]);
            acc[qb][j] = MFMA16(al2[qb], bh, acc[qb][j]);
            acc[qb][j] = MFMA16(ah[qb],  bl, acc[qb][j]);
          }
        } else {
          #pragma unroll
          for (int qb = 0; qb < 2; ++qb)
            acc[qb][j] = MFMA16(ah[qb], bh, acc[qb][j]);
        }
      }
    }
  }

  // ---- epilogue: RMSNorm + RoPE; fp16 stores (Q scaled by log2e) ----
  #pragma unroll
  for (int qb = 0; qb < 2; ++qb) {
    float scale[4];
    #pragma unroll
    for (int r = 0; r < 4; ++r) {
      float s = 0.f;
      #pragma unroll
      for (int j = 0; j < 4; ++j) s += acc[qb][j][r] * acc[qb][j][r];
      #pragma unroll
      for (int m = 1; m < 16; m <<= 1) s += __shfl_xor(s, m);
      scale[r] = 1.0f / sqrtf(s * (1.0f/64.0f) + 1e-6f);
    }
    float nw[4];
    #pragma unroll
    for (int j = 0; j < 4; ++j)
      nw[j] = (kind == 0) ? qnw[lo16 + 16*j] : (kind == 1 ? knw[lo16 + 16*j] : 1.0f);

    float y[4][4];
    #pragma unroll
    for (int j = 0; j < 4; ++j)
      #pragma unroll
      for (int r = 0; r < 4; ++r) y[j][r] = acc[qb][j][r] * scale[r] * nw[j];

    if (kind == 2) {
      #pragma unroll
      for (int r = 0; r < 4; ++r) {
        int mg = m0 + wave*32 + qb*16 + hi4*4 + r;
        int b = mg >> 11, sq = mg & 2047;
        #pragma unroll
        for (int j = 0; j < 4; ++j) {
          int d = lo16 + 16*j;
          vt_o[((size_t)((b*PKV + hd)*PD + d))*PS + sq] = (f16_t)y[j][r];
        }
      }
    } else {
      #pragma unroll
      for (int r = 0; r < 4; ++r) {
        int mg = m0 + wave*32 + qb*16 + hi4*4 + r;
        int b = mg >> 11, sq = mg & 2047;
        const float* cp = &cosp[(size_t)mg * PD];
        const float* sp = &sinp[(size_t)mg * PD];
        float z[4];
        #pragma unroll
        for (int j = 0; j < 4; ++j) {
          float c = cp[lo16 + 16*j], s = sp[lo16 + 16*j];
          float rot = (j & 1) ? y[j-1][r] : -y[j+1][r];
          z[j] = y[j][r] * c + rot * s;
        }
        #pragma unroll
        for (int j = 0; j < 4; ++j) {
          int d = lo16 + 16*j;
          if (kind == 0) {
            size_t idx = ((size_t)(b*PH + hd)*PS + sq)*PD + d;
            q_o[idx] = (f16_t)(z[j] * LOG2E);   // exp2-domain fold
          } else {
            size_t idx = ((size_t)(b*PKV + hd)*PS + sq)*PD + d;
            k_o[idx] = (f16_t)z[j];
          }
        }
      }
    }
  }
}

// ---------------------------------------------------------------------------
// Kernel 2: flash attention, all-fp16, swapped QK^T (single MFMA term),
// exp2-domain softmax + defer-max, kv-split x2, setprio around MFMA.
// grid 1024 XCD-swizzled -> (qt 16, bh 32, ks 2). 4 waves x 32 q-rows.
// Partials: per-split NORMALIZED O (fp16) + (m, l) float2 per row.
// ---------------------------------------------------------------------------
__global__ __launch_bounds__(256, 4)
void attn_kernel(const f16_t* __restrict__ q_g, const f16_t* __restrict__ k_g,
                 const f16_t* __restrict__ vt_g,
                 f16_t* __restrict__ op, float2* __restrict__ ml)
{
  __shared__ __align__(16) f16_t Ks[64][72];   // K tile [kv][d]
  __shared__ __align__(16) f16_t Vs[64][72];   // V^T tile [d][kv]
  __shared__ __align__(16) f16_t Ps[128][72];  // P tile [q][kv]; epilogue O-bounce

  const int tid = threadIdx.x, lane = tid & 63, wave = tid >> 6;
  const int lo16 = lane & 15, hi4 = lane >> 4;
  const int lin = blockIdx.x;
  const int swz = (lin & 7) * 128 + (lin >> 3);
  const int qt = swz & 15;
  const int bh = (swz >> 4) & 31;
  const int ks = swz >> 9;
  const int b = bh >> 4, h = bh & 15, kvh = h >> 1;   // GQA groups=2

  f16x8 qf[2][2];
  #pragma unroll
  for (int qb = 0; qb < 2; ++qb) {
    const size_t qbase = ((size_t)(b*PH + h)*PS + qt*128 + wave*32 + qb*16 + lo16) * PD;
    #pragma unroll
    for (int t = 0; t < 2; ++t)
      qf[qb][t] = *(const f16x8*)&q_g[qbase + t*32 + hi4*8];
  }

  f32x4 o[2][4];
  float mq[2] = {-1e30f, -1e30f}, lq[2] = {0.f, 0.f};
  #pragma unroll
  for (int qb = 0; qb < 2; ++qb)
    #pragma unroll
    for (int j = 0; j < 4; ++j) o[qb][j] = f32x4{0.f, 0.f, 0.f, 0.f};

  const int srow = tid >> 2, sc = (tid & 3) * 16;
  const size_t kbase = (size_t)(b*PKV + kvh) * PS * PD + (size_t)ks * 1024 * PD;
  const size_t vbase = (size_t)(b*PKV + kvh) * PD * PS + (size_t)ks * 1024;

  f16x8 gk0, gk1, gv0, gv1;
  auto LOADT = [&](int kt) {
    const f16_t* kp = &k_g[kbase + (size_t)(kt*64 + srow)*PD + sc];
    const f16_t* vp = &vt_g[vbase + (size_t)srow*PS + kt*64 + sc];
    gk0 = *(const f16x8*)kp;  gk1 = *(const f16x8*)(kp + 8);
    gv0 = *(const f16x8*)vp;  gv1 = *(const f16x8*)(vp + 8);
  };
  LOADT(0);

  for (int kt = 0; kt < 16; ++kt) {
    __syncthreads();
    *(f16x8*)&Ks[srow][sc]     = gk0;
    *(f16x8*)&Ks[srow][sc + 8] = gk1;
    *(f16x8*)&Vs[srow][sc]     = gv0;
    *(f16x8*)&Vs[srow][sc + 8] = gv1;
    if (kt + 1 < 16) LOADT(kt + 1);
    __syncthreads();

    // QK^T swapped, single fp16 term: sacc[qb][j][r] = S'[kv][q] (log2 domain)
    f32x4 sacc[2][4];
    #pragma unroll
    for (int qb = 0; qb < 2; ++qb)
      #pragma unroll
      for (int j = 0; j < 4; ++j) sacc[qb][j] = f32x4{0.f, 0.f, 0.f, 0.f};
    __builtin_amdgcn_s_setprio(1);
    #pragma unroll
    for (int j = 0; j < 4; ++j) {
      #pragma unroll
      for (int t = 0; t < 2; ++t) {
        f16x8 kf = *(const f16x8*)&Ks[j*16 + lo16][t*32 + hi4*8];
        #pragma unroll
        for (int qb = 0; qb < 2; ++qb)
          sacc[qb][j] = MFMAH(kf, qf[qb][t], sacc[qb][j]);
      }
    }
    __builtin_amdgcn_s_setprio(0);

    // exp2-domain online softmax with defer-max (THR=8 -> P <= 256)
    #pragma unroll
    for (int qb = 0; qb < 2; ++qb) {
      float tm = sacc[qb][0][0];
      #pragma unroll
      for (int j = 0; j < 4; ++j)
        #pragma unroll
        for (int r = 0; r < 4; ++r) tm = fmaxf(tm, sacc[qb][j][r]);
      tm = fmaxf(tm, __shfl_xor(tm, 16));
      tm = fmaxf(tm, __shfl_xor(tm, 32));
      if (!__all(tm <= mq[qb] + 8.0f)) {
        float mnew = fmaxf(mq[qb], tm);
        float alpha = __builtin_amdgcn_exp2f(mq[qb] - mnew);
        lq[qb] *= alpha;
        #pragma unroll
        for (int jd = 0; jd < 4; ++jd) o[qb][jd] *= alpha;
        mq[qb] = mnew;
      }
      float ls = 0.f;
      #pragma unroll
      for (int j = 0; j < 4; ++j)
        #pragma unroll
        for (int r = 0; r < 4; ++r) {
          float p = __builtin_amdgcn_exp2f(sacc[qb][j][r] - mq[qb]);
          sacc[qb][j][r] = p;
          ls += p;
        }
      ls += __shfl_xor(ls, 16);
      ls += __shfl_xor(ls, 32);
      lq[qb] += ls;
    }

    // P -> LDS packed (same-wave rows; in-wave DS ordering, no barrier)
    #pragma unroll
    for (int qb = 0; qb < 2; ++qb)
      #pragma unroll
      for (int j = 0; j < 4; ++j)
        #pragma unroll
        for (int rp = 0; rp < 2; ++rp)
          *(f16x2*)&Ps[wave*32 + qb*16 + lo16][j*16 + hi4*4 + 2*rp] =
              f16x2{(f16_t)sacc[qb][j][2*rp], (f16_t)sacc[qb][j][2*rp+1]};

    f16x8 pa[2][2];
    #pragma unroll
    for (int qb = 0; qb < 2; ++qb)
      #pragma unroll
      for (int t = 0; t < 2; ++t)
        pa[qb][t] = *(const f16x8*)&Ps[wave*32 + qb*16 + lo16][t*32 + hi4*8];

    // PV: O^T = V^T * P^T
    __builtin_amdgcn_s_setprio(1);
    #pragma unroll
    for (int jd = 0; jd < 4; ++jd) {
      #pragma unroll
      for (int t = 0; t < 2; ++t) {
        f16x8 vf = *(const f16x8*)&Vs[jd*16 + lo16][t*32 + hi4*8];
        #pragma unroll
        for (int qb = 0; qb < 2; ++qb)
          o[qb][jd] = MFMAH(vf, pa[qb][t], o[qb][jd]);
      }
    }
    __builtin_amdgcn_s_setprio(0);
  }

  // ---- epilogue: (m,l) + NORMALIZED O (fp16, |O|<=|V|max) via LDS bounce ----
  const int rbase = bh*PS + qt*128 + wave*32;
  if (hi4 == 0) {
    #pragma unroll
    for (int qb = 0; qb < 2; ++qb)
      ml[(size_t)ks*PR + rbase + qb*16 + lo16] = float2{mq[qb], lq[qb]};
  }
  #pragma unroll
  for (int qb = 0; qb < 2; ++qb) {
    float inv = 1.0f / lq[qb];
    #pragma unroll
    for (int jd = 0; jd < 4; ++jd)
      #pragma unroll
      for (int rp = 0; rp < 2; ++rp)
        *(f16x2*)&Ps[wave*32 + qb*16 + lo16][jd*16 + hi4*4 + 2*rp] =
            f16x2{(f16_t)(o[qb][jd][2*rp] * inv), (f16_t)(o[qb][jd][2*rp+1] * inv)};
  }
  {
    const int row = lane >> 1, half = lane & 1;
    const size_t gb_ = ((size_t)ks*PR + rbase + row) * PD + half*32;
    #pragma unroll
    for (int c = 0; c < 4; ++c)
      *(f16x8*)&op[gb_ + c*8] = *(const f16x8*)&Ps[wave*32 + row][half*32 + c*8];
  }
}

// ---------------------------------------------------------------------------
// Kernel 3: merge kv-split partials (normalized O + m,l in log2 domain).
// ---------------------------------------------------------------------------
__global__ __launch_bounds__(256)
void merge_kernel(const f16_t* __restrict__ op, const float2* __restrict__ ml,
                  f16_t* __restrict__ ao)
{
  const int gid = blockIdx.x * 256 + threadIdx.x;
  const int row = gid >> 3, oct = gid & 7;
  float2 e0 = ml[row], e1 = ml[PR + row];
  float M = fmaxf(e0.x, e1.x);
  float c0 = __builtin_amdgcn_exp2f(e0.x - M) * e0.y;
  float c1 = __builtin_amdgcn_exp2f(e1.x - M) * e1.y;
  float inv = 1.0f / (c0 + c1);
  c0 *= inv; c1 *= inv;
  f16x8 a = *(const f16x8*)&op[(size_t)row*PD + oct*8];
  f16x8 bq = *(const f16x8*)&op[(size_t)(PR + row)*PD + oct*8];
  f16x8 r;
  #pragma unroll
  for (int i = 0; i < 8; ++i)
    r[i] = (f16_t)(c0 * (float)a[i] + c1 * (float)bq[i]);
  const int bh = row >> 11, sq = row & 2047;
  const int b = bh >> 4, h = bh & 15;
  *(f16x8*)&ao[((size_t)(b*PS + sq))*PHID + h*PD + oct*8] = r;
}

// ---------------------------------------------------------------------------
// Kernel 4: out-projection, fp16 GEMM (ao x WoT) -> fp32. grid 512 swizzled.
// ---------------------------------------------------------------------------
__global__ __launch_bounds__(256)
void oproj_kernel(const f16_t* __restrict__ ao, const f16_t* __restrict__ woT,
                  float* __restrict__ out)
{
  __shared__ __align__(16) f16_t As[128][40], Bs[64][40];
  const int tid = threadIdx.x;
  const int lane = tid & 63, wave = tid >> 6;
  const int lo16 = lane & 15, hi4 = lane >> 4;
  const int lin = blockIdx.x;
  const int swz = (lin & 7) * 64 + (lin >> 3);
  const int m0 = (swz >> 4) * 128;
  const int col0 = (swz & 15) * 64;

  f32x4 acc[2][4];
  #pragma unroll
  for (int qb = 0; qb < 2; ++qb)
    #pragma unroll
    for (int j = 0; j < 4; ++j) acc[qb][j] = f32x4{0.f, 0.f, 0.f, 0.f};

  const int ar = tid >> 1, akc = (tid & 1) * 16;
  const int bn = tid & 63, bkc = (tid >> 6) * 8;

  f16x8 gA0, gA1, gB;
  auto LOADA = [&](int k0) {
    const f16_t* ap = &ao[(size_t)(m0 + ar) * PHID + k0 + akc];
    gA0 = *(const f16x8*)ap;
    gA1 = *(const f16x8*)(ap + 8);
  };
  auto LOADB = [&](int k0) {
    gB = *(const f16x8*)&woT[(size_t)(col0 + bn) * 1024 + k0 + bkc];
  };
  LOADA(0); LOADB(0);

  for (int k0 = 0; k0 < PHID; k0 += 32) {
    __syncthreads();
    *(f16x8*)&As[ar][akc]     = gA0;
    *(f16x8*)&As[ar][akc + 8] = gA1;
    *(f16x8*)&Bs[bn][bkc]     = gB;
    if (k0 + 32 < PHID) { LOADA(k0 + 32); LOADB(k0 + 32); }
    __syncthreads();
    {
      f16x8 a[2];
      #pragma unroll
      for (int qb = 0; qb < 2; ++qb)
        a[qb] = *(const f16x8*)&As[wave*32 + qb*16 + lo16][hi4*8];
      #pragma unroll
      for (int j = 0; j < 4; ++j) {
        f16x8 bb = *(const f16x8*)&Bs[j*16 + lo16][hi4*8];
        #pragma unroll
        for (int qb = 0; qb < 2; ++qb)
          acc[qb][j] = MFMAH(a[qb], bb, acc[qb][j]);
      }
    }
  }

  #pragma unroll
  for (int qb = 0; qb < 2; ++qb)
    #pragma unroll
    for (int r = 0; r < 4; ++r) {
      int mg = m0 + wave*32 + qb*16 + hi4*4 + r;
      #pragma unroll
      for (int j = 0; j < 4; ++j)
        out[(size_t)mg*PHID + col0 + lo16 + 16*j] = acc[qb][j][r];
    }
}

// ---------------------------------------------------------------------------
extern "C" void kernel_launch(void* const* d_in, const int* in_sizes, int n_in,
                              void* d_out, int out_size, void* d_ws, size_t ws_size,
                              hipStream_t stream) {
  (void)in_sizes; (void)n_in; (void)out_size; (void)ws_size;
  const float* hs   = (const float*)d_in[0];
  const float* cosp = (const float*)d_in[1];
  const float* sinp = (const float*)d_in[2];
  // d_in[3] position_ids: only shape[-1]=2 used (NDIM=2 hardcoded)
  const float* Wq   = (const float*)d_in[4];
  const float* Wk   = (const float*)d_in[5];
  const float* Wv   = (const float*)d_in[6];
  const float* Wo   = (const float*)d_in[7];
  const float* qnw  = (const float*)d_in[8];
  const float* knw  = (const float*)d_in[9];
  float* out = (float*)d_out;

  const size_t QN = (size_t)PB*PH*PS*PD;    // 4,194,304 (== PR*PD == PM*PHID)
  const size_t KN = (size_t)PB*PKV*PS*PD;   // 2,097,152
  const size_t HN = (size_t)PM*PHID;        // 4,194,304
  char* wsb = (char*)d_ws;
  f16_t*  qv  = (f16_t*)wsb;                       // QN  fp16 (8.4 MB)
  f16_t*  kv  = qv + QN;                           // KN  fp16
  f16_t*  vt  = kv + KN;                           // KN  fp16
  bf16_t* hsh = (bf16_t*)(vt + KN);                // HN  bf16 (dead after qkv)
  bf16_t* hsl = hsh + HN;                          // HN  bf16 (dead after qkv)
  bf16_t* wth = hsl + HN;                          // 2048*1024 bf16
  bf16_t* wtl = wth + (size_t)2048*1024;           // 1536*1024 bf16 (dead after qkv)
  f16_t*  woT = (f16_t*)(wtl + (size_t)1536*1024); // 1024*1024 fp16 (live to oproj)
  // stream-ordered aliases:
  f16_t*  op  = (f16_t*)hsh;                       // 2*QN fp16 == hsh+hsl exactly
  float2* ml  = (float2*)wtl;                      // 1 MB into dead wtl
  f16_t*  ao  = qv;                                // attn done with Q before merge

  convert_hs<<<dim3(2048), 256, 0, stream>>>(hs, hsh, hsl);
  convert_w <<<dim3(768),  256, 0, stream>>>(Wq, Wk, Wv, Wo, wth, wtl, woT);
  qkv_kernel<<<dim3(1024), 256, 0, stream>>>(hsh, hsl, wth, wtl, cosp, sinp,
                                             qnw, knw, qv, kv, vt);
  attn_kernel<<<dim3(1024), 256, 0, stream>>>(qv, kv, vt, op, ml);
  merge_kernel<<<dim3(PR*8/256), 256, 0, stream>>>(op, ml, ao);
  oproj_kernel<<<dim3(512), 256, 0, stream>>>(ao, woT, out);
}

// Round 7
// 131.228 us; speedup vs baseline: 2.1420x; 1.1987x over previous
//
#include <hip/hip_runtime.h>

// Problem constants
#define PB 2
#define PS 2048
#define PHID 1024
#define PH 16
#define PKV 8
#define PD 64
#define PM (PB*PS)    // 4096
#define PR (PB*PH*PS) // 65536 q-rows total

typedef _Float16 f16_t;
typedef _Float16 f16x8 __attribute__((ext_vector_type(8)));
typedef _Float16 f16x2 __attribute__((ext_vector_type(2)));
typedef float f32x4 __attribute__((ext_vector_type(4)));

#define MFMAH(a,b,c)  __builtin_amdgcn_mfma_f32_16x16x32_f16((a),(b),(c),0,0,0)
#define LOG2E 1.44269504f

// global -> LDS direct copy, 16B per lane.
__device__ __forceinline__ void gl16(const f16_t* g, f16_t* l) {
  __builtin_amdgcn_global_load_lds(
      (const __attribute__((address_space(1))) void*)g,
      (__attribute__((address_space(3))) void*)l, 16, 0, 0);
}

// ---------------------------------------------------------------------------
// Kernel 0a: hs fp32 -> fp16 (single stream).
// ---------------------------------------------------------------------------
__global__ __launch_bounds__(256)
void convert_hs(const float* __restrict__ hs, f16_t* __restrict__ hf)
{
  const size_t i = ((size_t)blockIdx.x * 256 + threadIdx.x) * 8;
  float4 a = *(const float4*)&hs[i];
  float4 b = *(const float4*)&hs[i + 4];
  float xs[8] = {a.x, a.y, a.z, a.w, b.x, b.y, b.z, b.w};
  f16x8 v;
  #pragma unroll
  for (int j = 0; j < 8; ++j) v[j] = (f16_t)xs[j];
  *(f16x8*)&hf[i] = v;
}

// ---------------------------------------------------------------------------
// Kernel 0b: all weights -> transposed [n][k] fp16, one array wtT:
// rows 0-1023 Wq^T, 1024-1535 Wk^T, 1536-2047 Wv^T, 2048-3071 Wo^T.
// grid 768 = 48 slots x 16 k-tiles; 64k x 64n tile via LDS transpose.
// ---------------------------------------------------------------------------
__global__ __launch_bounds__(256)
void convert_w(const float* __restrict__ Wq, const float* __restrict__ Wk,
               const float* __restrict__ Wv, const float* __restrict__ Wo,
               f16_t* __restrict__ wtT)
{
  __shared__ float Tt[64][68];
  const int tid = threadIdx.x;
  const int slot = blockIdx.x >> 4, k0 = (blockIdx.x & 15) * 64;

  const float* src; int N, ncol0, orow0;
  if (slot < 16)      { src = Wq; N = 1024; ncol0 = slot*64;      orow0 = slot*64; }
  else if (slot < 24) { src = Wk; N = 512;  ncol0 = (slot-16)*64; orow0 = 1024 + (slot-16)*64; }
  else if (slot < 32) { src = Wv; N = 512;  ncol0 = (slot-24)*64; orow0 = 1536 + (slot-24)*64; }
  else                { src = Wo; N = 1024; ncol0 = (slot-32)*64; orow0 = 2048 + (slot-32)*64; }

  const int tk = tid >> 6, tn = tid & 63;
  #pragma unroll
  for (int i = 0; i < 16; ++i)
    Tt[tn][tk*16 + i] = src[(size_t)(k0 + tk*16 + i) * N + ncol0 + tn];
  __syncthreads();

  const int n = tid >> 2, kc = (tid & 3) * 16;
  f16x8 a0, a1;
  #pragma unroll
  for (int i = 0; i < 8; ++i) {
    a0[i] = (f16_t)Tt[n][kc + i];
    a1[i] = (f16_t)Tt[n][kc + 8 + i];
  }
  const size_t ob = (size_t)(orow0 + n) * 1024 + k0 + kc;
  *(f16x8*)&wtT[ob]     = a0;
  *(f16x8*)&wtT[ob + 8] = a1;
}

// ---------------------------------------------------------------------------
// Kernel 1: QKV projection, single-term fp16 GEMM + RMSNorm + RoPE epilogue.
// Outputs fp16 (Q pre-scaled by log2e). BK=64, global_load_lds with XOR
// swizzle (pre-swizzled global src + swizzled ds_read, linear LDS dest).
// grid 1024 XCD-swizzled = 32 row-tiles x 32 slots. LDS 24 KB.
// ---------------------------------------------------------------------------
__global__ __launch_bounds__(256)
void qkv_kernel(const f16_t* __restrict__ hsf, const f16_t* __restrict__ wtT,
                const float* __restrict__ cosp, const float* __restrict__ sinp,
                const float* __restrict__ qnw, const float* __restrict__ knw,
                f16_t* __restrict__ q_o, f16_t* __restrict__ k_o,
                f16_t* __restrict__ vt_o)
{
  __shared__ __align__(16) f16_t Ah[128][64];  // 16 KB
  __shared__ __align__(16) f16_t Bh[64][64];   // 8 KB

  const int tid = threadIdx.x;
  const int lane = tid & 63, wave = tid >> 6;
  const int lo16 = lane & 15, hi4 = lane >> 4;
  const int lin = blockIdx.x;
  const int swz = (lin & 7) * 128 + (lin >> 3);
  const int m0 = (swz >> 5) * 128;
  const int slot = swz & 31;

  int kind, hd, orow;
  if (slot < 16)      { kind = 0; hd = slot;      orow = slot*64; }
  else if (slot < 24) { kind = 1; hd = slot - 16; orow = 1024 + hd*64; }
  else                { kind = 2; hd = slot - 24; orow = 1536 + hd*64; }

  f32x4 acc[2][4];
  #pragma unroll
  for (int qb = 0; qb < 2; ++qb)
    #pragma unroll
    for (int j = 0; j < 4; ++j) acc[qb][j] = f32x4{0.f, 0.f, 0.f, 0.f};

  // staging: one gl16 issue covers 8 rows x 128B; row-in-stripe ri, chunk pc.
  // logical chunk = pc ^ ri (stripe bases are multiples of 8 rows).
  const int ri = lane >> 3, pc = lane & 7;
  const int lcs = (pc ^ ri) * 8;   // element offset of logical 16B chunk
  size_t aoff[2]; f16_t* aldst[2];
  #pragma unroll
  for (int q = 0; q < 2; ++q) {
    aoff[q] = (size_t)(m0 + wave*32 + q*16 + (ri & 7) + (q*0)) * PHID + lcs;
    aldst[q] = &Ah[wave*32 + q*16][0];
  }
  // NOTE: each issue covers 8 rows but a qb-block is 16 rows -> need 4 issues.
  size_t aoff4[4]; f16_t* aldst4[4];
  #pragma unroll
  for (int q = 0; q < 4; ++q) {
    aoff4[q] = (size_t)(m0 + wave*32 + q*8 + ri) * PHID + lcs;
    aldst4[q] = &Ah[wave*32 + q*8][0];
  }
  size_t boff[2]; int brow[2];
  #pragma unroll
  for (int q = 0; q < 2; ++q) {
    brow[q] = wave*16 + q*8;
    boff[q] = (size_t)(orow + brow[q] + ri) * 1024 + lcs;
  }

  const int rsw = lo16 & 7;  // read-side swizzle key (row & 7)

  for (int k0 = 0; k0 < PHID; k0 += 64) {
    __syncthreads();
    #pragma unroll
    for (int q = 0; q < 4; ++q) gl16(hsf + aoff4[q] + k0, aldst4[q]);
    #pragma unroll
    for (int q = 0; q < 2; ++q) gl16(wtT + boff[q] + k0, &Bh[brow[q]][0]);
    __syncthreads();

    #pragma unroll
    for (int t = 0; t < 2; ++t) {
      const int ccol = ((t*4 + hi4) ^ rsw) * 8;
      f16x8 ah[2];
      #pragma unroll
      for (int qb = 0; qb < 2; ++qb)
        ah[qb] = *(const f16x8*)&Ah[wave*32 + qb*16 + lo16][ccol];
      #pragma unroll
      for (int j = 0; j < 4; ++j) {
        f16x8 bh = *(const f16x8*)&Bh[j*16 + lo16][ccol];
        #pragma unroll
        for (int qb = 0; qb < 2; ++qb)
          acc[qb][j] = MFMAH(ah[qb], bh, acc[qb][j]);
      }
    }
  }

  // ---- epilogue: RMSNorm + RoPE; fp16 stores (Q scaled by log2e) ----
  #pragma unroll
  for (int qb = 0; qb < 2; ++qb) {
    float scale[4];
    #pragma unroll
    for (int r = 0; r < 4; ++r) {
      float s = 0.f;
      #pragma unroll
      for (int j = 0; j < 4; ++j) s += acc[qb][j][r] * acc[qb][j][r];
      #pragma unroll
      for (int m = 1; m < 16; m <<= 1) s += __shfl_xor(s, m);
      scale[r] = 1.0f / sqrtf(s * (1.0f/64.0f) + 1e-6f);
    }
    float nw[4];
    #pragma unroll
    for (int j = 0; j < 4; ++j)
      nw[j] = (kind == 0) ? qnw[lo16 + 16*j] : (kind == 1 ? knw[lo16 + 16*j] : 1.0f);

    float y[4][4];
    #pragma unroll
    for (int j = 0; j < 4; ++j)
      #pragma unroll
      for (int r = 0; r < 4; ++r) y[j][r] = acc[qb][j][r] * scale[r] * nw[j];

    if (kind == 2) {
      #pragma unroll
      for (int r = 0; r < 4; ++r) {
        int mg = m0 + wave*32 + qb*16 + hi4*4 + r;
        int b = mg >> 11, sq = mg & 2047;
        #pragma unroll
        for (int j = 0; j < 4; ++j) {
          int d = lo16 + 16*j;
          vt_o[((size_t)((b*PKV + hd)*PD + d))*PS + sq] = (f16_t)y[j][r];
        }
      }
    } else {
      #pragma unroll
      for (int r = 0; r < 4; ++r) {
        int mg = m0 + wave*32 + qb*16 + hi4*4 + r;
        int b = mg >> 11, sq = mg & 2047;
        const float* cp = &cosp[(size_t)mg * PD];
        const float* sp = &sinp[(size_t)mg * PD];
        float z[4];
        #pragma unroll
        for (int j = 0; j < 4; ++j) {
          float c = cp[lo16 + 16*j], s = sp[lo16 + 16*j];
          float rot = (j & 1) ? y[j-1][r] : -y[j+1][r];
          z[j] = y[j][r] * c + rot * s;
        }
        #pragma unroll
        for (int j = 0; j < 4; ++j) {
          int d = lo16 + 16*j;
          if (kind == 0) {
            size_t idx = ((size_t)(b*PH + hd)*PS + sq)*PD + d;
            q_o[idx] = (f16_t)(z[j] * LOG2E);   // exp2-domain fold
          } else {
            size_t idx = ((size_t)(b*PKV + hd)*PS + sq)*PD + d;
            k_o[idx] = (f16_t)z[j];
          }
        }
      }
    }
  }
}

// ---------------------------------------------------------------------------
// Kernel 2: flash attention, all-fp16, swapped QK^T, exp2-domain softmax +
// defer-max, kv-split x2, setprio. (unchanged from round 6 — passed)
// ---------------------------------------------------------------------------
__global__ __launch_bounds__(256, 4)
void attn_kernel(const f16_t* __restrict__ q_g, const f16_t* __restrict__ k_g,
                 const f16_t* __restrict__ vt_g,
                 f16_t* __restrict__ op, float2* __restrict__ ml)
{
  __shared__ __align__(16) f16_t Ks[64][72];
  __shared__ __align__(16) f16_t Vs[64][72];
  __shared__ __align__(16) f16_t Ps[128][72];

  const int tid = threadIdx.x, lane = tid & 63, wave = tid >> 6;
  const int lo16 = lane & 15, hi4 = lane >> 4;
  const int lin = blockIdx.x;
  const int swz = (lin & 7) * 128 + (lin >> 3);
  const int qt = swz & 15;
  const int bh = (swz >> 4) & 31;
  const int ks = swz >> 9;
  const int b = bh >> 4, h = bh & 15, kvh = h >> 1;

  f16x8 qf[2][2];
  #pragma unroll
  for (int qb = 0; qb < 2; ++qb) {
    const size_t qbase = ((size_t)(b*PH + h)*PS + qt*128 + wave*32 + qb*16 + lo16) * PD;
    #pragma unroll
    for (int t = 0; t < 2; ++t)
      qf[qb][t] = *(const f16x8*)&q_g[qbase + t*32 + hi4*8];
  }

  f32x4 o[2][4];
  float mq[2] = {-1e30f, -1e30f}, lq[2] = {0.f, 0.f};
  #pragma unroll
  for (int qb = 0; qb < 2; ++qb)
    #pragma unroll
    for (int j = 0; j < 4; ++j) o[qb][j] = f32x4{0.f, 0.f, 0.f, 0.f};

  const int srow = tid >> 2, sc = (tid & 3) * 16;
  const size_t kbase = (size_t)(b*PKV + kvh) * PS * PD + (size_t)ks * 1024 * PD;
  const size_t vbase = (size_t)(b*PKV + kvh) * PD * PS + (size_t)ks * 1024;

  f16x8 gk0, gk1, gv0, gv1;
  auto LOADT = [&](int kt) {
    const f16_t* kp = &k_g[kbase + (size_t)(kt*64 + srow)*PD + sc];
    const f16_t* vp = &vt_g[vbase + (size_t)srow*PS + kt*64 + sc];
    gk0 = *(const f16x8*)kp;  gk1 = *(const f16x8*)(kp + 8);
    gv0 = *(const f16x8*)vp;  gv1 = *(const f16x8*)(vp + 8);
  };
  LOADT(0);

  for (int kt = 0; kt < 16; ++kt) {
    __syncthreads();
    *(f16x8*)&Ks[srow][sc]     = gk0;
    *(f16x8*)&Ks[srow][sc + 8] = gk1;
    *(f16x8*)&Vs[srow][sc]     = gv0;
    *(f16x8*)&Vs[srow][sc + 8] = gv1;
    if (kt + 1 < 16) LOADT(kt + 1);
    __syncthreads();

    f32x4 sacc[2][4];
    #pragma unroll
    for (int qb = 0; qb < 2; ++qb)
      #pragma unroll
      for (int j = 0; j < 4; ++j) sacc[qb][j] = f32x4{0.f, 0.f, 0.f, 0.f};
    __builtin_amdgcn_s_setprio(1);
    #pragma unroll
    for (int j = 0; j < 4; ++j) {
      #pragma unroll
      for (int t = 0; t < 2; ++t) {
        f16x8 kf = *(const f16x8*)&Ks[j*16 + lo16][t*32 + hi4*8];
        #pragma unroll
        for (int qb = 0; qb < 2; ++qb)
          sacc[qb][j] = MFMAH(kf, qf[qb][t], sacc[qb][j]);
      }
    }
    __builtin_amdgcn_s_setprio(0);

    #pragma unroll
    for (int qb = 0; qb < 2; ++qb) {
      float tm = sacc[qb][0][0];
      #pragma unroll
      for (int j = 0; j < 4; ++j)
        #pragma unroll
        for (int r = 0; r < 4; ++r) tm = fmaxf(tm, sacc[qb][j][r]);
      tm = fmaxf(tm, __shfl_xor(tm, 16));
      tm = fmaxf(tm, __shfl_xor(tm, 32));
      if (!__all(tm <= mq[qb] + 8.0f)) {
        float mnew = fmaxf(mq[qb], tm);
        float alpha = __builtin_amdgcn_exp2f(mq[qb] - mnew);
        lq[qb] *= alpha;
        #pragma unroll
        for (int jd = 0; jd < 4; ++jd) o[qb][jd] *= alpha;
        mq[qb] = mnew;
      }
      float ls = 0.f;
      #pragma unroll
      for (int j = 0; j < 4; ++j)
        #pragma unroll
        for (int r = 0; r < 4; ++r) {
          float p = __builtin_amdgcn_exp2f(sacc[qb][j][r] - mq[qb]);
          sacc[qb][j][r] = p;
          ls += p;
        }
      ls += __shfl_xor(ls, 16);
      ls += __shfl_xor(ls, 32);
      lq[qb] += ls;
    }

    #pragma unroll
    for (int qb = 0; qb < 2; ++qb)
      #pragma unroll
      for (int j = 0; j < 4; ++j)
        #pragma unroll
        for (int rp = 0; rp < 2; ++rp)
          *(f16x2*)&Ps[wave*32 + qb*16 + lo16][j*16 + hi4*4 + 2*rp] =
              f16x2{(f16_t)sacc[qb][j][2*rp], (f16_t)sacc[qb][j][2*rp+1]};

    f16x8 pa[2][2];
    #pragma unroll
    for (int qb = 0; qb < 2; ++qb)
      #pragma unroll
      for (int t = 0; t < 2; ++t)
        pa[qb][t] = *(const f16x8*)&Ps[wave*32 + qb*16 + lo16][t*32 + hi4*8];

    __builtin_amdgcn_s_setprio(1);
    #pragma unroll
    for (int jd = 0; jd < 4; ++jd) {
      #pragma unroll
      for (int t = 0; t < 2; ++t) {
        f16x8 vf = *(const f16x8*)&Vs[jd*16 + lo16][t*32 + hi4*8];
        #pragma unroll
        for (int qb = 0; qb < 2; ++qb)
          o[qb][jd] = MFMAH(vf, pa[qb][t], o[qb][jd]);
      }
    }
    __builtin_amdgcn_s_setprio(0);
  }

  const int rbase = bh*PS + qt*128 + wave*32;
  if (hi4 == 0) {
    #pragma unroll
    for (int qb = 0; qb < 2; ++qb)
      ml[(size_t)ks*PR + rbase + qb*16 + lo16] = float2{mq[qb], lq[qb]};
  }
  #pragma unroll
  for (int qb = 0; qb < 2; ++qb) {
    float inv = 1.0f / lq[qb];
    #pragma unroll
    for (int jd = 0; jd < 4; ++jd)
      #pragma unroll
      for (int rp = 0; rp < 2; ++rp)
        *(f16x2*)&Ps[wave*32 + qb*16 + lo16][jd*16 + hi4*4 + 2*rp] =
            f16x2{(f16_t)(o[qb][jd][2*rp] * inv), (f16_t)(o[qb][jd][2*rp+1] * inv)};
  }
  {
    const int row = lane >> 1, half = lane & 1;
    const size_t gb_ = ((size_t)ks*PR + rbase + row) * PD + half*32;
    #pragma unroll
    for (int c = 0; c < 4; ++c)
      *(f16x8*)&op[gb_ + c*8] = *(const f16x8*)&Ps[wave*32 + row][half*32 + c*8];
  }
}

// ---------------------------------------------------------------------------
// Kernel 3: merge kv-split partials (normalized O + m,l in log2 domain).
// ---------------------------------------------------------------------------
__global__ __launch_bounds__(256)
void merge_kernel(const f16_t* __restrict__ op, const float2* __restrict__ ml,
                  f16_t* __restrict__ ao)
{
  const int gid = blockIdx.x * 256 + threadIdx.x;
  const int row = gid >> 3, oct = gid & 7;
  float2 e0 = ml[row], e1 = ml[PR + row];
  float M = fmaxf(e0.x, e1.x);
  float c0 = __builtin_amdgcn_exp2f(e0.x - M) * e0.y;
  float c1 = __builtin_amdgcn_exp2f(e1.x - M) * e1.y;
  float inv = 1.0f / (c0 + c1);
  c0 *= inv; c1 *= inv;
  f16x8 a = *(const f16x8*)&op[(size_t)row*PD + oct*8];
  f16x8 bq = *(const f16x8*)&op[(size_t)(PR + row)*PD + oct*8];
  f16x8 r;
  #pragma unroll
  for (int i = 0; i < 8; ++i)
    r[i] = (f16_t)(c0 * (float)a[i] + c1 * (float)bq[i]);
  const int bh = row >> 11, sq = row & 2047;
  const int b = bh >> 4, h = bh & 15;
  *(f16x8*)&ao[((size_t)(b*PS + sq))*PHID + h*PD + oct*8] = r;
}

// ---------------------------------------------------------------------------
// Kernel 4: out-projection, fp16 GEMM (ao x WoT) -> fp32. grid 512 swizzled.
// ---------------------------------------------------------------------------
__global__ __launch_bounds__(256)
void oproj_kernel(const f16_t* __restrict__ ao, const f16_t* __restrict__ woT,
                  float* __restrict__ out)
{
  __shared__ __align__(16) f16_t As[128][40], Bs[64][40];
  const int tid = threadIdx.x;
  const int lane = tid & 63, wave = tid >> 6;
  const int lo16 = lane & 15, hi4 = lane >> 4;
  const int lin = blockIdx.x;
  const int swz = (lin & 7) * 64 + (lin >> 3);
  const int m0 = (swz >> 4) * 128;
  const int col0 = (swz & 15) * 64;

  f32x4 acc[2][4];
  #pragma unroll
  for (int qb = 0; qb < 2; ++qb)
    #pragma unroll
    for (int j = 0; j < 4; ++j) acc[qb][j] = f32x4{0.f, 0.f, 0.f, 0.f};

  const int ar = tid >> 1, akc = (tid & 1) * 16;
  const int bn = tid & 63, bkc = (tid >> 6) * 8;

  f16x8 gA0, gA1, gB;
  auto LOADA = [&](int k0) {
    const f16_t* ap = &ao[(size_t)(m0 + ar) * PHID + k0 + akc];
    gA0 = *(const f16x8*)ap;
    gA1 = *(const f16x8*)(ap + 8);
  };
  auto LOADB = [&](int k0) {
    gB = *(const f16x8*)&woT[(size_t)(col0 + bn) * 1024 + k0 + bkc];
  };
  LOADA(0); LOADB(0);

  for (int k0 = 0; k0 < PHID; k0 += 32) {
    __syncthreads();
    *(f16x8*)&As[ar][akc]     = gA0;
    *(f16x8*)&As[ar][akc + 8] = gA1;
    *(f16x8*)&Bs[bn][bkc]     = gB;
    if (k0 + 32 < PHID) { LOADA(k0 + 32); LOADB(k0 + 32); }
    __syncthreads();
    {
      f16x8 a[2];
      #pragma unroll
      for (int qb = 0; qb < 2; ++qb)
        a[qb] = *(const f16x8*)&As[wave*32 + qb*16 + lo16][hi4*8];
      #pragma unroll
      for (int j = 0; j < 4; ++j) {
        f16x8 bb = *(const f16x8*)&Bs[j*16 + lo16][hi4*8];
        #pragma unroll
        for (int qb = 0; qb < 2; ++qb)
          acc[qb][j] = MFMAH(a[qb], bb, acc[qb][j]);
      }
    }
  }

  #pragma unroll
  for (int qb = 0; qb < 2; ++qb)
    #pragma unroll
    for (int r = 0; r < 4; ++r) {
      int mg = m0 + wave*32 + qb*16 + hi4*4 + r;
      #pragma unroll
      for (int j = 0; j < 4; ++j)
        out[(size_t)mg*PHID + col0 + lo16 + 16*j] = acc[qb][j][r];
    }
}

// ---------------------------------------------------------------------------
extern "C" void kernel_launch(void* const* d_in, const int* in_sizes, int n_in,
                              void* d_out, int out_size, void* d_ws, size_t ws_size,
                              hipStream_t stream) {
  (void)in_sizes; (void)n_in; (void)out_size; (void)ws_size;
  const float* hs   = (const float*)d_in[0];
  const float* cosp = (const float*)d_in[1];
  const float* sinp = (const float*)d_in[2];
  // d_in[3] position_ids: only shape[-1]=2 used (NDIM=2 hardcoded)
  const float* Wq   = (const float*)d_in[4];
  const float* Wk   = (const float*)d_in[5];
  const float* Wv   = (const float*)d_in[6];
  const float* Wo   = (const float*)d_in[7];
  const float* qnw  = (const float*)d_in[8];
  const float* knw  = (const float*)d_in[9];
  float* out = (float*)d_out;

  const size_t QN = (size_t)PB*PH*PS*PD;    // 4,194,304 (== PR*PD == PM*PHID)
  const size_t KN = (size_t)PB*PKV*PS*PD;   // 2,097,152
  const size_t HN = (size_t)PM*PHID;        // 4,194,304
  char* wsb = (char*)d_ws;
  f16_t*  qv  = (f16_t*)wsb;                   // QN fp16 (8 MB)
  f16_t*  kv  = qv + QN;                       // KN (4 MB)
  f16_t*  vt  = kv + KN;                       // KN (4 MB)
  f16_t*  hsf = vt + KN;                       // HN (8 MB, dead after qkv)
  f16_t*  wtT = hsf + HN;                      // 3072*1024 (6 MB; rows 2048+ live)
  f16_t*  op  = wtT + (size_t)3072*1024;       // 2*QN (16 MB)
  float2* ml  = (float2*)(op + 2*QN);          // 2*PR float2 (1 MB)
  f16_t*  ao  = qv;   // alias: attn done with Q before merge (stream-ordered)
  const f16_t* woT = wtT + (size_t)2048*1024;

  convert_hs<<<dim3(2048), 256, 0, stream>>>(hs, hsf);
  convert_w <<<dim3(768),  256, 0, stream>>>(Wq, Wk, Wv, Wo, wtT);
  qkv_kernel<<<dim3(1024), 256, 0, stream>>>(hsf, wtT, cosp, sinp,
                                             qnw, knw, qv, kv, vt);
  attn_kernel<<<dim3(1024), 256, 0, stream>>>(qv, kv, vt, op, ml);
  merge_kernel<<<dim3(PR*8/256), 256, 0, stream>>>(op, ml, ao);
  oproj_kernel<<<dim3(512), 256, 0, stream>>>(ao, woT, out);
}

// Round 8
// 126.602 us; speedup vs baseline: 2.2203x; 1.0365x over previous
//
#include <hip/hip_runtime.h>

// Problem constants
#define PB 2
#define PS 2048
#define PHID 1024
#define PH 16
#define PKV 8
#define PD 64
#define PM (PB*PS)    // 4096
#define PR (PB*PH*PS) // 65536 q-rows total

typedef _Float16 f16_t;
typedef _Float16 f16x8 __attribute__((ext_vector_type(8)));
typedef _Float16 f16x2 __attribute__((ext_vector_type(2)));
typedef float f32x4 __attribute__((ext_vector_type(4)));

#define MFMAH(a,b,c)  __builtin_amdgcn_mfma_f32_16x16x32_f16((a),(b),(c),0,0,0)
#define LOG2E 1.44269504f

// global -> LDS direct copy, 16B per lane (dst = uniform base + lane*16).
__device__ __forceinline__ void gl16(const f16_t* g, f16_t* l) {
  __builtin_amdgcn_global_load_lds(
      (const __attribute__((address_space(1))) void*)g,
      (__attribute__((address_space(3))) void*)l, 16, 0, 0);
}

// ---------------------------------------------------------------------------
// Kernel 0a: hs fp32 -> fp16.
// ---------------------------------------------------------------------------
__global__ __launch_bounds__(256)
void convert_hs(const float* __restrict__ hs, f16_t* __restrict__ hf)
{
  const size_t i = ((size_t)blockIdx.x * 256 + threadIdx.x) * 8;
  float4 a = *(const float4*)&hs[i];
  float4 b = *(const float4*)&hs[i + 4];
  float xs[8] = {a.x, a.y, a.z, a.w, b.x, b.y, b.z, b.w};
  f16x8 v;
  #pragma unroll
  for (int j = 0; j < 8; ++j) v[j] = (f16_t)xs[j];
  *(f16x8*)&hf[i] = v;
}

// ---------------------------------------------------------------------------
// Kernel 0b: weights -> transposed [n][k] fp16 (rows: Wq^T 0-1023, Wk^T
// 1024-1535, Wv^T 1536-2047, Wo^T 2048-3071). grid 768.
// ---------------------------------------------------------------------------
__global__ __launch_bounds__(256)
void convert_w(const float* __restrict__ Wq, const float* __restrict__ Wk,
               const float* __restrict__ Wv, const float* __restrict__ Wo,
               f16_t* __restrict__ wtT)
{
  __shared__ float Tt[64][68];
  const int tid = threadIdx.x;
  const int slot = blockIdx.x >> 4, k0 = (blockIdx.x & 15) * 64;

  const float* src; int N, ncol0, orow0;
  if (slot < 16)      { src = Wq; N = 1024; ncol0 = slot*64;      orow0 = slot*64; }
  else if (slot < 24) { src = Wk; N = 512;  ncol0 = (slot-16)*64; orow0 = 1024 + (slot-16)*64; }
  else if (slot < 32) { src = Wv; N = 512;  ncol0 = (slot-24)*64; orow0 = 1536 + (slot-24)*64; }
  else                { src = Wo; N = 1024; ncol0 = (slot-32)*64; orow0 = 2048 + (slot-32)*64; }

  const int tk = tid >> 6, tn = tid & 63;
  #pragma unroll
  for (int i = 0; i < 16; ++i)
    Tt[tn][tk*16 + i] = src[(size_t)(k0 + tk*16 + i) * N + ncol0 + tn];
  __syncthreads();

  const int n = tid >> 2, kc = (tid & 3) * 16;
  f16x8 a0, a1;
  #pragma unroll
  for (int i = 0; i < 8; ++i) {
    a0[i] = (f16_t)Tt[n][kc + i];
    a1[i] = (f16_t)Tt[n][kc + 8 + i];
  }
  const size_t ob = (size_t)(orow0 + n) * 1024 + k0 + kc;
  *(f16x8*)&wtT[ob]     = a0;
  *(f16x8*)&wtT[ob + 8] = a1;
}

// ---------------------------------------------------------------------------
// Kernel 1: QKV projection fp16 GEMM + RMSNorm + RoPE. V is stored with the
// PV-feeding kv-permutation baked in (per 64-block: s2<-g4, s3<-g2, s4<-g3),
// so attn's PV B-operand becomes lane-local. grid 1024 XCD-swizzled.
// ---------------------------------------------------------------------------
__global__ __launch_bounds__(256)
void qkv_kernel(const f16_t* __restrict__ hsf, const f16_t* __restrict__ wtT,
                const float* __restrict__ cosp, const float* __restrict__ sinp,
                const float* __restrict__ qnw, const float* __restrict__ knw,
                f16_t* __restrict__ q_o, f16_t* __restrict__ k_o,
                f16_t* __restrict__ vt_o)
{
  __shared__ __align__(16) f16_t Ah[128][64];  // 16 KB
  __shared__ __align__(16) f16_t Bh[64][64];   // 8 KB

  const int tid = threadIdx.x;
  const int lane = tid & 63, wave = tid >> 6;
  const int lo16 = lane & 15, hi4 = lane >> 4;
  const int lin = blockIdx.x;
  const int swz = (lin & 7) * 128 + (lin >> 3);
  const int m0 = (swz >> 5) * 128;
  const int slot = swz & 31;

  int kind, hd, orow;
  if (slot < 16)      { kind = 0; hd = slot;      orow = slot*64; }
  else if (slot < 24) { kind = 1; hd = slot - 16; orow = 1024 + hd*64; }
  else                { kind = 2; hd = slot - 24; orow = 1536 + hd*64; }

  f32x4 acc[2][4];
  #pragma unroll
  for (int qb = 0; qb < 2; ++qb)
    #pragma unroll
    for (int j = 0; j < 4; ++j) acc[qb][j] = f32x4{0.f, 0.f, 0.f, 0.f};

  const int ri = lane >> 3, pc = lane & 7;
  const int lcs = (pc ^ ri) * 8;   // pre-swizzled global chunk
  size_t aoff4[4]; f16_t* aldst4[4];
  #pragma unroll
  for (int q = 0; q < 4; ++q) {
    aoff4[q] = (size_t)(m0 + wave*32 + q*8 + ri) * PHID + lcs;
    aldst4[q] = &Ah[wave*32 + q*8][0];
  }
  size_t boff[2]; int brow[2];
  #pragma unroll
  for (int q = 0; q < 2; ++q) {
    brow[q] = wave*16 + q*8;
    boff[q] = (size_t)(orow + brow[q] + ri) * 1024 + lcs;
  }

  const int rsw = lo16 & 7;

  for (int k0 = 0; k0 < PHID; k0 += 64) {
    __syncthreads();
    #pragma unroll
    for (int q = 0; q < 4; ++q) gl16(hsf + aoff4[q] + k0, aldst4[q]);
    #pragma unroll
    for (int q = 0; q < 2; ++q) gl16(wtT + boff[q] + k0, &Bh[brow[q]][0]);
    __syncthreads();

    #pragma unroll
    for (int t = 0; t < 2; ++t) {
      const int ccol = ((t*4 + hi4) ^ rsw) * 8;
      f16x8 ah[2];
      #pragma unroll
      for (int qb = 0; qb < 2; ++qb)
        ah[qb] = *(const f16x8*)&Ah[wave*32 + qb*16 + lo16][ccol];
      #pragma unroll
      for (int j = 0; j < 4; ++j) {
        f16x8 bh = *(const f16x8*)&Bh[j*16 + lo16][ccol];
        #pragma unroll
        for (int qb = 0; qb < 2; ++qb)
          acc[qb][j] = MFMAH(ah[qb], bh, acc[qb][j]);
      }
    }
  }

  // ---- epilogue: RMSNorm + RoPE; fp16 stores ----
  #pragma unroll
  for (int qb = 0; qb < 2; ++qb) {
    float scale[4];
    #pragma unroll
    for (int r = 0; r < 4; ++r) {
      float s = 0.f;
      #pragma unroll
      for (int j = 0; j < 4; ++j) s += acc[qb][j][r] * acc[qb][j][r];
      #pragma unroll
      for (int m = 1; m < 16; m <<= 1) s += __shfl_xor(s, m);
      scale[r] = 1.0f / sqrtf(s * (1.0f/64.0f) + 1e-6f);
    }
    float nw[4];
    #pragma unroll
    for (int j = 0; j < 4; ++j)
      nw[j] = (kind == 0) ? qnw[lo16 + 16*j] : (kind == 1 ? knw[lo16 + 16*j] : 1.0f);

    float y[4][4];
    #pragma unroll
    for (int j = 0; j < 4; ++j)
      #pragma unroll
      for (int r = 0; r < 4; ++r) y[j][r] = acc[qb][j][r] * scale[r] * nw[j];

    if (kind == 2) {
      #pragma unroll
      for (int r = 0; r < 4; ++r) {
        int mg = m0 + wave*32 + qb*16 + hi4*4 + r;
        int b = mg >> 11, sq = mg & 2047;
        // kv-permutation within each 64-block: slot s holds logical g where
        // g = lambda(s); store g at s: s10=g10, s2=g4, s3=g2, s4=g3, s5=g5.
        int g = sq & 63;
        int sp = (g & 3) | (((g >> 4) & 1) << 2) | (((g >> 2) & 1) << 3)
               | (((g >> 3) & 1) << 4) | (g & 32);
        int sq2 = (sq & ~63) | sp;
        #pragma unroll
        for (int j = 0; j < 4; ++j) {
          int d = lo16 + 16*j;
          vt_o[((size_t)((b*PKV + hd)*PD + d))*PS + sq2] = (f16_t)y[j][r];
        }
      }
    } else {
      #pragma unroll
      for (int r = 0; r < 4; ++r) {
        int mg = m0 + wave*32 + qb*16 + hi4*4 + r;
        int b = mg >> 11, sq = mg & 2047;
        const float* cp = &cosp[(size_t)mg * PD];
        const float* sp = &sinp[(size_t)mg * PD];
        float z[4];
        #pragma unroll
        for (int j = 0; j < 4; ++j) {
          float c = cp[lo16 + 16*j], s = sp[lo16 + 16*j];
          float rot = (j & 1) ? y[j-1][r] : -y[j+1][r];
          z[j] = y[j][r] * c + rot * s;
        }
        #pragma unroll
        for (int j = 0; j < 4; ++j) {
          int d = lo16 + 16*j;
          if (kind == 0) {
            size_t idx = ((size_t)(b*PH + hd)*PS + sq)*PD + d;
            q_o[idx] = (f16_t)(z[j] * LOG2E);   // exp2-domain fold
          } else {
            size_t idx = ((size_t)(b*PKV + hd)*PS + sq)*PD + d;
            k_o[idx] = (f16_t)z[j];
          }
        }
      }
    }
  }
}

// ---------------------------------------------------------------------------
// Kernel 2: flash attention. gl16 double-buffered K/V staging (XOR-swizzled),
// lane-local P via pre-permuted V (zero P LDS traffic), exp2 softmax +
// defer-max, kv-split x2. grid 1024 XCD-swizzled. LDS 32 KB.
// ---------------------------------------------------------------------------
__global__ __launch_bounds__(256, 4)
void attn_kernel(const f16_t* __restrict__ q_g, const f16_t* __restrict__ k_g,
                 const f16_t* __restrict__ vt_g,
                 f16_t* __restrict__ op, float2* __restrict__ ml)
{
  __shared__ __align__(16) char lds_raw[32768];
  f16_t (*Ks)[64][64] = (f16_t (*)[64][64])lds_raw;             // [2][64][64]
  f16_t (*Vs)[64][64] = (f16_t (*)[64][64])(lds_raw + 16384);   // [2][64][64]
  f16_t (*Ob)[72]     = (f16_t (*)[72])lds_raw;                 // epilogue overlay

  const int tid = threadIdx.x, lane = tid & 63, wave = tid >> 6;
  const int lo16 = lane & 15, hi4 = lane >> 4;
  const int lin = blockIdx.x;
  const int swz = (lin & 7) * 128 + (lin >> 3);
  const int qt = swz & 15;
  const int bh = (swz >> 4) & 31;
  const int ks = swz >> 9;
  const int b = bh >> 4, h = bh & 15, kvh = h >> 1;   // GQA groups=2

  f16x8 qf[2][2];
  #pragma unroll
  for (int qb = 0; qb < 2; ++qb) {
    const size_t qbase = ((size_t)(b*PH + h)*PS + qt*128 + wave*32 + qb*16 + lo16) * PD;
    #pragma unroll
    for (int t = 0; t < 2; ++t)
      qf[qb][t] = *(const f16x8*)&q_g[qbase + t*32 + hi4*8];
  }

  f32x4 o[2][4];
  float mq[2] = {-1e30f, -1e30f}, lq[2] = {0.f, 0.f};
  #pragma unroll
  for (int qb = 0; qb < 2; ++qb)
    #pragma unroll
    for (int j = 0; j < 4; ++j) o[qb][j] = f32x4{0.f, 0.f, 0.f, 0.f};

  const int ri = lane >> 3;
  const int lcs = ((lane & 7) ^ ri) * 8;   // pre-swizzled global chunk
  const size_t kbase = (size_t)(b*PKV + kvh) * PS * PD + (size_t)ks * 1024 * PD;
  const size_t vbase = (size_t)(b*PKV + kvh) * PD * PS + (size_t)ks * 1024;

  auto STAGE = [&](int kt, int buf) {
    const f16_t* kp = k_g + kbase + (size_t)kt * 64 * PD;
    const f16_t* vp = vt_g + vbase + kt * 64;
    #pragma unroll
    for (int i = 0; i < 2; ++i) {
      const int st = wave*2 + i;   // stripe of 8 rows
      gl16(kp + (st*8 + ri)*PD + lcs, &Ks[buf][st*8][0]);
      gl16(vp + (size_t)(st*8 + ri)*PS + lcs, &Vs[buf][st*8][0]);
    }
  };

  STAGE(0, 0);
  int cur = 0;
  const int rsw = lo16 & 7;

  for (int kt = 0; kt < 16; ++kt) {
    __syncthreads();   // drains vmcnt: buf[cur] ready; prev reads of buf[cur^1] done
    if (kt + 1 < 16) STAGE(kt + 1, cur ^ 1);

    // QK^T swapped: sacc[qb][j][r] = S'[kv = 16j + 4hi4 + r][q = 16qb + lo16]
    f32x4 sacc[2][4];
    #pragma unroll
    for (int qb = 0; qb < 2; ++qb)
      #pragma unroll
      for (int j = 0; j < 4; ++j) sacc[qb][j] = f32x4{0.f, 0.f, 0.f, 0.f};
    __builtin_amdgcn_s_setprio(1);
    #pragma unroll
    for (int j = 0; j < 4; ++j) {
      #pragma unroll
      for (int t = 0; t < 2; ++t) {
        f16x8 kf = *(const f16x8*)&Ks[cur][j*16 + lo16][((t*4 + hi4) ^ rsw) * 8];
        #pragma unroll
        for (int qb = 0; qb < 2; ++qb)
          sacc[qb][j] = MFMAH(kf, qf[qb][t], sacc[qb][j]);
      }
    }
    __builtin_amdgcn_s_setprio(0);

    // exp2-domain online softmax with defer-max (THR=8)
    #pragma unroll
    for (int qb = 0; qb < 2; ++qb) {
      float tm = sacc[qb][0][0];
      #pragma unroll
      for (int j = 0; j < 4; ++j)
        #pragma unroll
        for (int r = 0; r < 4; ++r) tm = fmaxf(tm, sacc[qb][j][r]);
      tm = fmaxf(tm, __shfl_xor(tm, 16));
      tm = fmaxf(tm, __shfl_xor(tm, 32));
      if (!__all(tm <= mq[qb] + 8.0f)) {
        float mnew = fmaxf(mq[qb], tm);
        float alpha = __builtin_amdgcn_exp2f(mq[qb] - mnew);
        lq[qb] *= alpha;
        #pragma unroll
        for (int jd = 0; jd < 4; ++jd) o[qb][jd] *= alpha;
        mq[qb] = mnew;
      }
      float ls = 0.f;
      #pragma unroll
      for (int j = 0; j < 4; ++j)
        #pragma unroll
        for (int r = 0; r < 4; ++r) {
          float p = __builtin_amdgcn_exp2f(sacc[qb][j][r] - mq[qb]);
          sacc[qb][j][r] = p;
          ls += p;
        }
      ls += __shfl_xor(ls, 16);
      ls += __shfl_xor(ls, 32);
      lq[qb] += ls;
    }

    // P fragments are lane-local thanks to V's kv-permutation:
    // pa[qb][t][e] = P[kv = lambda(32t+8*hi4+e)][q] = sacc[qb][2t+(e>>2)][e&3]
    f16x8 pa[2][2];
    #pragma unroll
    for (int qb = 0; qb < 2; ++qb)
      #pragma unroll
      for (int t = 0; t < 2; ++t) {
        f16x8 v;
        #pragma unroll
        for (int e = 0; e < 8; ++e)
          v[e] = (f16_t)sacc[qb][2*t + (e >> 2)][e & 3];
        pa[qb][t] = v;
      }

    // PV: O^T = V^T(permuted) * P
    __builtin_amdgcn_s_setprio(1);
    #pragma unroll
    for (int jd = 0; jd < 4; ++jd) {
      #pragma unroll
      for (int t = 0; t < 2; ++t) {
        f16x8 vf = *(const f16x8*)&Vs[cur][jd*16 + lo16][((t*4 + hi4) ^ rsw) * 8];
        #pragma unroll
        for (int qb = 0; qb < 2; ++qb)
          o[qb][jd] = MFMAH(vf, pa[qb][t], o[qb][jd]);
      }
    }
    __builtin_amdgcn_s_setprio(0);

    cur ^= 1;
  }

  // ---- epilogue: (m,l) + normalized O via LDS transpose bounce ----
  __syncthreads();   // all waves done with K/V tiles; overlay is safe
  const int rbase = bh*PS + qt*128 + wave*32;
  if (hi4 == 0) {
    #pragma unroll
    for (int qb = 0; qb < 2; ++qb)
      ml[(size_t)ks*PR + rbase + qb*16 + lo16] = float2{mq[qb], lq[qb]};
  }
  #pragma unroll
  for (int qb = 0; qb < 2; ++qb) {
    float inv = 1.0f / lq[qb];
    #pragma unroll
    for (int jd = 0; jd < 4; ++jd)
      #pragma unroll
      for (int rp = 0; rp < 2; ++rp)
        *(f16x2*)&Ob[wave*32 + qb*16 + lo16][jd*16 + hi4*4 + 2*rp] =
            f16x2{(f16_t)(o[qb][jd][2*rp] * inv), (f16_t)(o[qb][jd][2*rp+1] * inv)};
  }
  {
    const int row = lane >> 1, half = lane & 1;
    const size_t gb_ = ((size_t)ks*PR + rbase + row) * PD + half*32;
    #pragma unroll
    for (int c = 0; c < 4; ++c)
      *(f16x8*)&op[gb_ + c*8] = *(const f16x8*)&Ob[wave*32 + row][half*32 + c*8];
  }
}

// ---------------------------------------------------------------------------
// Kernel 3: merge kv-split partials (normalized O + m,l in log2 domain).
// ---------------------------------------------------------------------------
__global__ __launch_bounds__(256)
void merge_kernel(const f16_t* __restrict__ op, const float2* __restrict__ ml,
                  f16_t* __restrict__ ao)
{
  const int gid = blockIdx.x * 256 + threadIdx.x;
  const int row = gid >> 3, oct = gid & 7;
  float2 e0 = ml[row], e1 = ml[PR + row];
  float M = fmaxf(e0.x, e1.x);
  float c0 = __builtin_amdgcn_exp2f(e0.x - M) * e0.y;
  float c1 = __builtin_amdgcn_exp2f(e1.x - M) * e1.y;
  float inv = 1.0f / (c0 + c1);
  c0 *= inv; c1 *= inv;
  f16x8 a = *(const f16x8*)&op[(size_t)row*PD + oct*8];
  f16x8 bq = *(const f16x8*)&op[(size_t)(PR + row)*PD + oct*8];
  f16x8 r;
  #pragma unroll
  for (int i = 0; i < 8; ++i)
    r[i] = (f16_t)(c0 * (float)a[i] + c1 * (float)bq[i]);
  const int bh = row >> 11, sq = row & 2047;
  const int b = bh >> 4, h = bh & 15;
  *(f16x8*)&ao[((size_t)(b*PS + sq))*PHID + h*PD + oct*8] = r;
}

// ---------------------------------------------------------------------------
// Kernel 4: out-projection, fp16 GEMM (ao x WoT) -> fp32. grid 512 swizzled.
// ---------------------------------------------------------------------------
__global__ __launch_bounds__(256)
void oproj_kernel(const f16_t* __restrict__ ao, const f16_t* __restrict__ woT,
                  float* __restrict__ out)
{
  __shared__ __align__(16) f16_t As[128][40], Bs[64][40];
  const int tid = threadIdx.x;
  const int lane = tid & 63, wave = tid >> 6;
  const int lo16 = lane & 15, hi4 = lane >> 4;
  const int lin = blockIdx.x;
  const int swz = (lin & 7) * 64 + (lin >> 3);
  const int m0 = (swz >> 4) * 128;
  const int col0 = (swz & 15) * 64;

  f32x4 acc[2][4];
  #pragma unroll
  for (int qb = 0; qb < 2; ++qb)
    #pragma unroll
    for (int j = 0; j < 4; ++j) acc[qb][j] = f32x4{0.f, 0.f, 0.f, 0.f};

  const int ar = tid >> 1, akc = (tid & 1) * 16;
  const int bn = tid & 63, bkc = (tid >> 6) * 8;

  f16x8 gA0, gA1, gB;
  auto LOADA = [&](int k0) {
    const f16_t* ap = &ao[(size_t)(m0 + ar) * PHID + k0 + akc];
    gA0 = *(const f16x8*)ap;
    gA1 = *(const f16x8*)(ap + 8);
  };
  auto LOADB = [&](int k0) {
    gB = *(const f16x8*)&woT[(size_t)(col0 + bn) * 1024 + k0 + bkc];
  };
  LOADA(0); LOADB(0);

  for (int k0 = 0; k0 < PHID; k0 += 32) {
    __syncthreads();
    *(f16x8*)&As[ar][akc]     = gA0;
    *(f16x8*)&As[ar][akc + 8] = gA1;
    *(f16x8*)&Bs[bn][bkc]     = gB;
    if (k0 + 32 < PHID) { LOADA(k0 + 32); LOADB(k0 + 32); }
    __syncthreads();
    {
      f16x8 a[2];
      #pragma unroll
      for (int qb = 0; qb < 2; ++qb)
        a[qb] = *(const f16x8*)&As[wave*32 + qb*16 + lo16][hi4*8];
      #pragma unroll
      for (int j = 0; j < 4; ++j) {
        f16x8 bb = *(const f16x8*)&Bs[j*16 + lo16][hi4*8];
        #pragma unroll
        for (int qb = 0; qb < 2; ++qb)
          acc[qb][j] = MFMAH(a[qb], bb, acc[qb][j]);
      }
    }
  }

  #pragma unroll
  for (int qb = 0; qb < 2; ++qb)
    #pragma unroll
    for (int r = 0; r < 4; ++r) {
      int mg = m0 + wave*32 + qb*16 + hi4*4 + r;
      #pragma unroll
      for (int j = 0; j < 4; ++j)
        out[(size_t)mg*PHID + col0 + lo16 + 16*j] = acc[qb][j][r];
    }
}

// ---------------------------------------------------------------------------
extern "C" void kernel_launch(void* const* d_in, const int* in_sizes, int n_in,
                              void* d_out, int out_size, void* d_ws, size_t ws_size,
                              hipStream_t stream) {
  (void)in_sizes; (void)n_in; (void)out_size; (void)ws_size;
  const float* hs   = (const float*)d_in[0];
  const float* cosp = (const float*)d_in[1];
  const float* sinp = (const float*)d_in[2];
  // d_in[3] position_ids: only shape[-1]=2 used (NDIM=2 hardcoded)
  const float* Wq   = (const float*)d_in[4];
  const float* Wk   = (const float*)d_in[5];
  const float* Wv   = (const float*)d_in[6];
  const float* Wo   = (const float*)d_in[7];
  const float* qnw  = (const float*)d_in[8];
  const float* knw  = (const float*)d_in[9];
  float* out = (float*)d_out;

  const size_t QN = (size_t)PB*PH*PS*PD;    // 4,194,304 (== PR*PD == PM*PHID)
  const size_t KN = (size_t)PB*PKV*PS*PD;   // 2,097,152
  const size_t HN = (size_t)PM*PHID;        // 4,194,304
  char* wsb = (char*)d_ws;
  f16_t*  qv  = (f16_t*)wsb;                   // QN fp16 (8 MB)
  f16_t*  kv  = qv + QN;                       // KN (4 MB)
  f16_t*  vt  = kv + KN;                       // KN (4 MB)
  f16_t*  hsf = vt + KN;                       // HN (8 MB, dead after qkv)
  f16_t*  wtT = hsf + HN;                      // 3072*1024 (6 MB; rows 2048+ live)
  f16_t*  op  = wtT + (size_t)3072*1024;       // 2*QN (16 MB)
  float2* ml  = (float2*)(op + 2*QN);          // 2*PR float2 (1 MB)
  f16_t*  ao  = qv;   // alias: attn done with Q before merge (stream-ordered)
  const f16_t* woT = wtT + (size_t)2048*1024;

  convert_hs<<<dim3(2048), 256, 0, stream>>>(hs, hsf);
  convert_w <<<dim3(768),  256, 0, stream>>>(Wq, Wk, Wv, Wo, wtT);
  qkv_kernel<<<dim3(1024), 256, 0, stream>>>(hsf, wtT, cosp, sinp,
                                             qnw, knw, qv, kv, vt);
  attn_kernel<<<dim3(1024), 256, 0, stream>>>(qv, kv, vt, op, ml);
  merge_kernel<<<dim3(PR*8/256), 256, 0, stream>>>(op, ml, ao);
  oproj_kernel<<<dim3(512), 256, 0, stream>>>(ao, woT, out);
}

// Round 9
// 119.191 us; speedup vs baseline: 2.3584x; 1.0622x over previous
//
#include <hip/hip_runtime.h>

// Problem constants
#define PB 2
#define PS 2048
#define PHID 1024
#define PH 16
#define PKV 8
#define PD 64
#define PM (PB*PS)    // 4096
#define PR (PB*PH*PS) // 65536 q-rows total

typedef _Float16 f16_t;
typedef _Float16 f16x8 __attribute__((ext_vector_type(8)));
typedef _Float16 f16x2 __attribute__((ext_vector_type(2)));
typedef float f32x4 __attribute__((ext_vector_type(4)));

#define MFMAH(a,b,c)  __builtin_amdgcn_mfma_f32_16x16x32_f16((a),(b),(c),0,0,0)
#define LOG2E 1.44269504f

// global -> LDS direct copy, 16B per lane (dst = uniform base + lane*16).
__device__ __forceinline__ void gl16(const f16_t* g, f16_t* l) {
  __builtin_amdgcn_global_load_lds(
      (const __attribute__((address_space(1))) void*)g,
      (__attribute__((address_space(3))) void*)l, 16, 0, 0);
}

// ---------------------------------------------------------------------------
// Kernel 0a: hs fp32 -> fp16.
// ---------------------------------------------------------------------------
__global__ __launch_bounds__(256)
void convert_hs(const float* __restrict__ hs, f16_t* __restrict__ hf)
{
  const size_t i = ((size_t)blockIdx.x * 256 + threadIdx.x) * 8;
  float4 a = *(const float4*)&hs[i];
  float4 b = *(const float4*)&hs[i + 4];
  float xs[8] = {a.x, a.y, a.z, a.w, b.x, b.y, b.z, b.w};
  f16x8 v;
  #pragma unroll
  for (int j = 0; j < 8; ++j) v[j] = (f16_t)xs[j];
  *(f16x8*)&hf[i] = v;
}

// ---------------------------------------------------------------------------
// Kernel 0b: weights -> transposed [n][k] fp16 (rows: Wq^T 0-1023, Wk^T
// 1024-1535, Wv^T 1536-2047, Wo^T 2048-3071). grid 768.
// ---------------------------------------------------------------------------
__global__ __launch_bounds__(256)
void convert_w(const float* __restrict__ Wq, const float* __restrict__ Wk,
               const float* __restrict__ Wv, const float* __restrict__ Wo,
               f16_t* __restrict__ wtT)
{
  __shared__ float Tt[64][68];
  const int tid = threadIdx.x;
  const int slot = blockIdx.x >> 4, k0 = (blockIdx.x & 15) * 64;

  const float* src; int N, ncol0, orow0;
  if (slot < 16)      { src = Wq; N = 1024; ncol0 = slot*64;      orow0 = slot*64; }
  else if (slot < 24) { src = Wk; N = 512;  ncol0 = (slot-16)*64; orow0 = 1024 + (slot-16)*64; }
  else if (slot < 32) { src = Wv; N = 512;  ncol0 = (slot-24)*64; orow0 = 1536 + (slot-24)*64; }
  else                { src = Wo; N = 1024; ncol0 = (slot-32)*64; orow0 = 2048 + (slot-32)*64; }

  const int tk = tid >> 6, tn = tid & 63;
  #pragma unroll
  for (int i = 0; i < 16; ++i)
    Tt[tn][tk*16 + i] = src[(size_t)(k0 + tk*16 + i) * N + ncol0 + tn];
  __syncthreads();

  const int n = tid >> 2, kc = (tid & 3) * 16;
  f16x8 a0, a1;
  #pragma unroll
  for (int i = 0; i < 8; ++i) {
    a0[i] = (f16_t)Tt[n][kc + i];
    a1[i] = (f16_t)Tt[n][kc + 8 + i];
  }
  const size_t ob = (size_t)(orow0 + n) * 1024 + k0 + kc;
  *(f16x8*)&wtT[ob]     = a0;
  *(f16x8*)&wtT[ob + 8] = a1;
}

// ---------------------------------------------------------------------------
// Kernel 1: QKV projection fp16 GEMM, WIDE SLOTS (128 cols = 2 heads/block).
// grid 512 XCD-swizzled = 32 row-tiles x 16 wide-slots (ws<8 Q, <12 K, else V).
// Per-head RMSNorm + RoPE epilogue; V stored kv-permuted for lane-local PV.
// ---------------------------------------------------------------------------
__global__ __launch_bounds__(256)
void qkv_kernel(const f16_t* __restrict__ hsf, const f16_t* __restrict__ wtT,
                const float* __restrict__ cosp, const float* __restrict__ sinp,
                const float* __restrict__ qnw, const float* __restrict__ knw,
                f16_t* __restrict__ q_o, f16_t* __restrict__ k_o,
                f16_t* __restrict__ vt_o)
{
  __shared__ __align__(16) f16_t Ah[128][64];  // 16 KB
  __shared__ __align__(16) f16_t Bh[128][64];  // 16 KB

  const int tid = threadIdx.x;
  const int lane = tid & 63, wave = tid >> 6;
  const int lo16 = lane & 15, hi4 = lane >> 4;
  const int lin = blockIdx.x;
  const int swz = (lin & 7) * 64 + (lin >> 3);   // 512 = 8 * 64, bijective
  const int m0 = (swz >> 4) * 128;
  const int ws = swz & 15;
  const int orow = ws * 128;

  int kind, hd0;
  if (ws < 8)       { kind = 0; hd0 = ws*2; }
  else if (ws < 12) { kind = 1; hd0 = (ws-8)*2; }
  else              { kind = 2; hd0 = (ws-12)*2; }

  f32x4 acc[2][8];
  #pragma unroll
  for (int qb = 0; qb < 2; ++qb)
    #pragma unroll
    for (int j = 0; j < 8; ++j) acc[qb][j] = f32x4{0.f, 0.f, 0.f, 0.f};

  const int ri = lane >> 3, pc = lane & 7;
  const int lcs = (pc ^ ri) * 8;   // pre-swizzled global chunk
  size_t aoff4[4]; f16_t* aldst4[4];
  size_t boff4[4]; f16_t* bldst4[4];
  #pragma unroll
  for (int q = 0; q < 4; ++q) {
    aoff4[q] = (size_t)(m0 + wave*32 + q*8 + ri) * PHID + lcs;
    aldst4[q] = &Ah[wave*32 + q*8][0];
    boff4[q] = (size_t)(orow + wave*32 + q*8 + ri) * 1024 + lcs;
    bldst4[q] = &Bh[wave*32 + q*8][0];
  }

  const int rsw = lo16 & 7;

  for (int k0 = 0; k0 < PHID; k0 += 64) {
    __syncthreads();
    #pragma unroll
    for (int q = 0; q < 4; ++q) gl16(hsf + aoff4[q] + k0, aldst4[q]);
    #pragma unroll
    for (int q = 0; q < 4; ++q) gl16(wtT + boff4[q] + k0, bldst4[q]);
    __syncthreads();

    #pragma unroll
    for (int t = 0; t < 2; ++t) {
      const int ccol = ((t*4 + hi4) ^ rsw) * 8;
      f16x8 ah[2];
      #pragma unroll
      for (int qb = 0; qb < 2; ++qb)
        ah[qb] = *(const f16x8*)&Ah[wave*32 + qb*16 + lo16][ccol];
      #pragma unroll
      for (int j = 0; j < 8; ++j) {
        f16x8 bh = *(const f16x8*)&Bh[j*16 + lo16][ccol];
        #pragma unroll
        for (int qb = 0; qb < 2; ++qb)
          acc[qb][j] = MFMAH(ah[qb], bh, acc[qb][j]);
      }
    }
  }

  // ---- epilogue: per-head RMSNorm + RoPE; fp16 stores ----
  float nwv[4];
  #pragma unroll
  for (int jj = 0; jj < 4; ++jj)
    nwv[jj] = (kind == 0) ? qnw[lo16 + 16*jj]
            : (kind == 1) ? knw[lo16 + 16*jj] : 1.0f;

  #pragma unroll
  for (int qb = 0; qb < 2; ++qb) {
    float sc[2][4];
    #pragma unroll
    for (int r = 0; r < 4; ++r) {
      float s0 = 0.f, s1 = 0.f;
      #pragma unroll
      for (int j = 0; j < 4; ++j) {
        s0 += acc[qb][j][r]   * acc[qb][j][r];
        s1 += acc[qb][j+4][r] * acc[qb][j+4][r];
      }
      #pragma unroll
      for (int m = 1; m < 16; m <<= 1) {
        s0 += __shfl_xor(s0, m);
        s1 += __shfl_xor(s1, m);
      }
      sc[0][r] = 1.0f / sqrtf(s0 * (1.0f/64.0f) + 1e-6f);
      sc[1][r] = 1.0f / sqrtf(s1 * (1.0f/64.0f) + 1e-6f);
    }

    float y[8][4];
    #pragma unroll
    for (int j = 0; j < 8; ++j)
      #pragma unroll
      for (int r = 0; r < 4; ++r)
        y[j][r] = acc[qb][j][r] * sc[j>>2][r] * nwv[j&3];

    if (kind == 2) {
      #pragma unroll
      for (int r = 0; r < 4; ++r) {
        int mg = m0 + wave*32 + qb*16 + hi4*4 + r;
        int b = mg >> 11, sq = mg & 2047;
        int g = sq & 63;
        int sp = (g & 3) | (((g >> 4) & 1) << 2) | (((g >> 2) & 1) << 3)
               | (((g >> 3) & 1) << 4) | (g & 32);
        int sq2 = (sq & ~63) | sp;
        #pragma unroll
        for (int j = 0; j < 8; ++j) {
          int d = lo16 + 16*(j & 3), hd = hd0 + (j >> 2);
          vt_o[((size_t)((b*PKV + hd)*PD + d))*PS + sq2] = (f16_t)y[j][r];
        }
      }
    } else {
      #pragma unroll
      for (int r = 0; r < 4; ++r) {
        int mg = m0 + wave*32 + qb*16 + hi4*4 + r;
        int b = mg >> 11, sq = mg & 2047;
        const float* cp = &cosp[(size_t)mg * PD];
        const float* sp = &sinp[(size_t)mg * PD];
        float z[8];
        #pragma unroll
        for (int j = 0; j < 8; ++j) {
          int d = lo16 + 16*(j & 3);
          float c = cp[d], s = sp[d];
          float rot = (j & 1) ? y[j-1][r] : -y[j+1][r];
          z[j] = y[j][r] * c + rot * s;
        }
        #pragma unroll
        for (int j = 0; j < 8; ++j) {
          int d = lo16 + 16*(j & 3), hd = hd0 + (j >> 2);
          if (kind == 0) {
            size_t idx = ((size_t)(b*PH + hd)*PS + sq)*PD + d;
            q_o[idx] = (f16_t)(z[j] * LOG2E);   // exp2-domain fold
          } else {
            size_t idx = ((size_t)(b*PKV + hd)*PS + sq)*PD + d;
            k_o[idx] = (f16_t)z[j];
          }
        }
      }
    }
  }
}

// ---------------------------------------------------------------------------
// Kernel 2: flash attention. gl16 double-buffered K/V (XOR-swizzled),
// lane-local P, exp2 softmax + defer-max. VALU-lean softmax: fused exp+pack
// (no sacc write-back), zero-C first MFMA, pairwise max tree.
// grid 1024 XCD-swizzled. LDS 32 KB.
// ---------------------------------------------------------------------------
__global__ __launch_bounds__(256, 4)
void attn_kernel(const f16_t* __restrict__ q_g, const f16_t* __restrict__ k_g,
                 const f16_t* __restrict__ vt_g,
                 f16_t* __restrict__ op, float2* __restrict__ ml)
{
  __shared__ __align__(16) char lds_raw[32768];
  f16_t (*Ks)[64][64] = (f16_t (*)[64][64])lds_raw;             // [2][64][64]
  f16_t (*Vs)[64][64] = (f16_t (*)[64][64])(lds_raw + 16384);   // [2][64][64]
  f16_t (*Ob)[72]     = (f16_t (*)[72])lds_raw;                 // epilogue overlay

  const int tid = threadIdx.x, lane = tid & 63, wave = tid >> 6;
  const int lo16 = lane & 15, hi4 = lane >> 4;
  const int lin = blockIdx.x;
  const int swz = (lin & 7) * 128 + (lin >> 3);
  const int qt = swz & 15;
  const int bh = (swz >> 4) & 31;
  const int ks = swz >> 9;
  const int b = bh >> 4, h = bh & 15, kvh = h >> 1;   // GQA groups=2

  f16x8 qf[2][2];
  #pragma unroll
  for (int qb = 0; qb < 2; ++qb) {
    const size_t qbase = ((size_t)(b*PH + h)*PS + qt*128 + wave*32 + qb*16 + lo16) * PD;
    #pragma unroll
    for (int t = 0; t < 2; ++t)
      qf[qb][t] = *(const f16x8*)&q_g[qbase + t*32 + hi4*8];
  }

  f32x4 o[2][4];
  float mq[2] = {-1e30f, -1e30f}, lq[2] = {0.f, 0.f};
  #pragma unroll
  for (int qb = 0; qb < 2; ++qb)
    #pragma unroll
    for (int j = 0; j < 4; ++j) o[qb][j] = f32x4{0.f, 0.f, 0.f, 0.f};

  const f32x4 FZ = {0.f, 0.f, 0.f, 0.f};   // constant C for first MFMA

  const int ri = lane >> 3;
  const int lcs = ((lane & 7) ^ ri) * 8;   // pre-swizzled global chunk
  const size_t kbase = (size_t)(b*PKV + kvh) * PS * PD + (size_t)ks * 1024 * PD;
  const size_t vbase = (size_t)(b*PKV + kvh) * PD * PS + (size_t)ks * 1024;

  auto STAGE = [&](int kt, int buf) {
    const f16_t* kp = k_g + kbase + (size_t)kt * 64 * PD;
    const f16_t* vp = vt_g + vbase + kt * 64;
    #pragma unroll
    for (int i = 0; i < 2; ++i) {
      const int st = wave*2 + i;   // stripe of 8 rows
      gl16(kp + (st*8 + ri)*PD + lcs, &Ks[buf][st*8][0]);
      gl16(vp + (size_t)(st*8 + ri)*PS + lcs, &Vs[buf][st*8][0]);
    }
  };

  STAGE(0, 0);
  int cur = 0;
  const int rsw = lo16 & 7;

  for (int kt = 0; kt < 16; ++kt) {
    __syncthreads();   // drains vmcnt: buf[cur] ready; prev reads of buf[cur^1] done
    if (kt + 1 < 16) STAGE(kt + 1, cur ^ 1);

    // QK^T swapped: sacc[qb][j][r] = S'[kv = 16j + 4hi4 + r][q = 16qb + lo16]
    // first MFMA of each chain uses constant-zero C (no per-iter acc init)
    f32x4 sacc[2][4];
    __builtin_amdgcn_s_setprio(1);
    #pragma unroll
    for (int j = 0; j < 4; ++j) {
      f16x8 kf0 = *(const f16x8*)&Ks[cur][j*16 + lo16][(hi4 ^ rsw) * 8];
      f16x8 kf1 = *(const f16x8*)&Ks[cur][j*16 + lo16][((4 + hi4) ^ rsw) * 8];
      #pragma unroll
      for (int qb = 0; qb < 2; ++qb)
        sacc[qb][j] = MFMAH(kf1, qf[qb][1], MFMAH(kf0, qf[qb][0], FZ));
    }
    __builtin_amdgcn_s_setprio(0);

    // exp2-domain online softmax with defer-max (THR=8); fused exp+pack,
    // no write-back into sacc (avoids AGPR shuttle traffic).
    f16x8 pa[2][2];
    #pragma unroll
    for (int qb = 0; qb < 2; ++qb) {
      float x0 = fmaxf(fmaxf(sacc[qb][0][0], sacc[qb][0][1]),
                       fmaxf(sacc[qb][0][2], sacc[qb][0][3]));
      float x1 = fmaxf(fmaxf(sacc[qb][1][0], sacc[qb][1][1]),
                       fmaxf(sacc[qb][1][2], sacc[qb][1][3]));
      float x2 = fmaxf(fmaxf(sacc[qb][2][0], sacc[qb][2][1]),
                       fmaxf(sacc[qb][2][2], sacc[qb][2][3]));
      float x3 = fmaxf(fmaxf(sacc[qb][3][0], sacc[qb][3][1]),
                       fmaxf(sacc[qb][3][2], sacc[qb][3][3]));
      float tm = fmaxf(fmaxf(x0, x1), fmaxf(x2, x3));
      tm = fmaxf(tm, __shfl_xor(tm, 16));
      tm = fmaxf(tm, __shfl_xor(tm, 32));
      if (!__all(tm <= mq[qb] + 8.0f)) {
        float mnew = fmaxf(mq[qb], tm);
        float alpha = __builtin_amdgcn_exp2f(mq[qb] - mnew);
        lq[qb] *= alpha;
        #pragma unroll
        for (int jd = 0; jd < 4; ++jd) o[qb][jd] *= alpha;
        mq[qb] = mnew;
      }
      float ls = 0.f;
      #pragma unroll
      for (int t = 0; t < 2; ++t) {
        f16x8 v;
        #pragma unroll
        for (int e = 0; e < 8; ++e) {
          float p = __builtin_amdgcn_exp2f(sacc[qb][2*t + (e >> 2)][e & 3] - mq[qb]);
          ls += p;
          v[e] = (f16_t)p;
        }
        pa[qb][t] = v;
      }
      ls += __shfl_xor(ls, 16);
      ls += __shfl_xor(ls, 32);
      lq[qb] += ls;
    }

    // PV: O^T = V^T(permuted) * P  (P fragments lane-local)
    __builtin_amdgcn_s_setprio(1);
    #pragma unroll
    for (int jd = 0; jd < 4; ++jd) {
      #pragma unroll
      for (int t = 0; t < 2; ++t) {
        f16x8 vf = *(const f16x8*)&Vs[cur][jd*16 + lo16][((t*4 + hi4) ^ rsw) * 8];
        #pragma unroll
        for (int qb = 0; qb < 2; ++qb)
          o[qb][jd] = MFMAH(vf, pa[qb][t], o[qb][jd]);
      }
    }
    __builtin_amdgcn_s_setprio(0);

    cur ^= 1;
  }

  // ---- epilogue: (m,l) + normalized O via LDS transpose bounce ----
  __syncthreads();   // all waves done with K/V tiles; overlay is safe
  const int rbase = bh*PS + qt*128 + wave*32;
  if (hi4 == 0) {
    #pragma unroll
    for (int qb = 0; qb < 2; ++qb)
      ml[(size_t)ks*PR + rbase + qb*16 + lo16] = float2{mq[qb], lq[qb]};
  }
  #pragma unroll
  for (int qb = 0; qb < 2; ++qb) {
    float inv = 1.0f / lq[qb];
    #pragma unroll
    for (int jd = 0; jd < 4; ++jd)
      #pragma unroll
      for (int rp = 0; rp < 2; ++rp)
        *(f16x2*)&Ob[wave*32 + qb*16 + lo16][jd*16 + hi4*4 + 2*rp] =
            f16x2{(f16_t)(o[qb][jd][2*rp] * inv), (f16_t)(o[qb][jd][2*rp+1] * inv)};
  }
  {
    const int row = lane >> 1, half = lane & 1;
    const size_t gb_ = ((size_t)ks*PR + rbase + row) * PD + half*32;
    #pragma unroll
    for (int c = 0; c < 4; ++c)
      *(f16x8*)&op[gb_ + c*8] = *(const f16x8*)&Ob[wave*32 + row][half*32 + c*8];
  }
}

// ---------------------------------------------------------------------------
// Kernel 3: merge kv-split partials (normalized O + m,l in log2 domain).
// ---------------------------------------------------------------------------
__global__ __launch_bounds__(256)
void merge_kernel(const f16_t* __restrict__ op, const float2* __restrict__ ml,
                  f16_t* __restrict__ ao)
{
  const int gid = blockIdx.x * 256 + threadIdx.x;
  const int row = gid >> 3, oct = gid & 7;
  float2 e0 = ml[row], e1 = ml[PR + row];
  float M = fmaxf(e0.x, e1.x);
  float c0 = __builtin_amdgcn_exp2f(e0.x - M) * e0.y;
  float c1 = __builtin_amdgcn_exp2f(e1.x - M) * e1.y;
  float inv = 1.0f / (c0 + c1);
  c0 *= inv; c1 *= inv;
  f16x8 a = *(const f16x8*)&op[(size_t)row*PD + oct*8];
  f16x8 bq = *(const f16x8*)&op[(size_t)(PR + row)*PD + oct*8];
  f16x8 r;
  #pragma unroll
  for (int i = 0; i < 8; ++i)
    r[i] = (f16_t)(c0 * (float)a[i] + c1 * (float)bq[i]);
  const int bh = row >> 11, sq = row & 2047;
  const int b = bh >> 4, h = bh & 15;
  *(f16x8*)&ao[((size_t)(b*PS + sq))*PHID + h*PD + oct*8] = r;
}

// ---------------------------------------------------------------------------
// Kernel 4: out-projection, fp16 GEMM (ao x WoT) -> fp32. grid 512 swizzled.
// ---------------------------------------------------------------------------
__global__ __launch_bounds__(256)
void oproj_kernel(const f16_t* __restrict__ ao, const f16_t* __restrict__ woT,
                  float* __restrict__ out)
{
  __shared__ __align__(16) f16_t As[128][40], Bs[64][40];
  const int tid = threadIdx.x;
  const int lane = tid & 63, wave = tid >> 6;
  const int lo16 = lane & 15, hi4 = lane >> 4;
  const int lin = blockIdx.x;
  const int swz = (lin & 7) * 64 + (lin >> 3);
  const int m0 = (swz >> 4) * 128;
  const int col0 = (swz & 15) * 64;

  f32x4 acc[2][4];
  #pragma unroll
  for (int qb = 0; qb < 2; ++qb)
    #pragma unroll
    for (int j = 0; j < 4; ++j) acc[qb][j] = f32x4{0.f, 0.f, 0.f, 0.f};

  const int ar = tid >> 1, akc = (tid & 1) * 16;
  const int bn = tid & 63, bkc = (tid >> 6) * 8;

  f16x8 gA0, gA1, gB;
  auto LOADA = [&](int k0) {
    const f16_t* ap = &ao[(size_t)(m0 + ar) * PHID + k0 + akc];
    gA0 = *(const f16x8*)ap;
    gA1 = *(const f16x8*)(ap + 8);
  };
  auto LOADB = [&](int k0) {
    gB = *(const f16x8*)&woT[(size_t)(col0 + bn) * 1024 + k0 + bkc];
  };
  LOADA(0); LOADB(0);

  for (int k0 = 0; k0 < PHID; k0 += 32) {
    __syncthreads();
    *(f16x8*)&As[ar][akc]     = gA0;
    *(f16x8*)&As[ar][akc + 8] = gA1;
    *(f16x8*)&Bs[bn][bkc]     = gB;
    if (k0 + 32 < PHID) { LOADA(k0 + 32); LOADB(k0 + 32); }
    __syncthreads();
    {
      f16x8 a[2];
      #pragma unroll
      for (int qb = 0; qb < 2; ++qb)
        a[qb] = *(const f16x8*)&As[wave*32 + qb*16 + lo16][hi4*8];
      #pragma unroll
      for (int j = 0; j < 4; ++j) {
        f16x8 bb = *(const f16x8*)&Bs[j*16 + lo16][hi4*8];
        #pragma unroll
        for (int qb = 0; qb < 2; ++qb)
          acc[qb][j] = MFMAH(a[qb], bb, acc[qb][j]);
      }
    }
  }

  #pragma unroll
  for (int qb = 0; qb < 2; ++qb)
    #pragma unroll
    for (int r = 0; r < 4; ++r) {
      int mg = m0 + wave*32 + qb*16 + hi4*4 + r;
      #pragma unroll
      for (int j = 0; j < 4; ++j)
        out[(size_t)mg*PHID + col0 + lo16 + 16*j] = acc[qb][j][r];
    }
}

// ---------------------------------------------------------------------------
extern "C" void kernel_launch(void* const* d_in, const int* in_sizes, int n_in,
                              void* d_out, int out_size, void* d_ws, size_t ws_size,
                              hipStream_t stream) {
  (void)in_sizes; (void)n_in; (void)out_size; (void)ws_size;
  const float* hs   = (const float*)d_in[0];
  const float* cosp = (const float*)d_in[1];
  const float* sinp = (const float*)d_in[2];
  // d_in[3] position_ids: only shape[-1]=2 used (NDIM=2 hardcoded)
  const float* Wq   = (const float*)d_in[4];
  const float* Wk   = (const float*)d_in[5];
  const float* Wv   = (const float*)d_in[6];
  const float* Wo   = (const float*)d_in[7];
  const float* qnw  = (const float*)d_in[8];
  const float* knw  = (const float*)d_in[9];
  float* out = (float*)d_out;

  const size_t QN = (size_t)PB*PH*PS*PD;    // 4,194,304 (== PR*PD == PM*PHID)
  const size_t KN = (size_t)PB*PKV*PS*PD;   // 2,097,152
  const size_t HN = (size_t)PM*PHID;        // 4,194,304
  char* wsb = (char*)d_ws;
  f16_t*  qv  = (f16_t*)wsb;                   // QN fp16 (8 MB)
  f16_t*  kv  = qv + QN;                       // KN (4 MB)
  f16_t*  vt  = kv + KN;                       // KN (4 MB)
  f16_t*  hsf = vt + KN;                       // HN (8 MB, dead after qkv)
  f16_t*  wtT = hsf + HN;                      // 3072*1024 (6 MB; rows 2048+ live)
  f16_t*  op  = wtT + (size_t)3072*1024;       // 2*QN (16 MB)
  float2* ml  = (float2*)(op + 2*QN);          // 2*PR float2 (1 MB)
  f16_t*  ao  = qv;   // alias: attn done with Q before merge (stream-ordered)
  const f16_t* woT = wtT + (size_t)2048*1024;

  convert_hs<<<dim3(2048), 256, 0, stream>>>(hs, hsf);
  convert_w <<<dim3(768),  256, 0, stream>>>(Wq, Wk, Wv, Wo, wtT);
  qkv_kernel<<<dim3(512),  256, 0, stream>>>(hsf, wtT, cosp, sinp,
                                             qnw, knw, qv, kv, vt);
  attn_kernel<<<dim3(1024), 256, 0, stream>>>(qv, kv, vt, op, ml);
  merge_kernel<<<dim3(PR*8/256), 256, 0, stream>>>(op, ml, ao);
  oproj_kernel<<<dim3(512), 256, 0, stream>>>(ao, woT, out);
}

// Round 11
// 118.660 us; speedup vs baseline: 2.3689x; 1.0045x over previous
//
#include <hip/hip_runtime.h>

// Problem constants
#define PB 2
#define PS 2048
#define PHID 1024
#define PH 16
#define PKV 8
#define PD 64
#define PM (PB*PS)    // 4096
#define PR (PB*PH*PS) // 65536 q-rows total

typedef _Float16 f16_t;
typedef _Float16 f16x8 __attribute__((ext_vector_type(8)));
typedef _Float16 f16x2 __attribute__((ext_vector_type(2)));
typedef __fp16 fp16v2 __attribute__((ext_vector_type(2)));   // cvt_pkrtz native type
typedef float f32x4 __attribute__((ext_vector_type(4)));

#define MFMAH(a,b,c)  __builtin_amdgcn_mfma_f32_16x16x32_f16((a),(b),(c),0,0,0)
#define LOG2E 1.44269504f

// global -> LDS direct copy, 16B per lane (dst = uniform base + lane*16).
__device__ __forceinline__ void gl16(const f16_t* g, f16_t* l) {
  __builtin_amdgcn_global_load_lds(
      (const __attribute__((address_space(1))) void*)g,
      (__attribute__((address_space(3))) void*)l, 16, 0, 0);
}

// ---------------------------------------------------------------------------
// Kernel 0a: hs fp32 -> fp16.
// ---------------------------------------------------------------------------
__global__ __launch_bounds__(256)
void convert_hs(const float* __restrict__ hs, f16_t* __restrict__ hf)
{
  const size_t i = ((size_t)blockIdx.x * 256 + threadIdx.x) * 8;
  float4 a = *(const float4*)&hs[i];
  float4 b = *(const float4*)&hs[i + 4];
  float xs[8] = {a.x, a.y, a.z, a.w, b.x, b.y, b.z, b.w};
  f16x8 v;
  #pragma unroll
  for (int j = 0; j < 8; ++j) v[j] = (f16_t)xs[j];
  *(f16x8*)&hf[i] = v;
}

// ---------------------------------------------------------------------------
// Kernel 0b: weights -> transposed [n][k] fp16 (rows: Wq^T 0-1023, Wk^T
// 1024-1535, Wv^T 1536-2047, Wo^T 2048-3071). grid 768.
// ---------------------------------------------------------------------------
__global__ __launch_bounds__(256)
void convert_w(const float* __restrict__ Wq, const float* __restrict__ Wk,
               const float* __restrict__ Wv, const float* __restrict__ Wo,
               f16_t* __restrict__ wtT)
{
  __shared__ float Tt[64][68];
  const int tid = threadIdx.x;
  const int slot = blockIdx.x >> 4, k0 = (blockIdx.x & 15) * 64;

  const float* src; int N, ncol0, orow0;
  if (slot < 16)      { src = Wq; N = 1024; ncol0 = slot*64;      orow0 = slot*64; }
  else if (slot < 24) { src = Wk; N = 512;  ncol0 = (slot-16)*64; orow0 = 1024 + (slot-16)*64; }
  else if (slot < 32) { src = Wv; N = 512;  ncol0 = (slot-24)*64; orow0 = 1536 + (slot-24)*64; }
  else                { src = Wo; N = 1024; ncol0 = (slot-32)*64; orow0 = 2048 + (slot-32)*64; }

  const int tk = tid >> 6, tn = tid & 63;
  #pragma unroll
  for (int i = 0; i < 16; ++i)
    Tt[tn][tk*16 + i] = src[(size_t)(k0 + tk*16 + i) * N + ncol0 + tn];
  __syncthreads();

  const int n = tid >> 2, kc = (tid & 3) * 16;
  f16x8 a0, a1;
  #pragma unroll
  for (int i = 0; i < 8; ++i) {
    a0[i] = (f16_t)Tt[n][kc + i];
    a1[i] = (f16_t)Tt[n][kc + 8 + i];
  }
  const size_t ob = (size_t)(orow0 + n) * 1024 + k0 + kc;
  *(f16x8*)&wtT[ob]     = a0;
  *(f16x8*)&wtT[ob + 8] = a1;
}

// ---------------------------------------------------------------------------
// Kernel 1: QKV projection fp16 GEMM, WIDE SLOTS (128 cols = 2 heads/block).
// grid 512 XCD-swizzled = 32 row-tiles x 16 wide-slots (ws<8 Q, <12 K, else V).
// Per-head RMSNorm + RoPE epilogue; V stored kv-permuted for lane-local PV.
// ---------------------------------------------------------------------------
__global__ __launch_bounds__(256)
void qkv_kernel(const f16_t* __restrict__ hsf, const f16_t* __restrict__ wtT,
                const float* __restrict__ cosp, const float* __restrict__ sinp,
                const float* __restrict__ qnw, const float* __restrict__ knw,
                f16_t* __restrict__ q_o, f16_t* __restrict__ k_o,
                f16_t* __restrict__ vt_o)
{
  __shared__ __align__(16) f16_t Ah[128][64];  // 16 KB
  __shared__ __align__(16) f16_t Bh[128][64];  // 16 KB

  const int tid = threadIdx.x;
  const int lane = tid & 63, wave = tid >> 6;
  const int lo16 = lane & 15, hi4 = lane >> 4;
  const int lin = blockIdx.x;
  const int swz = (lin & 7) * 64 + (lin >> 3);   // 512 = 8 * 64, bijective
  const int m0 = (swz >> 4) * 128;
  const int ws = swz & 15;
  const int orow = ws * 128;

  int kind, hd0;
  if (ws < 8)       { kind = 0; hd0 = ws*2; }
  else if (ws < 12) { kind = 1; hd0 = (ws-8)*2; }
  else              { kind = 2; hd0 = (ws-12)*2; }

  f32x4 acc[2][8];
  #pragma unroll
  for (int qb = 0; qb < 2; ++qb)
    #pragma unroll
    for (int j = 0; j < 8; ++j) acc[qb][j] = f32x4{0.f, 0.f, 0.f, 0.f};

  const int ri = lane >> 3, pc = lane & 7;
  const int lcs = (pc ^ ri) * 8;   // pre-swizzled global chunk
  size_t aoff4[4]; f16_t* aldst4[4];
  size_t boff4[4]; f16_t* bldst4[4];
  #pragma unroll
  for (int q = 0; q < 4; ++q) {
    aoff4[q] = (size_t)(m0 + wave*32 + q*8 + ri) * PHID + lcs;
    aldst4[q] = &Ah[wave*32 + q*8][0];
    boff4[q] = (size_t)(orow + wave*32 + q*8 + ri) * 1024 + lcs;
    bldst4[q] = &Bh[wave*32 + q*8][0];
  }

  const int rsw = lo16 & 7;

  for (int k0 = 0; k0 < PHID; k0 += 64) {
    __syncthreads();
    #pragma unroll
    for (int q = 0; q < 4; ++q) gl16(hsf + aoff4[q] + k0, aldst4[q]);
    #pragma unroll
    for (int q = 0; q < 4; ++q) gl16(wtT + boff4[q] + k0, bldst4[q]);
    __syncthreads();

    #pragma unroll
    for (int t = 0; t < 2; ++t) {
      const int ccol = ((t*4 + hi4) ^ rsw) * 8;
      f16x8 ah[2];
      #pragma unroll
      for (int qb = 0; qb < 2; ++qb)
        ah[qb] = *(const f16x8*)&Ah[wave*32 + qb*16 + lo16][ccol];
      #pragma unroll
      for (int j = 0; j < 8; ++j) {
        f16x8 bh = *(const f16x8*)&Bh[j*16 + lo16][ccol];
        #pragma unroll
        for (int qb = 0; qb < 2; ++qb)
          acc[qb][j] = MFMAH(ah[qb], bh, acc[qb][j]);
      }
    }
  }

  // ---- epilogue: per-head RMSNorm + RoPE; fp16 stores ----
  float nwv[4];
  #pragma unroll
  for (int jj = 0; jj < 4; ++jj)
    nwv[jj] = (kind == 0) ? qnw[lo16 + 16*jj]
            : (kind == 1) ? knw[lo16 + 16*jj] : 1.0f;

  #pragma unroll
  for (int qb = 0; qb < 2; ++qb) {
    float sc[2][4];
    #pragma unroll
    for (int r = 0; r < 4; ++r) {
      float s0 = 0.f, s1 = 0.f;
      #pragma unroll
      for (int j = 0; j < 4; ++j) {
        s0 += acc[qb][j][r]   * acc[qb][j][r];
        s1 += acc[qb][j+4][r] * acc[qb][j+4][r];
      }
      #pragma unroll
      for (int m = 1; m < 16; m <<= 1) {
        s0 += __shfl_xor(s0, m);
        s1 += __shfl_xor(s1, m);
      }
      sc[0][r] = 1.0f / sqrtf(s0 * (1.0f/64.0f) + 1e-6f);
      sc[1][r] = 1.0f / sqrtf(s1 * (1.0f/64.0f) + 1e-6f);
    }

    float y[8][4];
    #pragma unroll
    for (int j = 0; j < 8; ++j)
      #pragma unroll
      for (int r = 0; r < 4; ++r)
        y[j][r] = acc[qb][j][r] * sc[j>>2][r] * nwv[j&3];

    if (kind == 2) {
      #pragma unroll
      for (int r = 0; r < 4; ++r) {
        int mg = m0 + wave*32 + qb*16 + hi4*4 + r;
        int b = mg >> 11, sq = mg & 2047;
        int g = sq & 63;
        int sp = (g & 3) | (((g >> 4) & 1) << 2) | (((g >> 2) & 1) << 3)
               | (((g >> 3) & 1) << 4) | (g & 32);
        int sq2 = (sq & ~63) | sp;
        #pragma unroll
        for (int j = 0; j < 8; ++j) {
          int d = lo16 + 16*(j & 3), hd = hd0 + (j >> 2);
          vt_o[((size_t)((b*PKV + hd)*PD + d))*PS + sq2] = (f16_t)y[j][r];
        }
      }
    } else {
      #pragma unroll
      for (int r = 0; r < 4; ++r) {
        int mg = m0 + wave*32 + qb*16 + hi4*4 + r;
        int b = mg >> 11, sq = mg & 2047;
        const float* cp = &cosp[(size_t)mg * PD];
        const float* sp = &sinp[(size_t)mg * PD];
        float z[8];
        #pragma unroll
        for (int j = 0; j < 8; ++j) {
          int d = lo16 + 16*(j & 3);
          float c = cp[d], s = sp[d];
          float rot = (j & 1) ? y[j-1][r] : -y[j+1][r];
          z[j] = y[j][r] * c + rot * s;
        }
        #pragma unroll
        for (int j = 0; j < 8; ++j) {
          int d = lo16 + 16*(j & 3), hd = hd0 + (j >> 2);
          if (kind == 0) {
            size_t idx = ((size_t)(b*PH + hd)*PS + sq)*PD + d;
            q_o[idx] = (f16_t)(z[j] * LOG2E);   // exp2-domain fold
          } else {
            size_t idx = ((size_t)(b*PKV + hd)*PS + sq)*PD + d;
            k_o[idx] = (f16_t)z[j];
          }
        }
      }
    }
  }
}

// ---------------------------------------------------------------------------
// Kernel 2: flash attention. gl16 double-buffered K/V (XOR-swizzled),
// lane-local P. VALU-lean softmax: -m folded into MFMA C-operand (subs only
// in rare rescale branch), l via ones-MFMA (no adds/shuffles), cvt_pkrtz
// packing, max3 tree. launch_bounds(256,3) keeps accumulators in VGPRs.
// grid 1024 XCD-swizzled. LDS 32 KB.
// ---------------------------------------------------------------------------
__global__ __launch_bounds__(256, 3)
void attn_kernel(const f16_t* __restrict__ q_g, const f16_t* __restrict__ k_g,
                 const f16_t* __restrict__ vt_g,
                 f16_t* __restrict__ op, float2* __restrict__ ml)
{
  __shared__ __align__(16) char lds_raw[32768];
  f16_t (*Ks)[64][64] = (f16_t (*)[64][64])lds_raw;             // [2][64][64]
  f16_t (*Vs)[64][64] = (f16_t (*)[64][64])(lds_raw + 16384);   // [2][64][64]
  f16_t (*Ob)[72]     = (f16_t (*)[72])lds_raw;                 // epilogue overlay

  const int tid = threadIdx.x, lane = tid & 63, wave = tid >> 6;
  const int lo16 = lane & 15, hi4 = lane >> 4;
  const int lin = blockIdx.x;
  const int swz = (lin & 7) * 128 + (lin >> 3);
  const int qt = swz & 15;
  const int bh = (swz >> 4) & 31;
  const int ks = swz >> 9;
  const int b = bh >> 4, h = bh & 15, kvh = h >> 1;   // GQA groups=2

  f16x8 qf[2][2];
  #pragma unroll
  for (int qb = 0; qb < 2; ++qb) {
    const size_t qbase = ((size_t)(b*PH + h)*PS + qt*128 + wave*32 + qb*16 + lo16) * PD;
    #pragma unroll
    for (int t = 0; t < 2; ++t)
      qf[qb][t] = *(const f16x8*)&q_g[qbase + t*32 + hi4*8];
  }

  f32x4 o[2][4], lsum[2];
  float mq[2] = {0.f, 0.f};   // log2-domain running max
  #pragma unroll
  for (int qb = 0; qb < 2; ++qb) {
    lsum[qb] = f32x4{0.f, 0.f, 0.f, 0.f};
    #pragma unroll
    for (int j = 0; j < 4; ++j) o[qb][j] = f32x4{0.f, 0.f, 0.f, 0.f};
  }

  f16x8 ONES;
  #pragma unroll
  for (int e = 0; e < 8; ++e) ONES[e] = (f16_t)1.0f;

  const int ri = lane >> 3;
  const int lcs = ((lane & 7) ^ ri) * 8;   // pre-swizzled global chunk
  const size_t kbase = (size_t)(b*PKV + kvh) * PS * PD + (size_t)ks * 1024 * PD;
  const size_t vbase = (size_t)(b*PKV + kvh) * PD * PS + (size_t)ks * 1024;

  auto STAGE = [&](int kt, int buf) {
    const f16_t* kp = k_g + kbase + (size_t)kt * 64 * PD;
    const f16_t* vp = vt_g + vbase + kt * 64;
    #pragma unroll
    for (int i = 0; i < 2; ++i) {
      const int st = wave*2 + i;   // stripe of 8 rows
      gl16(kp + (st*8 + ri)*PD + lcs, &Ks[buf][st*8][0]);
      gl16(vp + (size_t)(st*8 + ri)*PS + lcs, &Vs[buf][st*8][0]);
    }
  };

  STAGE(0, 0);
  int cur = 0;
  const int rsw = lo16 & 7;

  for (int kt = 0; kt < 16; ++kt) {
    __syncthreads();   // buf[cur] ready; prev reads of buf[cur^1] done
    if (kt + 1 < 16) STAGE(kt + 1, cur ^ 1);

    // QK^T swapped with -mq folded into the C operand: sacc = K.Q - mq
    f32x4 sacc[2][4];
    __builtin_amdgcn_s_setprio(1);
    #pragma unroll
    for (int j = 0; j < 4; ++j) {
      f16x8 kf0 = *(const f16x8*)&Ks[cur][j*16 + lo16][(hi4 ^ rsw) * 8];
      f16x8 kf1 = *(const f16x8*)&Ks[cur][j*16 + lo16][((4 + hi4) ^ rsw) * 8];
      #pragma unroll
      for (int qb = 0; qb < 2; ++qb) {
        f32x4 mc = {-mq[qb], -mq[qb], -mq[qb], -mq[qb]};
        sacc[qb][j] = MFMAH(kf1, qf[qb][1], MFMAH(kf0, qf[qb][0], mc));
      }
    }
    __builtin_amdgcn_s_setprio(0);

    // softmax: scores arrive pre-shifted; exp+pack straight to fp16 pairs.
    f16x8 pa[2][2];
    #pragma unroll
    for (int qb = 0; qb < 2; ++qb) {
      // max3-shaped reduction over the 16 shifted scores
      float m0_ = fmaxf(fmaxf(sacc[qb][0][0], sacc[qb][0][1]), sacc[qb][0][2]);
      float m1_ = fmaxf(fmaxf(sacc[qb][0][3], sacc[qb][1][0]), sacc[qb][1][1]);
      float m2_ = fmaxf(fmaxf(sacc[qb][1][2], sacc[qb][1][3]), sacc[qb][2][0]);
      float m3_ = fmaxf(fmaxf(sacc[qb][2][1], sacc[qb][2][2]), sacc[qb][2][3]);
      float m4_ = fmaxf(fmaxf(sacc[qb][3][0], sacc[qb][3][1]), sacc[qb][3][2]);
      float tm  = fmaxf(fmaxf(m0_, m1_), m2_);
      tm = fmaxf(fmaxf(tm, m3_), m4_);
      tm = fmaxf(tm, sacc[qb][3][3]);
      tm = fmaxf(tm, __shfl_xor(tm, 16));
      tm = fmaxf(tm, __shfl_xor(tm, 32));

      if (!__all(tm <= 8.0f)) {
        // rescale path (rare after first tile)
        float tmx = fmaxf(tm, 0.f);
        float alpha = __builtin_amdgcn_exp2f(-tmx);
        lsum[qb] *= alpha;
        #pragma unroll
        for (int jd = 0; jd < 4; ++jd) o[qb][jd] *= alpha;
        mq[qb] += tmx;
        #pragma unroll
        for (int t = 0; t < 2; ++t) {
          union { fp16v2 h[4]; f16x8 v; } u;
          #pragma unroll
          for (int pr = 0; pr < 2; ++pr) {
            float p0 = __builtin_amdgcn_exp2f(sacc[qb][2*t+pr][0] - tmx);
            float p1 = __builtin_amdgcn_exp2f(sacc[qb][2*t+pr][1] - tmx);
            float p2 = __builtin_amdgcn_exp2f(sacc[qb][2*t+pr][2] - tmx);
            float p3 = __builtin_amdgcn_exp2f(sacc[qb][2*t+pr][3] - tmx);
            u.h[pr*2]   = __builtin_amdgcn_cvt_pkrtz(p0, p1);
            u.h[pr*2+1] = __builtin_amdgcn_cvt_pkrtz(p2, p3);
          }
          pa[qb][t] = u.v;
        }
      } else {
        // common path: no subtraction at all
        #pragma unroll
        for (int t = 0; t < 2; ++t) {
          union { fp16v2 h[4]; f16x8 v; } u;
          #pragma unroll
          for (int pr = 0; pr < 2; ++pr) {
            float p0 = __builtin_amdgcn_exp2f(sacc[qb][2*t+pr][0]);
            float p1 = __builtin_amdgcn_exp2f(sacc[qb][2*t+pr][1]);
            float p2 = __builtin_amdgcn_exp2f(sacc[qb][2*t+pr][2]);
            float p3 = __builtin_amdgcn_exp2f(sacc[qb][2*t+pr][3]);
            u.h[pr*2]   = __builtin_amdgcn_cvt_pkrtz(p0, p1);
            u.h[pr*2+1] = __builtin_amdgcn_cvt_pkrtz(p2, p3);
          }
          pa[qb][t] = u.v;
        }
      }
    }

    // PV + l-accumulation (ones-row MFMA sums P over kv; no VALU adds)
    __builtin_amdgcn_s_setprio(1);
    #pragma unroll
    for (int jd = 0; jd < 4; ++jd) {
      #pragma unroll
      for (int t = 0; t < 2; ++t) {
        f16x8 vf = *(const f16x8*)&Vs[cur][jd*16 + lo16][((t*4 + hi4) ^ rsw) * 8];
        #pragma unroll
        for (int qb = 0; qb < 2; ++qb)
          o[qb][jd] = MFMAH(vf, pa[qb][t], o[qb][jd]);
      }
    }
    #pragma unroll
    for (int qb = 0; qb < 2; ++qb)
      #pragma unroll
      for (int t = 0; t < 2; ++t)
        lsum[qb] = MFMAH(ONES, pa[qb][t], lsum[qb]);
    __builtin_amdgcn_s_setprio(0);

    cur ^= 1;
  }

  // ---- epilogue: (m,l) + normalized O via LDS transpose bounce ----
  __syncthreads();   // all waves done with K/V tiles; overlay is safe
  const int rbase = bh*PS + qt*128 + wave*32;
  if (hi4 == 0) {
    #pragma unroll
    for (int qb = 0; qb < 2; ++qb)
      ml[(size_t)ks*PR + rbase + qb*16 + lo16] = float2{mq[qb], lsum[qb][0]};
  }
  #pragma unroll
  for (int qb = 0; qb < 2; ++qb) {
    float inv = 1.0f / lsum[qb][0];
    #pragma unroll
    for (int jd = 0; jd < 4; ++jd)
      #pragma unroll
      for (int rp = 0; rp < 2; ++rp)
        *(f16x2*)&Ob[wave*32 + qb*16 + lo16][jd*16 + hi4*4 + 2*rp] =
            f16x2{(f16_t)(o[qb][jd][2*rp] * inv), (f16_t)(o[qb][jd][2*rp+1] * inv)};
  }
  {
    const int row = lane >> 1, half = lane & 1;
    const size_t gb_ = ((size_t)ks*PR + rbase + row) * PD + half*32;
    #pragma unroll
    for (int c = 0; c < 4; ++c)
      *(f16x8*)&op[gb_ + c*8] = *(const f16x8*)&Ob[wave*32 + row][half*32 + c*8];
  }
}

// ---------------------------------------------------------------------------
// Kernel 3: merge kv-split partials (normalized O + m,l in log2 domain).
// ---------------------------------------------------------------------------
__global__ __launch_bounds__(256)
void merge_kernel(const f16_t* __restrict__ op, const float2* __restrict__ ml,
                  f16_t* __restrict__ ao)
{
  const int gid = blockIdx.x * 256 + threadIdx.x;
  const int row = gid >> 3, oct = gid & 7;
  float2 e0 = ml[row], e1 = ml[PR + row];
  float M = fmaxf(e0.x, e1.x);
  float c0 = __builtin_amdgcn_exp2f(e0.x - M) * e0.y;
  float c1 = __builtin_amdgcn_exp2f(e1.x - M) * e1.y;
  float inv = 1.0f / (c0 + c1);
  c0 *= inv; c1 *= inv;
  f16x8 a = *(const f16x8*)&op[(size_t)row*PD + oct*8];
  f16x8 bq = *(const f16x8*)&op[(size_t)(PR + row)*PD + oct*8];
  f16x8 r;
  #pragma unroll
  for (int i = 0; i < 8; ++i)
    r[i] = (f16_t)(c0 * (float)a[i] + c1 * (float)bq[i]);
  const int bh = row >> 11, sq = row & 2047;
  const int b = bh >> 4, h = bh & 15;
  *(f16x8*)&ao[((size_t)(b*PS + sq))*PHID + h*PD + oct*8] = r;
}

// ---------------------------------------------------------------------------
// Kernel 4: out-projection, fp16 GEMM (ao x WoT) -> fp32. grid 512 swizzled.
// ---------------------------------------------------------------------------
__global__ __launch_bounds__(256)
void oproj_kernel(const f16_t* __restrict__ ao, const f16_t* __restrict__ woT,
                  float* __restrict__ out)
{
  __shared__ __align__(16) f16_t As[128][40], Bs[64][40];
  const int tid = threadIdx.x;
  const int lane = tid & 63, wave = tid >> 6;
  const int lo16 = lane & 15, hi4 = lane >> 4;
  const int lin = blockIdx.x;
  const int swz = (lin & 7) * 64 + (lin >> 3);
  const int m0 = (swz >> 4) * 128;
  const int col0 = (swz & 15) * 64;

  f32x4 acc[2][4];
  #pragma unroll
  for (int qb = 0; qb < 2; ++qb)
    #pragma unroll
    for (int j = 0; j < 4; ++j) acc[qb][j] = f32x4{0.f, 0.f, 0.f, 0.f};

  const int ar = tid >> 1, akc = (tid & 1) * 16;
  const int bn = tid & 63, bkc = (tid >> 6) * 8;

  f16x8 gA0, gA1, gB;
  auto LOADA = [&](int k0) {
    const f16_t* ap = &ao[(size_t)(m0 + ar) * PHID + k0 + akc];
    gA0 = *(const f16x8*)ap;
    gA1 = *(const f16x8*)(ap + 8);
  };
  auto LOADB = [&](int k0) {
    gB = *(const f16x8*)&woT[(size_t)(col0 + bn) * 1024 + k0 + bkc];
  };
  LOADA(0); LOADB(0);

  for (int k0 = 0; k0 < PHID; k0 += 32) {
    __syncthreads();
    *(f16x8*)&As[ar][akc]     = gA0;
    *(f16x8*)&As[ar][akc + 8] = gA1;
    *(f16x8*)&Bs[bn][bkc]     = gB;
    if (k0 + 32 < PHID) { LOADA(k0 + 32); LOADB(k0 + 32); }
    __syncthreads();
    {
      f16x8 a[2];
      #pragma unroll
      for (int qb = 0; qb < 2; ++qb)
        a[qb] = *(const f16x8*)&As[wave*32 + qb*16 + lo16][hi4*8];
      #pragma unroll
      for (int j = 0; j < 4; ++j) {
        f16x8 bb = *(const f16x8*)&Bs[j*16 + lo16][hi4*8];
        #pragma unroll
        for (int qb = 0; qb < 2; ++qb)
          acc[qb][j] = MFMAH(a[qb], bb, acc[qb][j]);
      }
    }
  }

  #pragma unroll
  for (int qb = 0; qb < 2; ++qb)
    #pragma unroll
    for (int r = 0; r < 4; ++r) {
      int mg = m0 + wave*32 + qb*16 + hi4*4 + r;
      #pragma unroll
      for (int j = 0; j < 4; ++j)
        out[(size_t)mg*PHID + col0 + lo16 + 16*j] = acc[qb][j][r];
    }
}

// ---------------------------------------------------------------------------
extern "C" void kernel_launch(void* const* d_in, const int* in_sizes, int n_in,
                              void* d_out, int out_size, void* d_ws, size_t ws_size,
                              hipStream_t stream) {
  (void)in_sizes; (void)n_in; (void)out_size; (void)ws_size;
  const float* hs   = (const float*)d_in[0];
  const float* cosp = (const float*)d_in[1];
  const float* sinp = (const float*)d_in[2];
  // d_in[3] position_ids: only shape[-1]=2 used (NDIM=2 hardcoded)
  const float* Wq   = (const float*)d_in[4];
  const float* Wk   = (const float*)d_in[5];
  const float* Wv   = (const float*)d_in[6];
  const float* Wo   = (const float*)d_in[7];
  const float* qnw  = (const float*)d_in[8];
  const float* knw  = (const float*)d_in[9];
  float* out = (float*)d_out;

  const size_t QN = (size_t)PB*PH*PS*PD;    // 4,194,304 (== PR*PD == PM*PHID)
  const size_t KN = (size_t)PB*PKV*PS*PD;   // 2,097,152
  const size_t HN = (size_t)PM*PHID;        // 4,194,304
  char* wsb = (char*)d_ws;
  f16_t*  qv  = (f16_t*)wsb;                   // QN fp16 (8 MB)
  f16_t*  kv  = qv + QN;                       // KN (4 MB)
  f16_t*  vt  = kv + KN;                       // KN (4 MB)
  f16_t*  hsf = vt + KN;                       // HN (8 MB, dead after qkv)
  f16_t*  wtT = hsf + HN;                      // 3072*1024 (6 MB; rows 2048+ live)
  f16_t*  op  = wtT + (size_t)3072*1024;       // 2*QN (16 MB)
  float2* ml  = (float2*)(op + 2*QN);          // 2*PR float2 (1 MB)
  f16_t*  ao  = qv;   // alias: attn done with Q before merge (stream-ordered)
  const f16_t* woT = wtT + (size_t)2048*1024;

  convert_hs<<<dim3(2048), 256, 0, stream>>>(hs, hsf);
  convert_w <<<dim3(768),  256, 0, stream>>>(Wq, Wk, Wv, Wo, wtT);
  qkv_kernel<<<dim3(512),  256, 0, stream>>>(hsf, wtT, cosp, sinp,
                                             qnw, knw, qv, kv, vt);
  attn_kernel<<<dim3(1024), 256, 0, stream>>>(qv, kv, vt, op, ml);
  merge_kernel<<<dim3(PR*8/256), 256, 0, stream>>>(op, ml, ao);
  oproj_kernel<<<dim3(512), 256, 0, stream>>>(ao, woT, out);
}